// Round 10
// baseline (2244.796 us; speedup 1.0000x reference)
//
#include <hip/hip_runtime.h>
#include <stdint.h>

// ---------------------------------------------------------------------------
// TransformerEncoderLayer: b=4 s=2048 d=128 h=8 (head_dim=128) dff=2048
// Round-10: r9 green build + conflict-free LDS attention:
//  - V pre-transposed by k_qkv (Vt [hh][d][s]) -> PV B-fragment = vector load
//  - K/V^T/P tiles XOR-swizzled (chunk16B ^= row&7) on write AND read
//  - 1/sqrt(d) folded into Q at projection
// Everything else byte-identical to r9 (proven green).
// ---------------------------------------------------------------------------

using f32x4 = __attribute__((ext_vector_type(4))) float;
using s16x8 = __attribute__((ext_vector_type(8))) short;
using s16x4 = __attribute__((ext_vector_type(4))) short;
typedef __bf16 bf16x8 __attribute__((ext_vector_type(8)));

// D = A*B + D. A: lane holds A[lane&15][8*(lane>>4)+e]; B: B[8*(lane>>4)+e][lane&15];
// D: D[(lane>>4)*4+r][lane&15]  (HW-proven r8/r9)
__device__ inline void mfma_bf16(f32x4* acc, s16x8 a, s16x8 b) {
    *acc = __builtin_amdgcn_mfma_f32_16x16x32_bf16(
        __builtin_bit_cast(bf16x8, a), __builtin_bit_cast(bf16x8, b), *acc, 0, 0, 0);
}

__device__ inline short f2bf(float f) {   // RNE f32 -> bf16 bits
    uint32_t u = __builtin_bit_cast(uint32_t, f);
    u += 0x7fffu + ((u >> 16) & 1u);
    return (short)(u >> 16);
}

// ---------------- zero an f32 buffer (graph-safe) --------------------------
__global__ __launch_bounds__(256) void k_zero(float* __restrict__ p) {
    p[blockIdx.x * 256 + threadIdx.x] = 0.f;
}

// ---------------- weight transpose: w [R][C] f32 (C=1<<lc) -> wt [C][R] bf16
__global__ __launch_bounds__(256) void k_transpose_w(const float* __restrict__ w,
                                                     short* __restrict__ wt,
                                                     int R, int lc) {
    int i = blockIdx.x * 256 + threadIdx.x;
    int r = i >> lc, c = i & ((1 << lc) - 1);
    wt[c * R + r] = f2bf(w[i]);
}

// ---------------- QKV projection (one batch, one 4-head pass) --------------
// Q (pre-scaled by 1/sqrt(d)), K row-major [hh4][2048][128];
// V transposed [hh4][128][2048]. hp = head pass (0/1).
__global__ __launch_bounds__(256) void k_qkv(
    const float* __restrict__ xB, const short* __restrict__ WqT,
    const short* __restrict__ WkT, const short* __restrict__ WvT,
    short* __restrict__ Qh, short* __restrict__ Kh, short* __restrict__ Vt,
    int hp)
{
    const int z = blockIdx.z;
    const short* __restrict__ WT = (z == 0) ? WqT : (z == 1) ? WkT : WvT; // [1024][128]
    const int w = threadIdx.x >> 6, lane = threadIdx.x & 63;
    const int g = lane >> 4, li = lane & 15;
    const int m0 = blockIdx.x * 64 + w * 16;
    const int n0 = blockIdx.y * 64;               // 0..448 within the 512-col pass
    f32x4 acc[4] = {};
    #pragma unroll
    for (int ks = 0; ks < 4; ++ks) {
        const float* xr = xB + (size_t)(m0 + li) * 128 + ks * 32 + g * 8;
        float4 v0 = *(const float4*)xr, v1 = *(const float4*)(xr + 4);
        s16x8 a = { f2bf(v0.x), f2bf(v0.y), f2bf(v0.z), f2bf(v0.w),
                    f2bf(v1.x), f2bf(v1.y), f2bf(v1.z), f2bf(v1.w) };
        #pragma unroll
        for (int nt = 0; nt < 4; ++nt) {
            s16x8 bfr = *(const s16x8*)(WT + (size_t)(hp * 512 + n0 + nt * 16 + li) * 128
                                           + ks * 32 + g * 8);
            mfma_bf16(&acc[nt], a, bfr);
        }
    }
    const float sc = (z == 0) ? 0.088388347648318447f : 1.0f; // 1/sqrt(128) into Q
    #pragma unroll
    for (int nt = 0; nt < 4; ++nt) {
        int col = n0 + nt * 16 + li;              // 0..511
        int hh = col >> 7, dd = col & 127;        // head-in-pass, dim
        if (z == 2) {
            int row0 = m0 + g * 4;
            s16x4 o = { f2bf(acc[nt][0]), f2bf(acc[nt][1]),
                        f2bf(acc[nt][2]), f2bf(acc[nt][3]) };
            *(s16x4*)(Vt + ((size_t)hh * 128 + dd) * 2048 + row0) = o;
        } else {
            short* __restrict__ dst = (z == 0) ? Qh : Kh;
            #pragma unroll
            for (int r = 0; r < 4; ++r)
                dst[((size_t)hh * 2048 + m0 + g * 4 + r) * 128 + dd] =
                    f2bf(acc[nt][r] * sc);
        }
    }
}

// ---------------- flash attention (swizzled LDS, vector PV) ----------------
// grid (64 qblocks of 32 rows, 4 heads); 2 waves, wave owns 16 q rows, KBLK=64.
// ctx written seq-major [2048][512] (cols = hh*128 + d) for the out-proj GEMM.
__global__ __launch_bounds__(128) void k_attn(
    const short* __restrict__ Qh, const short* __restrict__ Kh,
    const short* __restrict__ Vt, short* __restrict__ ctxp)
{
    __shared__ __align__(16) short Kls[64 * 128];   // swizzled [k][d]
    __shared__ __align__(16) short Vls[128 * 64];   // swizzled [d][k]
    __shared__ __align__(16) short Pls[2][16 * 64]; // per-wave swizzled [q][k]
    const int hh = blockIdx.y;
    const size_t base = (size_t)hh * 2048 * 128;
    const int w = threadIdx.x >> 6, lane = threadIdx.x & 63;
    const int g = lane >> 4, li = lane & 15;
    const int q0 = blockIdx.x * 32;
    const int qw = q0 + w * 16;

    s16x8 qf[4];
    #pragma unroll
    for (int ks = 0; ks < 4; ++ks)
        qf[ks] = *(const s16x8*)(Qh + base + (size_t)(qw + li) * 128 + ks * 32 + g * 8);

    f32x4 acc[8] = {};
    float mrow[4] = { -1e30f, -1e30f, -1e30f, -1e30f };
    float lrow[4] = { 0.f, 0.f, 0.f, 0.f };

    for (int kt = 0; kt < 32; ++kt) {
        __syncthreads();
        #pragma unroll
        for (int c2 = 0; c2 < 8; ++c2) {   // K tile 64x128, swizzled write
            int ci = threadIdx.x + c2 * 128;       // 0..1023
            int row = ci >> 4, cc = ci & 15;
            *(uint4*)&Kls[row * 128 + ((cc ^ (row & 7)) * 8)] =
                *(const uint4*)(Kh + base + (size_t)(kt * 64 + row) * 128 + cc * 8);
        }
        #pragma unroll
        for (int c2 = 0; c2 < 8; ++c2) {   // V^T tile 128x64, swizzled write
            int ci = threadIdx.x + c2 * 128;
            int d = ci >> 3, jc = ci & 7;
            *(uint4*)&Vls[d * 64 + ((jc ^ (d & 7)) * 8)] =
                *(const uint4*)(Vt + ((size_t)hh * 128 + d) * 2048 + kt * 64 + jc * 8);
        }
        __syncthreads();

        // S tile [16 q][64 k] = Q K^T (Q pre-scaled)
        f32x4 st[4];
        #pragma unroll
        for (int nt = 0; nt < 4; ++nt) {
            st[nt] = (f32x4){0.f, 0.f, 0.f, 0.f};
            #pragma unroll
            for (int ks = 0; ks < 4; ++ks) {
                s16x8 bfr = *(const s16x8*)&Kls[(nt * 16 + li) * 128
                                                + (((ks * 4 + g) ^ (li & 7)) * 8)];
                mfma_bf16(&st[nt], qf[ks], bfr);
            }
        }

        // online softmax: row (g*4+r) spread over 16 lanes (li) x 4 regs (nt)
        #pragma unroll
        for (int r = 0; r < 4; ++r) {
            float mx = fmaxf(fmaxf(st[0][r], st[1][r]), fmaxf(st[2][r], st[3][r]));
            mx = fmaxf(mx, __shfl_xor(mx, 1));
            mx = fmaxf(mx, __shfl_xor(mx, 2));
            mx = fmaxf(mx, __shfl_xor(mx, 4));
            mx = fmaxf(mx, __shfl_xor(mx, 8));
            float mnew = fmaxf(mrow[r], mx);
            float alpha = __expf(mrow[r] - mnew);
            float rs = 0.f;
            #pragma unroll
            for (int nt = 0; nt < 4; ++nt) {
                float p = __expf(st[nt][r] - mnew);
                st[nt][r] = p;
                rs += p;
            }
            rs += __shfl_xor(rs, 1);
            rs += __shfl_xor(rs, 2);
            rs += __shfl_xor(rs, 4);
            rs += __shfl_xor(rs, 8);
            lrow[r] = lrow[r] * alpha + rs;
            mrow[r] = mnew;
            #pragma unroll
            for (int dt = 0; dt < 8; ++dt) acc[dt][r] *= alpha;
        }

        // P -> swizzled per-wave LDS, then PV (vector B-fragments)
        short* pw = Pls[w];
        #pragma unroll
        for (int nt = 0; nt < 4; ++nt)
            #pragma unroll
            for (int r = 0; r < 4; ++r) {
                int row = g * 4 + r;
                pw[row * 64 + (((nt * 2 + (li >> 3)) ^ (row & 7)) * 8) + (li & 7)]
                    = f2bf(st[nt][r]);
            }
        #pragma unroll
        for (int kk = 0; kk < 2; ++kk) {
            s16x8 af = *(const s16x8*)&pw[li * 64 + (((kk * 4 + g) ^ (li & 7)) * 8)];
            #pragma unroll
            for (int dt = 0; dt < 8; ++dt) {
                s16x8 bfr = *(const s16x8*)&Vls[(dt * 16 + li) * 64
                                                + (((kk * 4 + g) ^ (li & 7)) * 8)];
                mfma_bf16(&acc[dt], af, bfr);
            }
        }
    }
    #pragma unroll
    for (int r = 0; r < 4; ++r) {
        float inv = 1.f / lrow[r];
        int row = q0 + w * 16 + g * 4 + r;
        #pragma unroll
        for (int dt = 0; dt < 8; ++dt)
            ctxp[(size_t)row * 512 + hh * 128 + dt * 16 + li] =
                f2bf(acc[dt][r] * inv);
    }
}

// ---------------- K-split GEMM accumulate: C += A[.][kslice] @ WT^T --------
// A [rows][lda] bf16, WT [128][ldw] bf16, C [rows][128] f32 (pre-zeroed).
__global__ __launch_bounds__(128) void k_gemmacc(
    const short* __restrict__ A, int lda, const short* __restrict__ WT, int ldw,
    float* __restrict__ C)
{
    const int w = threadIdx.x >> 6, lane = threadIdx.x & 63;
    const int g = lane >> 4, li = lane & 15;
    const int m0 = blockIdx.x * 32 + w * 16;
    const int k0 = blockIdx.y * 512;
    f32x4 acc[8] = {};
    for (int ks = 0; ks < 16; ++ks) {
        s16x8 a = *(const s16x8*)(A + (size_t)(m0 + li) * lda + k0 + ks * 32 + g * 8);
        #pragma unroll
        for (int nt = 0; nt < 8; ++nt) {
            s16x8 bfr = *(const s16x8*)(WT + (size_t)(nt * 16 + li) * ldw
                                           + k0 + ks * 32 + g * 8);
            mfma_bf16(&acc[nt], a, bfr);
        }
    }
    #pragma unroll
    for (int nt = 0; nt < 8; ++nt)
        #pragma unroll
        for (int r = 0; r < 4; ++r)
            atomicAdd(&C[(size_t)(m0 + g * 4 + r) * 128 + nt * 16 + li], acc[nt][r]);
}

// ---------------- out[r] = LayerNorm(base[r]+delta[r]) * g (audited) -------
__global__ __launch_bounds__(128) void k_addln(const float* __restrict__ base,
                                               const float* __restrict__ delta,
                                               const float* __restrict__ g,
                                               float* __restrict__ out) {
    __shared__ float r1[128], r2[128];
    int r = blockIdx.x, t = threadIdx.x;
    float v = base[(size_t)r * 128 + t] + delta[(size_t)r * 128 + t];
    r1[t] = v; r2[t] = v * v; __syncthreads();
    for (int s = 64; s > 0; s >>= 1) {
        if (t < s) { r1[t] += r1[t + s]; r2[t] += r2[t + s]; }
        __syncthreads();
    }
    float mean = r1[0] * (1.f / 128.f);
    float var  = r2[0] * (1.f / 128.f) - mean * mean;
    out[(size_t)r * 128 + t] = (v - mean) * rsqrtf(var + 1e-5f) * g[t];
}

// ---------------- FFN1: H = relu(x1 @ W1), 1024-row chunk ------------------
__global__ __launch_bounds__(256) void k_ffn1(
    const float* __restrict__ x1, const short* __restrict__ W1T,
    short* __restrict__ H)
{
    const int w = threadIdx.x >> 6, lane = threadIdx.x & 63;
    const int g = lane >> 4, li = lane & 15;
    const int m0 = blockIdx.x * 64 + w * 16;
    const int n0 = blockIdx.y * 64;
    f32x4 acc[4] = {};
    #pragma unroll
    for (int ks = 0; ks < 4; ++ks) {
        const float* xr = x1 + (size_t)(m0 + li) * 128 + ks * 32 + g * 8;
        float4 v0 = *(const float4*)xr, v1 = *(const float4*)(xr + 4);
        s16x8 a = { f2bf(v0.x), f2bf(v0.y), f2bf(v0.z), f2bf(v0.w),
                    f2bf(v1.x), f2bf(v1.y), f2bf(v1.z), f2bf(v1.w) };
        #pragma unroll
        for (int nt = 0; nt < 4; ++nt) {
            s16x8 bfr = *(const s16x8*)(W1T + (size_t)(n0 + nt * 16 + li) * 128
                                            + ks * 32 + g * 8);
            mfma_bf16(&acc[nt], a, bfr);
        }
    }
    #pragma unroll
    for (int nt = 0; nt < 4; ++nt)
        #pragma unroll
        for (int r = 0; r < 4; ++r)
            H[(size_t)(m0 + g * 4 + r) * 2048 + n0 + nt * 16 + li] =
                f2bf(fmaxf(acc[nt][r], 0.f));
}

// ---------------------------------------------------------------------------
extern "C" void kernel_launch(void* const* d_in, const int* in_sizes, int n_in,
                              void* d_out, int out_size, void* d_ws, size_t ws_size,
                              hipStream_t stream)
{
    const float* x  = (const float*)d_in[0];
    const float* Wq = (const float*)d_in[1];
    const float* Wk = (const float*)d_in[2];
    const float* Wv = (const float*)d_in[3];
    const float* Wo = (const float*)d_in[4];
    const float* W1 = (const float*)d_in[5];
    const float* W2 = (const float*)d_in[6];
    const float* g1 = (const float*)d_in[7];
    const float* g2 = (const float*)d_in[8];
    float* out = (float*)d_out;
    (void)in_sizes; (void)n_in; (void)out_size; (void)ws_size;

    char* basep = (char*)d_ws;
    size_t off = 0;
    auto carve = [&](size_t bytes) {
        void* q = basep + off;
        off += (bytes + 255) & ~(size_t)255;
        return q;
    };
    // total 10.8 MB (proven-safe: 9-10.8 MB green in r4/r8/r9)
    short* WqT = (short*)carve(1024ull * 128 * 2);       // 256 KB
    short* WkT = (short*)carve(1024ull * 128 * 2);
    short* WvT = (short*)carve(1024ull * 128 * 2);
    short* WoT = (short*)carve(128ull * 1024 * 2);       // 256 KB
    short* W1T = (short*)carve(2048ull * 128 * 2);       // 512 KB
    short* W2T = (short*)carve(128ull * 2048 * 2);       // 512 KB
    short* Qh  = (short*)carve(4ull * 2048 * 128 * 2);   // 2 MB (4 heads/pass)
    short* Kh  = (short*)carve(4ull * 2048 * 128 * 2);   // 2 MB
    short* Vt  = (short*)carve(4ull * 128 * 2048 * 2);   // 2 MB (transposed)
    short* ctxp= (short*)carve(2048ull * 512 * 2);       // 2 MB [s][512] per pass
    float* sab = (float*)carve(2048ull * 128 * 4);       // 1 MB
    short* H   = Qh;            // FFN1 chunk [1024][2048] bf16 = 4 MB over Qh+Kh
    float* ffb = sab;           // FFN2 accumulator aliases sab

    // weight prep
    k_transpose_w<<<512,  256, 0, stream>>>(Wq, WqT, 128, 10);
    k_transpose_w<<<512,  256, 0, stream>>>(Wk, WkT, 128, 10);
    k_transpose_w<<<512,  256, 0, stream>>>(Wv, WvT, 128, 10);
    k_transpose_w<<<512,  256, 0, stream>>>(Wo, WoT, 1024, 7);
    k_transpose_w<<<1024, 256, 0, stream>>>(W1, W1T, 128, 11);
    k_transpose_w<<<1024, 256, 0, stream>>>(W2, W2T, 2048, 7);

    for (int b = 0; b < 4; ++b) {
        const float* xb = x + (size_t)b * 2048 * 128;
        float* x1b = out + (size_t)b * 2048 * 128;   // x1 lives in d_out rows

        // ---- attention + out-proj ----
        k_zero<<<1024, 256, 0, stream>>>(sab);
        for (int hp = 0; hp < 2; ++hp) {
            k_qkv<<<dim3(32, 8, 3), 256, 0, stream>>>(xb, WqT, WkT, WvT,
                                                      Qh, Kh, Vt, hp);
            k_attn<<<dim3(64, 4), 128, 0, stream>>>(Qh, Kh, Vt, ctxp);
            // sab += ctxp @ Wo[hp*512:(hp+1)*512, :]
            k_gemmacc<<<dim3(64, 1), 128, 0, stream>>>(ctxp, 512,
                                                       WoT + hp * 512, 1024, sab);
        }
        k_addln<<<2048, 128, 0, stream>>>(xb, sab, g1, x1b);

        // ---- FFN ----
        k_zero<<<1024, 256, 0, stream>>>(ffb);
        for (int c = 0; c < 2; ++c) {
            k_ffn1<<<dim3(16, 32), 256, 0, stream>>>(x1b + (size_t)c * 1024 * 128,
                                                     W1T, H);
            k_gemmacc<<<dim3(32, 4), 128, 0, stream>>>(H, 2048, W2T, 2048,
                                                       ffb + (size_t)c * 1024 * 128);
        }
        k_addln<<<2048, 128, 0, stream>>>(x1b, ffb, g2, x1b);
    }
}

// Round 11
// 1148.115 us; speedup vs baseline: 1.9552x; 1.9552x over previous
//
#include <hip/hip_runtime.h>
#include <stdint.h>

// ---------------------------------------------------------------------------
// TransformerEncoderLayer: b=4 s=2048 d=128 h=8 (head_dim=128) dff=2048
// Round-11: latency attack on k_attn (r10 post-mortem: latency-bound, not
// conflict-bound).
//  1. V^T stored TILE-BLOCKED [hh][kt][d][64] -> staging reads fully coalesced
//  2. whole-batch passes: k_attn grid 64x8=512 blocks -> 2 blocks/CU
//  3. T14 prefetch: next-tile global->reg loads issued before compute
// Swizzles, fragment math, FFN path byte-identical to r10 (green).
// ---------------------------------------------------------------------------

using f32x4 = __attribute__((ext_vector_type(4))) float;
using s16x8 = __attribute__((ext_vector_type(8))) short;
using s16x4 = __attribute__((ext_vector_type(4))) short;
typedef __bf16 bf16x8 __attribute__((ext_vector_type(8)));

__device__ inline void mfma_bf16(f32x4* acc, s16x8 a, s16x8 b) {
    *acc = __builtin_amdgcn_mfma_f32_16x16x32_bf16(
        __builtin_bit_cast(bf16x8, a), __builtin_bit_cast(bf16x8, b), *acc, 0, 0, 0);
}

__device__ inline short f2bf(float f) {   // RNE f32 -> bf16 bits
    uint32_t u = __builtin_bit_cast(uint32_t, f);
    u += 0x7fffu + ((u >> 16) & 1u);
    return (short)(u >> 16);
}

// ---------------- zero an f32 buffer (graph-safe) --------------------------
__global__ __launch_bounds__(256) void k_zero(float* __restrict__ p) {
    p[blockIdx.x * 256 + threadIdx.x] = 0.f;
}

// ---------------- weight transpose: w [R][C] f32 (C=1<<lc) -> wt [C][R] bf16
__global__ __launch_bounds__(256) void k_transpose_w(const float* __restrict__ w,
                                                     short* __restrict__ wt,
                                                     int R, int lc) {
    int i = blockIdx.x * 256 + threadIdx.x;
    int r = i >> lc, c = i & ((1 << lc) - 1);
    wt[c * R + r] = f2bf(w[i]);
}

// ---------------- QKV projection (one batch, ALL 8 heads) ------------------
// Q (pre-scaled 1/sqrt(d)), K row-major [h8][2048][128];
// V tile-blocked [h8][kt32][d128][s64].
__global__ __launch_bounds__(256) void k_qkv(
    const float* __restrict__ xB, const short* __restrict__ WqT,
    const short* __restrict__ WkT, const short* __restrict__ WvT,
    short* __restrict__ Qh, short* __restrict__ Kh, short* __restrict__ Vt)
{
    const int z = blockIdx.z;
    const short* __restrict__ WT = (z == 0) ? WqT : (z == 1) ? WkT : WvT; // [1024][128]
    const int w = threadIdx.x >> 6, lane = threadIdx.x & 63;
    const int g = lane >> 4, li = lane & 15;
    const int m0 = blockIdx.x * 64 + w * 16;
    const int n0 = blockIdx.y * 64;               // 0..960
    f32x4 acc[4] = {};
    #pragma unroll
    for (int ks = 0; ks < 4; ++ks) {
        const float* xr = xB + (size_t)(m0 + li) * 128 + ks * 32 + g * 8;
        float4 v0 = *(const float4*)xr, v1 = *(const float4*)(xr + 4);
        s16x8 a = { f2bf(v0.x), f2bf(v0.y), f2bf(v0.z), f2bf(v0.w),
                    f2bf(v1.x), f2bf(v1.y), f2bf(v1.z), f2bf(v1.w) };
        #pragma unroll
        for (int nt = 0; nt < 4; ++nt) {
            s16x8 bfr = *(const s16x8*)(WT + (size_t)(n0 + nt * 16 + li) * 128
                                           + ks * 32 + g * 8);
            mfma_bf16(&acc[nt], a, bfr);
        }
    }
    const float sc = (z == 0) ? 0.088388347648318447f : 1.0f; // 1/sqrt(128) into Q
    #pragma unroll
    for (int nt = 0; nt < 4; ++nt) {
        int col = n0 + nt * 16 + li;              // 0..1023
        int hh = col >> 7, dd = col & 127;        // head, dim
        if (z == 2) {
            int row0 = m0 + g * 4;                // s, multiple of 4
            int kt = row0 >> 6, so = row0 & 63;
            s16x4 o = { f2bf(acc[nt][0]), f2bf(acc[nt][1]),
                        f2bf(acc[nt][2]), f2bf(acc[nt][3]) };
            *(s16x4*)(Vt + (((size_t)hh * 32 + kt) * 128 + dd) * 64 + so) = o;
        } else {
            short* __restrict__ dst = (z == 0) ? Qh : Kh;
            #pragma unroll
            for (int r = 0; r < 4; ++r)
                dst[((size_t)hh * 2048 + m0 + g * 4 + r) * 128 + dd] =
                    f2bf(acc[nt][r] * sc);
        }
    }
}

// ---------------- flash attention (swizzled LDS + prefetch) ----------------
// grid (64 qblocks of 32 rows, 8 heads) = 512 blocks, 2/CU; 2 waves/block.
// ctx written seq-major [2048][1024] for the out-proj GEMM.
__global__ __launch_bounds__(128) void k_attn(
    const short* __restrict__ Qh, const short* __restrict__ Kh,
    const short* __restrict__ Vt, short* __restrict__ ctxp)
{
    __shared__ __align__(16) short Kls[64 * 128];   // swizzled [k][d]
    __shared__ __align__(16) short Vls[128 * 64];   // swizzled [d][k]
    __shared__ __align__(16) short Pls[2][16 * 64]; // per-wave swizzled [q][k]
    const int hh = blockIdx.y;
    const size_t base  = (size_t)hh * 2048 * 128;
    const size_t vbase = (size_t)hh * 32 * 8192;    // tile-blocked V^T
    const int w = threadIdx.x >> 6, lane = threadIdx.x & 63;
    const int g = lane >> 4, li = lane & 15;
    const int q0 = blockIdx.x * 32;
    const int qw = q0 + w * 16;

    s16x8 qf[4];
    #pragma unroll
    for (int ks = 0; ks < 4; ++ks)
        qf[ks] = *(const s16x8*)(Qh + base + (size_t)(qw + li) * 128 + ks * 32 + g * 8);

    f32x4 acc[8] = {};
    float mrow[4] = { -1e30f, -1e30f, -1e30f, -1e30f };
    float lrow[4] = { 0.f, 0.f, 0.f, 0.f };

    uint4 kreg[8], vreg[8];
    #define LOAD_TILES(KT)                                                        \
        _Pragma("unroll")                                                         \
        for (int c2 = 0; c2 < 8; ++c2) {                                          \
            int ci = threadIdx.x + c2 * 128;                                      \
            int row = ci >> 4, cc = ci & 15;                                      \
            kreg[c2] = *(const uint4*)(Kh + base + (size_t)((KT) * 64 + row) * 128\
                                          + cc * 8);                              \
            vreg[c2] = *(const uint4*)(Vt + vbase + (size_t)(KT) * 8192 + ci * 8);\
        }

    LOAD_TILES(0);
    for (int kt = 0; kt < 32; ++kt) {
        __syncthreads();                 // previous tile's LDS reads complete
        #pragma unroll
        for (int c2 = 0; c2 < 8; ++c2) { // staged regs -> swizzled LDS
            int ci = threadIdx.x + c2 * 128;
            int row = ci >> 4, cc = ci & 15;
            *(uint4*)&Kls[row * 128 + ((cc ^ (row & 7)) * 8)] = kreg[c2];
            int d = ci >> 3, jc = ci & 7;
            *(uint4*)&Vls[d * 64 + ((jc ^ (d & 7)) * 8)] = vreg[c2];
        }
        __syncthreads();
        if (kt + 1 < 32) LOAD_TILES(kt + 1);  // in flight during compute

        // S tile [16 q][64 k] = Q K^T (Q pre-scaled)
        f32x4 st[4];
        #pragma unroll
        for (int nt = 0; nt < 4; ++nt) {
            st[nt] = (f32x4){0.f, 0.f, 0.f, 0.f};
            #pragma unroll
            for (int ks = 0; ks < 4; ++ks) {
                s16x8 bfr = *(const s16x8*)&Kls[(nt * 16 + li) * 128
                                                + (((ks * 4 + g) ^ (li & 7)) * 8)];
                mfma_bf16(&st[nt], qf[ks], bfr);
            }
        }

        // online softmax: row (g*4+r) spread over 16 lanes (li) x 4 regs (nt)
        #pragma unroll
        for (int r = 0; r < 4; ++r) {
            float mx = fmaxf(fmaxf(st[0][r], st[1][r]), fmaxf(st[2][r], st[3][r]));
            mx = fmaxf(mx, __shfl_xor(mx, 1));
            mx = fmaxf(mx, __shfl_xor(mx, 2));
            mx = fmaxf(mx, __shfl_xor(mx, 4));
            mx = fmaxf(mx, __shfl_xor(mx, 8));
            float mnew = fmaxf(mrow[r], mx);
            float alpha = __expf(mrow[r] - mnew);
            float rs = 0.f;
            #pragma unroll
            for (int nt = 0; nt < 4; ++nt) {
                float p = __expf(st[nt][r] - mnew);
                st[nt][r] = p;
                rs += p;
            }
            rs += __shfl_xor(rs, 1);
            rs += __shfl_xor(rs, 2);
            rs += __shfl_xor(rs, 4);
            rs += __shfl_xor(rs, 8);
            lrow[r] = lrow[r] * alpha + rs;
            mrow[r] = mnew;
            #pragma unroll
            for (int dt = 0; dt < 8; ++dt) acc[dt][r] *= alpha;
        }

        // P -> swizzled per-wave LDS, then PV (vector B-fragments)
        short* pw = Pls[w];
        #pragma unroll
        for (int nt = 0; nt < 4; ++nt)
            #pragma unroll
            for (int r = 0; r < 4; ++r) {
                int row = g * 4 + r;
                pw[row * 64 + (((nt * 2 + (li >> 3)) ^ (row & 7)) * 8) + (li & 7)]
                    = f2bf(st[nt][r]);
            }
        #pragma unroll
        for (int kk = 0; kk < 2; ++kk) {
            s16x8 af = *(const s16x8*)&pw[li * 64 + (((kk * 4 + g) ^ (li & 7)) * 8)];
            #pragma unroll
            for (int dt = 0; dt < 8; ++dt) {
                s16x8 bfr = *(const s16x8*)&Vls[(dt * 16 + li) * 64
                                                + (((kk * 4 + g) ^ (li & 7)) * 8)];
                mfma_bf16(&acc[dt], af, bfr);
            }
        }
    }
    #undef LOAD_TILES
    #pragma unroll
    for (int r = 0; r < 4; ++r) {
        float inv = 1.f / lrow[r];
        int row = q0 + w * 16 + g * 4 + r;
        #pragma unroll
        for (int dt = 0; dt < 8; ++dt)
            ctxp[(size_t)row * 1024 + hh * 128 + dt * 16 + li] =
                f2bf(acc[dt][r] * inv);
    }
}

// ---------------- K-split GEMM accumulate: C += A[.][kslice] @ WT^T --------
// A [rows][lda] bf16, WT [128][ldw] bf16, C [rows][128] f32 (pre-zeroed).
__global__ __launch_bounds__(128) void k_gemmacc(
    const short* __restrict__ A, int lda, const short* __restrict__ WT, int ldw,
    float* __restrict__ C)
{
    const int w = threadIdx.x >> 6, lane = threadIdx.x & 63;
    const int g = lane >> 4, li = lane & 15;
    const int m0 = blockIdx.x * 32 + w * 16;
    const int k0 = blockIdx.y * 512;
    f32x4 acc[8] = {};
    for (int ks = 0; ks < 16; ++ks) {
        s16x8 a = *(const s16x8*)(A + (size_t)(m0 + li) * lda + k0 + ks * 32 + g * 8);
        #pragma unroll
        for (int nt = 0; nt < 8; ++nt) {
            s16x8 bfr = *(const s16x8*)(WT + (size_t)(nt * 16 + li) * ldw
                                           + k0 + ks * 32 + g * 8);
            mfma_bf16(&acc[nt], a, bfr);
        }
    }
    #pragma unroll
    for (int nt = 0; nt < 8; ++nt)
        #pragma unroll
        for (int r = 0; r < 4; ++r)
            atomicAdd(&C[(size_t)(m0 + g * 4 + r) * 128 + nt * 16 + li], acc[nt][r]);
}

// ---------------- out[r] = LayerNorm(base[r]+delta[r]) * g (audited) -------
__global__ __launch_bounds__(128) void k_addln(const float* __restrict__ base,
                                               const float* __restrict__ delta,
                                               const float* __restrict__ g,
                                               float* __restrict__ out) {
    __shared__ float r1[128], r2[128];
    int r = blockIdx.x, t = threadIdx.x;
    float v = base[(size_t)r * 128 + t] + delta[(size_t)r * 128 + t];
    r1[t] = v; r2[t] = v * v; __syncthreads();
    for (int s = 64; s > 0; s >>= 1) {
        if (t < s) { r1[t] += r1[t + s]; r2[t] += r2[t + s]; }
        __syncthreads();
    }
    float mean = r1[0] * (1.f / 128.f);
    float var  = r2[0] * (1.f / 128.f) - mean * mean;
    out[(size_t)r * 128 + t] = (v - mean) * rsqrtf(var + 1e-5f) * g[t];
}

// ---------------- FFN1: H = relu(x1 @ W1), 1024-row chunk ------------------
__global__ __launch_bounds__(256) void k_ffn1(
    const float* __restrict__ x1, const short* __restrict__ W1T,
    short* __restrict__ H)
{
    const int w = threadIdx.x >> 6, lane = threadIdx.x & 63;
    const int g = lane >> 4, li = lane & 15;
    const int m0 = blockIdx.x * 64 + w * 16;
    const int n0 = blockIdx.y * 64;
    f32x4 acc[4] = {};
    #pragma unroll
    for (int ks = 0; ks < 4; ++ks) {
        const float* xr = x1 + (size_t)(m0 + li) * 128 + ks * 32 + g * 8;
        float4 v0 = *(const float4*)xr, v1 = *(const float4*)(xr + 4);
        s16x8 a = { f2bf(v0.x), f2bf(v0.y), f2bf(v0.z), f2bf(v0.w),
                    f2bf(v1.x), f2bf(v1.y), f2bf(v1.z), f2bf(v1.w) };
        #pragma unroll
        for (int nt = 0; nt < 4; ++nt) {
            s16x8 bfr = *(const s16x8*)(W1T + (size_t)(n0 + nt * 16 + li) * 128
                                            + ks * 32 + g * 8);
            mfma_bf16(&acc[nt], a, bfr);
        }
    }
    #pragma unroll
    for (int nt = 0; nt < 4; ++nt)
        #pragma unroll
        for (int r = 0; r < 4; ++r)
            H[(size_t)(m0 + g * 4 + r) * 2048 + n0 + nt * 16 + li] =
                f2bf(fmaxf(acc[nt][r], 0.f));
}

// ---------------------------------------------------------------------------
extern "C" void kernel_launch(void* const* d_in, const int* in_sizes, int n_in,
                              void* d_out, int out_size, void* d_ws, size_t ws_size,
                              hipStream_t stream)
{
    const float* x  = (const float*)d_in[0];
    const float* Wq = (const float*)d_in[1];
    const float* Wk = (const float*)d_in[2];
    const float* Wv = (const float*)d_in[3];
    const float* Wo = (const float*)d_in[4];
    const float* W1 = (const float*)d_in[5];
    const float* W2 = (const float*)d_in[6];
    const float* g1 = (const float*)d_in[7];
    const float* g2 = (const float*)d_in[8];
    float* out = (float*)d_out;
    (void)in_sizes; (void)n_in; (void)out_size; (void)ws_size;

    char* basep = (char*)d_ws;
    size_t off = 0;
    auto carve = [&](size_t bytes) {
        void* q = basep + off;
        off += (bytes + 255) & ~(size_t)255;
        return q;
    };
    // total 19.1 MB (green range 9-10.8 MB proven; cliff located at ~45 MB)
    short* WqT = (short*)carve(1024ull * 128 * 2);       // 256 KB
    short* WkT = (short*)carve(1024ull * 128 * 2);
    short* WvT = (short*)carve(1024ull * 128 * 2);
    short* WoT = (short*)carve(128ull * 1024 * 2);       // 256 KB
    short* W1T = (short*)carve(2048ull * 128 * 2);       // 512 KB
    short* W2T = (short*)carve(128ull * 2048 * 2);       // 512 KB
    short* Qh  = (short*)carve(8ull * 2048 * 128 * 2);   // 4 MB (8 heads)
    short* Kh  = (short*)carve(8ull * 2048 * 128 * 2);   // 4 MB
    short* Vt  = (short*)carve(8ull * 32 * 128 * 64 * 2);// 4 MB (tile-blocked)
    short* ctxp= (short*)carve(2048ull * 1024 * 2);      // 4 MB [s][1024]
    float* sab = (float*)carve(2048ull * 128 * 4);       // 1 MB
    short* H   = Qh;            // FFN1 chunk [1024][2048] bf16 = 4 MB over Qh
    float* ffb = sab;           // FFN2 accumulator aliases sab

    // weight prep
    k_transpose_w<<<512,  256, 0, stream>>>(Wq, WqT, 128, 10);
    k_transpose_w<<<512,  256, 0, stream>>>(Wk, WkT, 128, 10);
    k_transpose_w<<<512,  256, 0, stream>>>(Wv, WvT, 128, 10);
    k_transpose_w<<<512,  256, 0, stream>>>(Wo, WoT, 1024, 7);
    k_transpose_w<<<1024, 256, 0, stream>>>(W1, W1T, 128, 11);
    k_transpose_w<<<1024, 256, 0, stream>>>(W2, W2T, 2048, 7);

    for (int b = 0; b < 4; ++b) {
        const float* xb = x + (size_t)b * 2048 * 128;
        float* x1b = out + (size_t)b * 2048 * 128;   // x1 lives in d_out rows

        // ---- attention + out-proj (whole batch, 8 heads) ----
        k_zero<<<1024, 256, 0, stream>>>(sab);
        k_qkv<<<dim3(32, 16, 3), 256, 0, stream>>>(xb, WqT, WkT, WvT, Qh, Kh, Vt);
        k_attn<<<dim3(64, 8), 128, 0, stream>>>(Qh, Kh, Vt, ctxp);
        k_gemmacc<<<dim3(64, 2), 128, 0, stream>>>(ctxp, 1024, WoT, 1024, sab);
        k_addln<<<2048, 128, 0, stream>>>(xb, sab, g1, x1b);

        // ---- FFN ----
        k_zero<<<1024, 256, 0, stream>>>(ffb);
        for (int c = 0; c < 2; ++c) {
            k_ffn1<<<dim3(16, 32), 256, 0, stream>>>(x1b + (size_t)c * 1024 * 128,
                                                     W1T, H);
            k_gemmacc<<<dim3(32, 4), 128, 0, stream>>>(H, 2048, W2T, 2048,
                                                       ffb + (size_t)c * 1024 * 128);
        }
        k_addln<<<2048, 128, 0, stream>>>(x1b, ffb, g2, x1b);
    }
}

// Round 12
// 1110.832 us; speedup vs baseline: 2.0208x; 1.0336x over previous
//
#include <hip/hip_runtime.h>
#include <stdint.h>

// ---------------------------------------------------------------------------
// TransformerEncoderLayer: b=4 s=2048 d=128 h=8 (head_dim=128) dff=2048
// Round-12: attention occupancy + spill fix (r11 post-mortem: 234MB/dispatch
// scratch spill of the prefetch regs; grid-limited at 2 blocks/CU).
//  1. __launch_bounds__(128, 2): VGPR cap 256 -> K+V prefetch fits, no spill
//  2. kv-split x2 (flash-decoding): grid (64,8,2)=1024 blocks -> 4 blocks/CU,
//     each half emits unnormalized O + per-row (m,l)
//  3. k_combine merges halves in-place (vectorized, ~10us)
// Everything outside attention byte-identical to r11 (green).
// ---------------------------------------------------------------------------

using f32x4 = __attribute__((ext_vector_type(4))) float;
using s16x8 = __attribute__((ext_vector_type(8))) short;
using s16x4 = __attribute__((ext_vector_type(4))) short;
typedef __bf16 bf16x8 __attribute__((ext_vector_type(8)));

__device__ inline void mfma_bf16(f32x4* acc, s16x8 a, s16x8 b) {
    *acc = __builtin_amdgcn_mfma_f32_16x16x32_bf16(
        __builtin_bit_cast(bf16x8, a), __builtin_bit_cast(bf16x8, b), *acc, 0, 0, 0);
}

__device__ inline short f2bf(float f) {   // RNE f32 -> bf16 bits
    uint32_t u = __builtin_bit_cast(uint32_t, f);
    u += 0x7fffu + ((u >> 16) & 1u);
    return (short)(u >> 16);
}

__device__ inline float bf2f(short s) {
    return __builtin_bit_cast(float, (uint32_t)((uint16_t)s) << 16);
}

// ---------------- zero an f32 buffer (graph-safe) --------------------------
__global__ __launch_bounds__(256) void k_zero(float* __restrict__ p) {
    p[blockIdx.x * 256 + threadIdx.x] = 0.f;
}

// ---------------- weight transpose: w [R][C] f32 (C=1<<lc) -> wt [C][R] bf16
__global__ __launch_bounds__(256) void k_transpose_w(const float* __restrict__ w,
                                                     short* __restrict__ wt,
                                                     int R, int lc) {
    int i = blockIdx.x * 256 + threadIdx.x;
    int r = i >> lc, c = i & ((1 << lc) - 1);
    wt[c * R + r] = f2bf(w[i]);
}

// ---------------- QKV projection (one batch, ALL 8 heads) ------------------
// Q (pre-scaled 1/sqrt(d)), K row-major [h8][2048][128];
// V tile-blocked [h8][kt32][d128][s64].
__global__ __launch_bounds__(256) void k_qkv(
    const float* __restrict__ xB, const short* __restrict__ WqT,
    const short* __restrict__ WkT, const short* __restrict__ WvT,
    short* __restrict__ Qh, short* __restrict__ Kh, short* __restrict__ Vt)
{
    const int z = blockIdx.z;
    const short* __restrict__ WT = (z == 0) ? WqT : (z == 1) ? WkT : WvT; // [1024][128]
    const int w = threadIdx.x >> 6, lane = threadIdx.x & 63;
    const int g = lane >> 4, li = lane & 15;
    const int m0 = blockIdx.x * 64 + w * 16;
    const int n0 = blockIdx.y * 64;               // 0..960
    f32x4 acc[4] = {};
    #pragma unroll
    for (int ks = 0; ks < 4; ++ks) {
        const float* xr = xB + (size_t)(m0 + li) * 128 + ks * 32 + g * 8;
        float4 v0 = *(const float4*)xr, v1 = *(const float4*)(xr + 4);
        s16x8 a = { f2bf(v0.x), f2bf(v0.y), f2bf(v0.z), f2bf(v0.w),
                    f2bf(v1.x), f2bf(v1.y), f2bf(v1.z), f2bf(v1.w) };
        #pragma unroll
        for (int nt = 0; nt < 4; ++nt) {
            s16x8 bfr = *(const s16x8*)(WT + (size_t)(n0 + nt * 16 + li) * 128
                                           + ks * 32 + g * 8);
            mfma_bf16(&acc[nt], a, bfr);
        }
    }
    const float sc = (z == 0) ? 0.088388347648318447f : 1.0f; // 1/sqrt(128) into Q
    #pragma unroll
    for (int nt = 0; nt < 4; ++nt) {
        int col = n0 + nt * 16 + li;              // 0..1023
        int hh = col >> 7, dd = col & 127;        // head, dim
        if (z == 2) {
            int row0 = m0 + g * 4;                // s, multiple of 4
            int kt = row0 >> 6, so = row0 & 63;
            s16x4 o = { f2bf(acc[nt][0]), f2bf(acc[nt][1]),
                        f2bf(acc[nt][2]), f2bf(acc[nt][3]) };
            *(s16x4*)(Vt + (((size_t)hh * 32 + kt) * 128 + dd) * 64 + so) = o;
        } else {
            short* __restrict__ dst = (z == 0) ? Qh : Kh;
            #pragma unroll
            for (int r = 0; r < 4; ++r)
                dst[((size_t)hh * 2048 + m0 + g * 4 + r) * 128 + dd] =
                    f2bf(acc[nt][r] * sc);
        }
    }
}

// ---------------- flash attention, kv-split x2 -----------------------------
// grid (64 qblocks of 32 rows, 8 heads, 2 kv-halves) = 1024 blocks, 4/CU.
// Each half processes 16 kv tiles; emits unnormalized O (bf16) + (m,l)/row.
__global__ __launch_bounds__(128, 2) void k_attn(
    const short* __restrict__ Qh, const short* __restrict__ Kh,
    const short* __restrict__ Vt, short* __restrict__ O0,
    short* __restrict__ O1, float2* __restrict__ ml0, float2* __restrict__ ml1)
{
    __shared__ __align__(16) short Kls[64 * 128];   // swizzled [k][d]
    __shared__ __align__(16) short Vls[128 * 64];   // swizzled [d][k]
    __shared__ __align__(16) short Pls[2][16 * 64]; // per-wave swizzled [q][k]
    const int hh = blockIdx.y;
    const int half = blockIdx.z;
    const size_t base  = (size_t)hh * 2048 * 128;
    const size_t vbase = (size_t)hh * 32 * 8192;    // tile-blocked V^T
    const int w = threadIdx.x >> 6, lane = threadIdx.x & 63;
    const int g = lane >> 4, li = lane & 15;
    const int q0 = blockIdx.x * 32;
    const int qw = q0 + w * 16;
    const int kt0 = half * 16;

    s16x8 qf[4];
    #pragma unroll
    for (int ks = 0; ks < 4; ++ks)
        qf[ks] = *(const s16x8*)(Qh + base + (size_t)(qw + li) * 128 + ks * 32 + g * 8);

    f32x4 acc[8] = {};
    float mrow[4] = { -1e30f, -1e30f, -1e30f, -1e30f };
    float lrow[4] = { 0.f, 0.f, 0.f, 0.f };

    uint4 kreg[8], vreg[8];
    #define LOAD_TILES(KT)                                                        \
        _Pragma("unroll")                                                         \
        for (int c2 = 0; c2 < 8; ++c2) {                                          \
            int ci = threadIdx.x + c2 * 128;                                      \
            int row = ci >> 4, cc = ci & 15;                                      \
            kreg[c2] = *(const uint4*)(Kh + base + (size_t)((KT) * 64 + row) * 128\
                                          + cc * 8);                              \
            vreg[c2] = *(const uint4*)(Vt + vbase + (size_t)(KT) * 8192 + ci * 8);\
        }

    LOAD_TILES(kt0);
    for (int t = 0; t < 16; ++t) {
        __syncthreads();                 // previous tile's LDS reads complete
        #pragma unroll
        for (int c2 = 0; c2 < 8; ++c2) { // staged regs -> swizzled LDS
            int ci = threadIdx.x + c2 * 128;
            int row = ci >> 4, cc = ci & 15;
            *(uint4*)&Kls[row * 128 + ((cc ^ (row & 7)) * 8)] = kreg[c2];
            int d = ci >> 3, jc = ci & 7;
            *(uint4*)&Vls[d * 64 + ((jc ^ (d & 7)) * 8)] = vreg[c2];
        }
        __syncthreads();
        if (t + 1 < 16) LOAD_TILES(kt0 + t + 1);  // in flight during compute

        // S tile [16 q][64 k] = Q K^T (Q pre-scaled)
        f32x4 st[4];
        #pragma unroll
        for (int nt = 0; nt < 4; ++nt) {
            st[nt] = (f32x4){0.f, 0.f, 0.f, 0.f};
            #pragma unroll
            for (int ks = 0; ks < 4; ++ks) {
                s16x8 bfr = *(const s16x8*)&Kls[(nt * 16 + li) * 128
                                                + (((ks * 4 + g) ^ (li & 7)) * 8)];
                mfma_bf16(&st[nt], qf[ks], bfr);
            }
        }

        // online softmax: row (g*4+r) spread over 16 lanes (li) x 4 regs (nt)
        #pragma unroll
        for (int r = 0; r < 4; ++r) {
            float mx = fmaxf(fmaxf(st[0][r], st[1][r]), fmaxf(st[2][r], st[3][r]));
            mx = fmaxf(mx, __shfl_xor(mx, 1));
            mx = fmaxf(mx, __shfl_xor(mx, 2));
            mx = fmaxf(mx, __shfl_xor(mx, 4));
            mx = fmaxf(mx, __shfl_xor(mx, 8));
            float mnew = fmaxf(mrow[r], mx);
            float alpha = __expf(mrow[r] - mnew);
            float rs = 0.f;
            #pragma unroll
            for (int nt = 0; nt < 4; ++nt) {
                float p = __expf(st[nt][r] - mnew);
                st[nt][r] = p;
                rs += p;
            }
            rs += __shfl_xor(rs, 1);
            rs += __shfl_xor(rs, 2);
            rs += __shfl_xor(rs, 4);
            rs += __shfl_xor(rs, 8);
            lrow[r] = lrow[r] * alpha + rs;
            mrow[r] = mnew;
            #pragma unroll
            for (int dt = 0; dt < 8; ++dt) acc[dt][r] *= alpha;
        }

        // P -> swizzled per-wave LDS, then PV (vector B-fragments)
        short* pw = Pls[w];
        #pragma unroll
        for (int nt = 0; nt < 4; ++nt)
            #pragma unroll
            for (int r = 0; r < 4; ++r) {
                int row = g * 4 + r;
                pw[row * 64 + (((nt * 2 + (li >> 3)) ^ (row & 7)) * 8) + (li & 7)]
                    = f2bf(st[nt][r]);
            }
        #pragma unroll
        for (int kk = 0; kk < 2; ++kk) {
            s16x8 af = *(const s16x8*)&pw[li * 64 + (((kk * 4 + g) ^ (li & 7)) * 8)];
            #pragma unroll
            for (int dt = 0; dt < 8; ++dt) {
                s16x8 bfr = *(const s16x8*)&Vls[(dt * 16 + li) * 64
                                                + (((kk * 4 + g) ^ (li & 7)) * 8)];
                mfma_bf16(&acc[dt], af, bfr);
            }
        }
    }
    #undef LOAD_TILES

    short* __restrict__ Op = half ? O1 : O0;
    float2* __restrict__ mlp = half ? ml1 : ml0;
    #pragma unroll
    for (int r = 0; r < 4; ++r) {
        int row = q0 + w * 16 + g * 4 + r;
        if (li == 0) mlp[hh * 2048 + row] = make_float2(mrow[r], lrow[r]);
        #pragma unroll
        for (int dt = 0; dt < 8; ++dt)
            Op[(size_t)row * 1024 + hh * 128 + dt * 16 + li] = f2bf(acc[dt][r]);
    }
}

// ---------------- combine kv-split halves (in-place on O0 -> ctx) ----------
// grid 1024 x 256 thr; each thread merges 8 consecutive cols of one row.
__global__ __launch_bounds__(256) void k_combine(
    short* __restrict__ O0, const short* __restrict__ O1,
    const float2* __restrict__ ml0, const float2* __restrict__ ml1)
{
    int idx = (blockIdx.x * 256 + threadIdx.x) * 8;   // over 2048*1024
    int row = idx >> 10, col = idx & 1023, h = col >> 7;
    float2 a = ml0[h * 2048 + row], b = ml1[h * 2048 + row];
    float M = fmaxf(a.x, b.x);
    float w0 = __expf(a.x - M), w1 = __expf(b.x - M);
    float invL = 1.f / (a.y * w0 + b.y * w1);
    s16x8 v0 = *(const s16x8*)(O0 + idx);
    s16x8 v1 = *(const s16x8*)(O1 + idx);
    s16x8 o;
    #pragma unroll
    for (int e = 0; e < 8; ++e)
        o[e] = f2bf((bf2f(v0[e]) * w0 + bf2f(v1[e]) * w1) * invL);
    *(s16x8*)(O0 + idx) = o;
}

// ---------------- K-split GEMM accumulate: C += A[.][kslice] @ WT^T --------
// A [rows][lda] bf16, WT [128][ldw] bf16, C [rows][128] f32 (pre-zeroed).
__global__ __launch_bounds__(128) void k_gemmacc(
    const short* __restrict__ A, int lda, const short* __restrict__ WT, int ldw,
    float* __restrict__ C)
{
    const int w = threadIdx.x >> 6, lane = threadIdx.x & 63;
    const int g = lane >> 4, li = lane & 15;
    const int m0 = blockIdx.x * 32 + w * 16;
    const int k0 = blockIdx.y * 512;
    f32x4 acc[8] = {};
    for (int ks = 0; ks < 16; ++ks) {
        s16x8 a = *(const s16x8*)(A + (size_t)(m0 + li) * lda + k0 + ks * 32 + g * 8);
        #pragma unroll
        for (int nt = 0; nt < 8; ++nt) {
            s16x8 bfr = *(const s16x8*)(WT + (size_t)(nt * 16 + li) * ldw
                                           + k0 + ks * 32 + g * 8);
            mfma_bf16(&acc[nt], a, bfr);
        }
    }
    #pragma unroll
    for (int nt = 0; nt < 8; ++nt)
        #pragma unroll
        for (int r = 0; r < 4; ++r)
            atomicAdd(&C[(size_t)(m0 + g * 4 + r) * 128 + nt * 16 + li], acc[nt][r]);
}

// ---------------- out[r] = LayerNorm(base[r]+delta[r]) * g (audited) -------
__global__ __launch_bounds__(128) void k_addln(const float* __restrict__ base,
                                               const float* __restrict__ delta,
                                               const float* __restrict__ g,
                                               float* __restrict__ out) {
    __shared__ float r1[128], r2[128];
    int r = blockIdx.x, t = threadIdx.x;
    float v = base[(size_t)r * 128 + t] + delta[(size_t)r * 128 + t];
    r1[t] = v; r2[t] = v * v; __syncthreads();
    for (int s = 64; s > 0; s >>= 1) {
        if (t < s) { r1[t] += r1[t + s]; r2[t] += r2[t + s]; }
        __syncthreads();
    }
    float mean = r1[0] * (1.f / 128.f);
    float var  = r2[0] * (1.f / 128.f) - mean * mean;
    out[(size_t)r * 128 + t] = (v - mean) * rsqrtf(var + 1e-5f) * g[t];
}

// ---------------- FFN1: H = relu(x1 @ W1), 1024-row chunk ------------------
__global__ __launch_bounds__(256) void k_ffn1(
    const float* __restrict__ x1, const short* __restrict__ W1T,
    short* __restrict__ H)
{
    const int w = threadIdx.x >> 6, lane = threadIdx.x & 63;
    const int g = lane >> 4, li = lane & 15;
    const int m0 = blockIdx.x * 64 + w * 16;
    const int n0 = blockIdx.y * 64;
    f32x4 acc[4] = {};
    #pragma unroll
    for (int ks = 0; ks < 4; ++ks) {
        const float* xr = x1 + (size_t)(m0 + li) * 128 + ks * 32 + g * 8;
        float4 v0 = *(const float4*)xr, v1 = *(const float4*)(xr + 4);
        s16x8 a = { f2bf(v0.x), f2bf(v0.y), f2bf(v0.z), f2bf(v0.w),
                    f2bf(v1.x), f2bf(v1.y), f2bf(v1.z), f2bf(v1.w) };
        #pragma unroll
        for (int nt = 0; nt < 4; ++nt) {
            s16x8 bfr = *(const s16x8*)(W1T + (size_t)(n0 + nt * 16 + li) * 128
                                            + ks * 32 + g * 8);
            mfma_bf16(&acc[nt], a, bfr);
        }
    }
    #pragma unroll
    for (int nt = 0; nt < 4; ++nt)
        #pragma unroll
        for (int r = 0; r < 4; ++r)
            H[(size_t)(m0 + g * 4 + r) * 2048 + n0 + nt * 16 + li] =
                f2bf(fmaxf(acc[nt][r], 0.f));
}

// ---------------------------------------------------------------------------
extern "C" void kernel_launch(void* const* d_in, const int* in_sizes, int n_in,
                              void* d_out, int out_size, void* d_ws, size_t ws_size,
                              hipStream_t stream)
{
    const float* x  = (const float*)d_in[0];
    const float* Wq = (const float*)d_in[1];
    const float* Wk = (const float*)d_in[2];
    const float* Wv = (const float*)d_in[3];
    const float* Wo = (const float*)d_in[4];
    const float* W1 = (const float*)d_in[5];
    const float* W2 = (const float*)d_in[6];
    const float* g1 = (const float*)d_in[7];
    const float* g2 = (const float*)d_in[8];
    float* out = (float*)d_out;
    (void)in_sizes; (void)n_in; (void)out_size; (void)ws_size;

    char* basep = (char*)d_ws;
    size_t off = 0;
    auto carve = [&](size_t bytes) {
        void* q = basep + off;
        off += (bytes + 255) & ~(size_t)255;
        return q;
    };
    // total ~23.3 MB (green proven to 19.1; hard failure located at ~45)
    short*  WqT = (short*)carve(1024ull * 128 * 2);       // 256 KB
    short*  WkT = (short*)carve(1024ull * 128 * 2);
    short*  WvT = (short*)carve(1024ull * 128 * 2);
    short*  WoT = (short*)carve(128ull * 1024 * 2);       // 256 KB
    short*  W1T = (short*)carve(2048ull * 128 * 2);       // 512 KB
    short*  W2T = (short*)carve(128ull * 2048 * 2);       // 512 KB
    short*  Qh  = (short*)carve(8ull * 2048 * 128 * 2);   // 4 MB (8 heads)
    short*  Kh  = (short*)carve(8ull * 2048 * 128 * 2);   // 4 MB
    short*  Vt  = (short*)carve(8ull * 32 * 128 * 64 * 2);// 4 MB (tile-blocked)
    short*  O0  = (short*)carve(2048ull * 1024 * 2);      // 4 MB (-> ctx)
    short*  O1  = (short*)carve(2048ull * 1024 * 2);      // 4 MB
    float2* ml0 = (float2*)carve(8ull * 2048 * 8);        // 128 KB
    float2* ml1 = (float2*)carve(8ull * 2048 * 8);        // 128 KB
    float*  sab = (float*)carve(2048ull * 128 * 4);       // 1 MB
    short*  H   = Qh;           // FFN1 chunk [1024][2048] bf16 = 4 MB over Qh
    float*  ffb = sab;          // FFN2 accumulator aliases sab

    // weight prep
    k_transpose_w<<<512,  256, 0, stream>>>(Wq, WqT, 128, 10);
    k_transpose_w<<<512,  256, 0, stream>>>(Wk, WkT, 128, 10);
    k_transpose_w<<<512,  256, 0, stream>>>(Wv, WvT, 128, 10);
    k_transpose_w<<<512,  256, 0, stream>>>(Wo, WoT, 1024, 7);
    k_transpose_w<<<1024, 256, 0, stream>>>(W1, W1T, 128, 11);
    k_transpose_w<<<1024, 256, 0, stream>>>(W2, W2T, 2048, 7);

    for (int b = 0; b < 4; ++b) {
        const float* xb = x + (size_t)b * 2048 * 128;
        float* x1b = out + (size_t)b * 2048 * 128;   // x1 lives in d_out rows

        // ---- attention + out-proj (whole batch, 8 heads, kv-split x2) ----
        k_zero<<<1024, 256, 0, stream>>>(sab);
        k_qkv<<<dim3(32, 16, 3), 256, 0, stream>>>(xb, WqT, WkT, WvT, Qh, Kh, Vt);
        k_attn<<<dim3(64, 8, 2), 128, 0, stream>>>(Qh, Kh, Vt, O0, O1, ml0, ml1);
        k_combine<<<1024, 256, 0, stream>>>(O0, O1, ml0, ml1);
        k_gemmacc<<<dim3(64, 2), 128, 0, stream>>>(O0, 1024, WoT, 1024, sab);
        k_addln<<<2048, 128, 0, stream>>>(xb, sab, g1, x1b);

        // ---- FFN ----
        k_zero<<<1024, 256, 0, stream>>>(ffb);
        for (int c = 0; c < 2; ++c) {
            k_ffn1<<<dim3(16, 32), 256, 0, stream>>>(x1b + (size_t)c * 1024 * 128,
                                                     W1T, H);
            k_gemmacc<<<dim3(32, 4), 128, 0, stream>>>(H, 2048, W2T, 2048,
                                                       ffb + (size_t)c * 1024 * 128);
        }
        k_addln<<<2048, 128, 0, stream>>>(x1b, ffb, g2, x1b);
    }
}

// Round 13
// 791.015 us; speedup vs baseline: 2.8379x; 1.4043x over previous
//
#include <hip/hip_runtime.h>
#include <stdint.h>

// ---------------------------------------------------------------------------
// TransformerEncoderLayer: b=4 s=2048 d=128 h=8 (head_dim=128) dff=2048
// Round-13: r12 post-mortem showed the reg-prefetch STILL spills (516 MB
// scratch writes/dispatch). Mechanism swap in k_attn only:
//   global_load_lds (16B) + double-buffered LDS, swizzle folded into the
//   per-lane GLOBAL source address (LDS dest stays linear), one barrier/tile.
// Everything else byte-identical to r12 (green).
// ---------------------------------------------------------------------------

using f32x4 = __attribute__((ext_vector_type(4))) float;
using s16x8 = __attribute__((ext_vector_type(8))) short;
using s16x4 = __attribute__((ext_vector_type(4))) short;
typedef __bf16 bf16x8 __attribute__((ext_vector_type(8)));

__device__ inline void mfma_bf16(f32x4* acc, s16x8 a, s16x8 b) {
    *acc = __builtin_amdgcn_mfma_f32_16x16x32_bf16(
        __builtin_bit_cast(bf16x8, a), __builtin_bit_cast(bf16x8, b), *acc, 0, 0, 0);
}

__device__ inline short f2bf(float f) {   // RNE f32 -> bf16 bits
    uint32_t u = __builtin_bit_cast(uint32_t, f);
    u += 0x7fffu + ((u >> 16) & 1u);
    return (short)(u >> 16);
}

__device__ inline float bf2f(short s) {
    return __builtin_bit_cast(float, (uint32_t)((uint16_t)s) << 16);
}

// async global->LDS, 16B per lane; LDS dest = wave-uniform base + lane*16
__device__ inline void gload16(const short* g, short* l) {
    __builtin_amdgcn_global_load_lds(
        (const __attribute__((address_space(1))) void*)g,
        (__attribute__((address_space(3))) void*)l, 16, 0, 0);
}

// ---------------- zero an f32 buffer (graph-safe) --------------------------
__global__ __launch_bounds__(256) void k_zero(float* __restrict__ p) {
    p[blockIdx.x * 256 + threadIdx.x] = 0.f;
}

// ---------------- weight transpose: w [R][C] f32 (C=1<<lc) -> wt [C][R] bf16
__global__ __launch_bounds__(256) void k_transpose_w(const float* __restrict__ w,
                                                     short* __restrict__ wt,
                                                     int R, int lc) {
    int i = blockIdx.x * 256 + threadIdx.x;
    int r = i >> lc, c = i & ((1 << lc) - 1);
    wt[c * R + r] = f2bf(w[i]);
}

// ---------------- QKV projection (one batch, ALL 8 heads) ------------------
// Q (pre-scaled 1/sqrt(d)), K row-major [h8][2048][128];
// V tile-blocked [h8][kt32][d128][s64].
__global__ __launch_bounds__(256) void k_qkv(
    const float* __restrict__ xB, const short* __restrict__ WqT,
    const short* __restrict__ WkT, const short* __restrict__ WvT,
    short* __restrict__ Qh, short* __restrict__ Kh, short* __restrict__ Vt)
{
    const int z = blockIdx.z;
    const short* __restrict__ WT = (z == 0) ? WqT : (z == 1) ? WkT : WvT; // [1024][128]
    const int w = threadIdx.x >> 6, lane = threadIdx.x & 63;
    const int g = lane >> 4, li = lane & 15;
    const int m0 = blockIdx.x * 64 + w * 16;
    const int n0 = blockIdx.y * 64;               // 0..960
    f32x4 acc[4] = {};
    #pragma unroll
    for (int ks = 0; ks < 4; ++ks) {
        const float* xr = xB + (size_t)(m0 + li) * 128 + ks * 32 + g * 8;
        float4 v0 = *(const float4*)xr, v1 = *(const float4*)(xr + 4);
        s16x8 a = { f2bf(v0.x), f2bf(v0.y), f2bf(v0.z), f2bf(v0.w),
                    f2bf(v1.x), f2bf(v1.y), f2bf(v1.z), f2bf(v1.w) };
        #pragma unroll
        for (int nt = 0; nt < 4; ++nt) {
            s16x8 bfr = *(const s16x8*)(WT + (size_t)(n0 + nt * 16 + li) * 128
                                           + ks * 32 + g * 8);
            mfma_bf16(&acc[nt], a, bfr);
        }
    }
    const float sc = (z == 0) ? 0.088388347648318447f : 1.0f; // 1/sqrt(128) into Q
    #pragma unroll
    for (int nt = 0; nt < 4; ++nt) {
        int col = n0 + nt * 16 + li;              // 0..1023
        int hh = col >> 7, dd = col & 127;        // head, dim
        if (z == 2) {
            int row0 = m0 + g * 4;                // s, multiple of 4
            int kt = row0 >> 6, so = row0 & 63;
            s16x4 o = { f2bf(acc[nt][0]), f2bf(acc[nt][1]),
                        f2bf(acc[nt][2]), f2bf(acc[nt][3]) };
            *(s16x4*)(Vt + (((size_t)hh * 32 + kt) * 128 + dd) * 64 + so) = o;
        } else {
            short* __restrict__ dst = (z == 0) ? Qh : Kh;
            #pragma unroll
            for (int r = 0; r < 4; ++r)
                dst[((size_t)hh * 2048 + m0 + g * 4 + r) * 128 + dd] =
                    f2bf(acc[nt][r] * sc);
        }
    }
}

// ---------------- flash attention, kv-split x2, async dbuf staging ---------
// grid (64 qblocks of 32 rows, 8 heads, 2 kv-halves) = 1024 blocks.
// Each half processes 16 kv tiles; emits unnormalized O (bf16) + (m,l)/row.
// LDS 68KB -> 2 blocks/CU; global_load_lds pipeline hides staging latency.
__global__ __launch_bounds__(128) void k_attn(
    const short* __restrict__ Qh, const short* __restrict__ Kh,
    const short* __restrict__ Vt, short* __restrict__ O0,
    short* __restrict__ O1, float2* __restrict__ ml0, float2* __restrict__ ml1)
{
    __shared__ __align__(16) short Kls[2][64 * 128];   // swizzled [k][d], dbuf
    __shared__ __align__(16) short Vls[2][128 * 64];   // swizzled [d][k], dbuf
    __shared__ __align__(16) short Pls[2][16 * 64];    // per-wave swizzled [q][k]
    const int hh = blockIdx.y;
    const int half = blockIdx.z;
    const size_t base  = (size_t)hh * 2048 * 128;
    const size_t vbase = (size_t)hh * 32 * 8192;       // tile-blocked V^T
    const int w = threadIdx.x >> 6, lane = threadIdx.x & 63;
    const int g = lane >> 4, li = lane & 15;
    const int q0 = blockIdx.x * 32;
    const int qw = q0 + w * 16;
    const int kt0 = half * 16;

    // Async stage tile KT into buffer BUF. LDS dest is LINEAR (lane*16B);
    // the XOR swizzle is applied to the per-lane GLOBAL source chunk, which
    // only permutes chunks within a row segment -> still fully coalesced.
    #define STAGE(BUF, KT)                                                      \
        { _Pragma("unroll")                                                     \
          for (int c2 = 0; c2 < 8; ++c2) {                                      \
              int ci = c2 * 128 + (int)threadIdx.x;                             \
              int row = ci >> 4, cc = ci & 15;                                  \
              gload16(Kh + base + (size_t)((KT) * 64 + row) * 128               \
                         + ((cc ^ (row & 7)) * 8),                              \
                      &Kls[BUF][(c2 * 128 + w * 64) * 8]);                      \
              int d = ci >> 3, jc = ci & 7;                                     \
              gload16(Vt + vbase + (size_t)(KT) * 8192 + d * 64                 \
                         + ((jc ^ (d & 7)) * 8),                                \
                      &Vls[BUF][(c2 * 128 + w * 64) * 8]);                      \
          } }

    s16x8 qf[4];
    #pragma unroll
    for (int ks = 0; ks < 4; ++ks)
        qf[ks] = *(const s16x8*)(Qh + base + (size_t)(qw + li) * 128 + ks * 32 + g * 8);

    f32x4 acc[8] = {};
    float mrow[4] = { -1e30f, -1e30f, -1e30f, -1e30f };
    float lrow[4] = { 0.f, 0.f, 0.f, 0.f };

    STAGE(0, kt0);
    for (int t = 0; t < 16; ++t) {
        const int cur = t & 1;
        __syncthreads();                  // drains vmcnt: buf[cur] ready
        if (t + 1 < 16) STAGE(cur ^ 1, kt0 + t + 1);   // in flight during compute

        // S tile [16 q][64 k] = Q K^T (Q pre-scaled)
        f32x4 st[4];
        #pragma unroll
        for (int nt = 0; nt < 4; ++nt) {
            st[nt] = (f32x4){0.f, 0.f, 0.f, 0.f};
            #pragma unroll
            for (int ks = 0; ks < 4; ++ks) {
                s16x8 bfr = *(const s16x8*)&Kls[cur][(nt * 16 + li) * 128
                                                + (((ks * 4 + g) ^ (li & 7)) * 8)];
                mfma_bf16(&st[nt], qf[ks], bfr);
            }
        }

        // online softmax: row (g*4+r) spread over 16 lanes (li) x 4 regs (nt)
        #pragma unroll
        for (int r = 0; r < 4; ++r) {
            float mx = fmaxf(fmaxf(st[0][r], st[1][r]), fmaxf(st[2][r], st[3][r]));
            mx = fmaxf(mx, __shfl_xor(mx, 1));
            mx = fmaxf(mx, __shfl_xor(mx, 2));
            mx = fmaxf(mx, __shfl_xor(mx, 4));
            mx = fmaxf(mx, __shfl_xor(mx, 8));
            float mnew = fmaxf(mrow[r], mx);
            float alpha = __expf(mrow[r] - mnew);
            float rs = 0.f;
            #pragma unroll
            for (int nt = 0; nt < 4; ++nt) {
                float p = __expf(st[nt][r] - mnew);
                st[nt][r] = p;
                rs += p;
            }
            rs += __shfl_xor(rs, 1);
            rs += __shfl_xor(rs, 2);
            rs += __shfl_xor(rs, 4);
            rs += __shfl_xor(rs, 8);
            lrow[r] = lrow[r] * alpha + rs;
            mrow[r] = mnew;
            #pragma unroll
            for (int dt = 0; dt < 8; ++dt) acc[dt][r] *= alpha;
        }

        // P -> swizzled per-wave LDS, then PV (vector B-fragments)
        short* pw = Pls[w];
        #pragma unroll
        for (int nt = 0; nt < 4; ++nt)
            #pragma unroll
            for (int r = 0; r < 4; ++r) {
                int row = g * 4 + r;
                pw[row * 64 + (((nt * 2 + (li >> 3)) ^ (row & 7)) * 8) + (li & 7)]
                    = f2bf(st[nt][r]);
            }
        #pragma unroll
        for (int kk = 0; kk < 2; ++kk) {
            s16x8 af = *(const s16x8*)&pw[li * 64 + (((kk * 4 + g) ^ (li & 7)) * 8)];
            #pragma unroll
            for (int dt = 0; dt < 8; ++dt) {
                s16x8 bfr = *(const s16x8*)&Vls[cur][(dt * 16 + li) * 64
                                                + (((kk * 4 + g) ^ (li & 7)) * 8)];
                mfma_bf16(&acc[dt], af, bfr);
            }
        }
    }
    #undef STAGE

    short* __restrict__ Op = half ? O1 : O0;
    float2* __restrict__ mlp = half ? ml1 : ml0;
    #pragma unroll
    for (int r = 0; r < 4; ++r) {
        int row = q0 + w * 16 + g * 4 + r;
        if (li == 0) mlp[hh * 2048 + row] = make_float2(mrow[r], lrow[r]);
        #pragma unroll
        for (int dt = 0; dt < 8; ++dt)
            Op[(size_t)row * 1024 + hh * 128 + dt * 16 + li] = f2bf(acc[dt][r]);
    }
}

// ---------------- combine kv-split halves (in-place on O0 -> ctx) ----------
__global__ __launch_bounds__(256) void k_combine(
    short* __restrict__ O0, const short* __restrict__ O1,
    const float2* __restrict__ ml0, const float2* __restrict__ ml1)
{
    int idx = (blockIdx.x * 256 + threadIdx.x) * 8;   // over 2048*1024
    int row = idx >> 10, col = idx & 1023, h = col >> 7;
    float2 a = ml0[h * 2048 + row], b = ml1[h * 2048 + row];
    float M = fmaxf(a.x, b.x);
    float w0 = __expf(a.x - M), w1 = __expf(b.x - M);
    float invL = 1.f / (a.y * w0 + b.y * w1);
    s16x8 v0 = *(const s16x8*)(O0 + idx);
    s16x8 v1 = *(const s16x8*)(O1 + idx);
    s16x8 o;
    #pragma unroll
    for (int e = 0; e < 8; ++e)
        o[e] = f2bf((bf2f(v0[e]) * w0 + bf2f(v1[e]) * w1) * invL);
    *(s16x8*)(O0 + idx) = o;
}

// ---------------- K-split GEMM accumulate: C += A[.][kslice] @ WT^T --------
// A [rows][lda] bf16, WT [128][ldw] bf16, C [rows][128] f32 (pre-zeroed).
__global__ __launch_bounds__(128) void k_gemmacc(
    const short* __restrict__ A, int lda, const short* __restrict__ WT, int ldw,
    float* __restrict__ C)
{
    const int w = threadIdx.x >> 6, lane = threadIdx.x & 63;
    const int g = lane >> 4, li = lane & 15;
    const int m0 = blockIdx.x * 32 + w * 16;
    const int k0 = blockIdx.y * 512;
    f32x4 acc[8] = {};
    for (int ks = 0; ks < 16; ++ks) {
        s16x8 a = *(const s16x8*)(A + (size_t)(m0 + li) * lda + k0 + ks * 32 + g * 8);
        #pragma unroll
        for (int nt = 0; nt < 8; ++nt) {
            s16x8 bfr = *(const s16x8*)(WT + (size_t)(nt * 16 + li) * ldw
                                           + k0 + ks * 32 + g * 8);
            mfma_bf16(&acc[nt], a, bfr);
        }
    }
    #pragma unroll
    for (int nt = 0; nt < 8; ++nt)
        #pragma unroll
        for (int r = 0; r < 4; ++r)
            atomicAdd(&C[(size_t)(m0 + g * 4 + r) * 128 + nt * 16 + li], acc[nt][r]);
}

// ---------------- out[r] = LayerNorm(base[r]+delta[r]) * g (audited) -------
__global__ __launch_bounds__(128) void k_addln(const float* __restrict__ base,
                                               const float* __restrict__ delta,
                                               const float* __restrict__ g,
                                               float* __restrict__ out) {
    __shared__ float r1[128], r2[128];
    int r = blockIdx.x, t = threadIdx.x;
    float v = base[(size_t)r * 128 + t] + delta[(size_t)r * 128 + t];
    r1[t] = v; r2[t] = v * v; __syncthreads();
    for (int s = 64; s > 0; s >>= 1) {
        if (t < s) { r1[t] += r1[t + s]; r2[t] += r2[t + s]; }
        __syncthreads();
    }
    float mean = r1[0] * (1.f / 128.f);
    float var  = r2[0] * (1.f / 128.f) - mean * mean;
    out[(size_t)r * 128 + t] = (v - mean) * rsqrtf(var + 1e-5f) * g[t];
}

// ---------------- FFN1: H = relu(x1 @ W1), 1024-row chunk ------------------
__global__ __launch_bounds__(256) void k_ffn1(
    const float* __restrict__ x1, const short* __restrict__ W1T,
    short* __restrict__ H)
{
    const int w = threadIdx.x >> 6, lane = threadIdx.x & 63;
    const int g = lane >> 4, li = lane & 15;
    const int m0 = blockIdx.x * 64 + w * 16;
    const int n0 = blockIdx.y * 64;
    f32x4 acc[4] = {};
    #pragma unroll
    for (int ks = 0; ks < 4; ++ks) {
        const float* xr = x1 + (size_t)(m0 + li) * 128 + ks * 32 + g * 8;
        float4 v0 = *(const float4*)xr, v1 = *(const float4*)(xr + 4);
        s16x8 a = { f2bf(v0.x), f2bf(v0.y), f2bf(v0.z), f2bf(v0.w),
                    f2bf(v1.x), f2bf(v1.y), f2bf(v1.z), f2bf(v1.w) };
        #pragma unroll
        for (int nt = 0; nt < 4; ++nt) {
            s16x8 bfr = *(const s16x8*)(W1T + (size_t)(n0 + nt * 16 + li) * 128
                                            + ks * 32 + g * 8);
            mfma_bf16(&acc[nt], a, bfr);
        }
    }
    #pragma unroll
    for (int nt = 0; nt < 4; ++nt)
        #pragma unroll
        for (int r = 0; r < 4; ++r)
            H[(size_t)(m0 + g * 4 + r) * 2048 + n0 + nt * 16 + li] =
                f2bf(fmaxf(acc[nt][r], 0.f));
}

// ---------------------------------------------------------------------------
extern "C" void kernel_launch(void* const* d_in, const int* in_sizes, int n_in,
                              void* d_out, int out_size, void* d_ws, size_t ws_size,
                              hipStream_t stream)
{
    const float* x  = (const float*)d_in[0];
    const float* Wq = (const float*)d_in[1];
    const float* Wk = (const float*)d_in[2];
    const float* Wv = (const float*)d_in[3];
    const float* Wo = (const float*)d_in[4];
    const float* W1 = (const float*)d_in[5];
    const float* W2 = (const float*)d_in[6];
    const float* g1 = (const float*)d_in[7];
    const float* g2 = (const float*)d_in[8];
    float* out = (float*)d_out;
    (void)in_sizes; (void)n_in; (void)out_size; (void)ws_size;

    char* basep = (char*)d_ws;
    size_t off = 0;
    auto carve = [&](size_t bytes) {
        void* q = basep + off;
        off += (bytes + 255) & ~(size_t)255;
        return q;
    };
    // total ~23.3 MB (green proven to 23.3 in r12; hard failure located ~45)
    short*  WqT = (short*)carve(1024ull * 128 * 2);       // 256 KB
    short*  WkT = (short*)carve(1024ull * 128 * 2);
    short*  WvT = (short*)carve(1024ull * 128 * 2);
    short*  WoT = (short*)carve(128ull * 1024 * 2);       // 256 KB
    short*  W1T = (short*)carve(2048ull * 128 * 2);       // 512 KB
    short*  W2T = (short*)carve(128ull * 2048 * 2);       // 512 KB
    short*  Qh  = (short*)carve(8ull * 2048 * 128 * 2);   // 4 MB (8 heads)
    short*  Kh  = (short*)carve(8ull * 2048 * 128 * 2);   // 4 MB
    short*  Vt  = (short*)carve(8ull * 32 * 128 * 64 * 2);// 4 MB (tile-blocked)
    short*  O0  = (short*)carve(2048ull * 1024 * 2);      // 4 MB (-> ctx)
    short*  O1  = (short*)carve(2048ull * 1024 * 2);      // 4 MB
    float2* ml0 = (float2*)carve(8ull * 2048 * 8);        // 128 KB
    float2* ml1 = (float2*)carve(8ull * 2048 * 8);        // 128 KB
    float*  sab = (float*)carve(2048ull * 128 * 4);       // 1 MB
    short*  H   = Qh;           // FFN1 chunk [1024][2048] bf16 = 4 MB over Qh
    float*  ffb = sab;          // FFN2 accumulator aliases sab

    // weight prep
    k_transpose_w<<<512,  256, 0, stream>>>(Wq, WqT, 128, 10);
    k_transpose_w<<<512,  256, 0, stream>>>(Wk, WkT, 128, 10);
    k_transpose_w<<<512,  256, 0, stream>>>(Wv, WvT, 128, 10);
    k_transpose_w<<<512,  256, 0, stream>>>(Wo, WoT, 1024, 7);
    k_transpose_w<<<1024, 256, 0, stream>>>(W1, W1T, 128, 11);
    k_transpose_w<<<1024, 256, 0, stream>>>(W2, W2T, 2048, 7);

    for (int b = 0; b < 4; ++b) {
        const float* xb = x + (size_t)b * 2048 * 128;
        float* x1b = out + (size_t)b * 2048 * 128;   // x1 lives in d_out rows

        // ---- attention + out-proj (whole batch, 8 heads, kv-split x2) ----
        k_zero<<<1024, 256, 0, stream>>>(sab);
        k_qkv<<<dim3(32, 16, 3), 256, 0, stream>>>(xb, WqT, WkT, WvT, Qh, Kh, Vt);
        k_attn<<<dim3(64, 8, 2), 128, 0, stream>>>(Qh, Kh, Vt, O0, O1, ml0, ml1);
        k_combine<<<1024, 256, 0, stream>>>(O0, O1, ml0, ml1);
        k_gemmacc<<<dim3(64, 2), 128, 0, stream>>>(O0, 1024, WoT, 1024, sab);
        k_addln<<<2048, 128, 0, stream>>>(xb, sab, g1, x1b);

        // ---- FFN ----
        k_zero<<<1024, 256, 0, stream>>>(ffb);
        for (int c = 0; c < 2; ++c) {
            k_ffn1<<<dim3(16, 32), 256, 0, stream>>>(x1b + (size_t)c * 1024 * 128,
                                                     W1T, H);
            k_gemmacc<<<dim3(32, 4), 128, 0, stream>>>(H, 2048, W2T, 2048,
                                                       ffb + (size_t)c * 1024 * 128);
        }
        k_addln<<<2048, 128, 0, stream>>>(x1b, ffb, g2, x1b);
    }
}

// Round 14
// 720.559 us; speedup vs baseline: 3.1154x; 1.0978x over previous
//
#include <hip/hip_runtime.h>
#include <stdint.h>

// ---------------------------------------------------------------------------
// TransformerEncoderLayer: b=4 s=2048 d=128 h=8 (head_dim=128) dff=2048
// Round-14: fusion of the non-attention pipeline (r13 post-mortem: 486us in
// ~50 small launches).
//  - k_oproj: combine(kv-split) folded into out-proj A-frag load (lane-local)
//    + residual + LN1. Kills k_zero/k_combine/k_gemmacc/k_addln for stage A.
//  - k_ffn: FFN1+ReLU+FFN2+residual+LN2 in ONE kernel for ALL batches;
//    H tensor never materialized (per-wave LDS chunk staging).
//  - 19 launches total (was ~54).
// k_attn / k_qkv / transposes byte-identical to r13 (green).
// ---------------------------------------------------------------------------

using f32x4 = __attribute__((ext_vector_type(4))) float;
using s16x8 = __attribute__((ext_vector_type(8))) short;
using s16x4 = __attribute__((ext_vector_type(4))) short;
typedef __bf16 bf16x8 __attribute__((ext_vector_type(8)));

__device__ inline void mfma_bf16(f32x4* acc, s16x8 a, s16x8 b) {
    *acc = __builtin_amdgcn_mfma_f32_16x16x32_bf16(
        __builtin_bit_cast(bf16x8, a), __builtin_bit_cast(bf16x8, b), *acc, 0, 0, 0);
}

__device__ inline short f2bf(float f) {   // RNE f32 -> bf16 bits
    uint32_t u = __builtin_bit_cast(uint32_t, f);
    u += 0x7fffu + ((u >> 16) & 1u);
    return (short)(u >> 16);
}

__device__ inline float bf2f(short s) {
    return __builtin_bit_cast(float, (uint32_t)((uint16_t)s) << 16);
}

// async global->LDS, 16B per lane; LDS dest = wave-uniform base + lane*16
__device__ inline void gload16(const short* g, short* l) {
    __builtin_amdgcn_global_load_lds(
        (const __attribute__((address_space(1))) void*)g,
        (__attribute__((address_space(3))) void*)l, 16, 0, 0);
}

// ---------------- weight transpose: w [R][C] f32 (C=1<<lc) -> wt [C][R] bf16
__global__ __launch_bounds__(256) void k_transpose_w(const float* __restrict__ w,
                                                     short* __restrict__ wt,
                                                     int R, int lc) {
    int i = blockIdx.x * 256 + threadIdx.x;
    int r = i >> lc, c = i & ((1 << lc) - 1);
    wt[c * R + r] = f2bf(w[i]);
}

// ---------------- QKV projection (one batch, ALL 8 heads) ------------------
// Q (pre-scaled 1/sqrt(d)), K row-major [h8][2048][128];
// V tile-blocked [h8][kt32][d128][s64].
__global__ __launch_bounds__(256) void k_qkv(
    const float* __restrict__ xB, const short* __restrict__ WqT,
    const short* __restrict__ WkT, const short* __restrict__ WvT,
    short* __restrict__ Qh, short* __restrict__ Kh, short* __restrict__ Vt)
{
    const int z = blockIdx.z;
    const short* __restrict__ WT = (z == 0) ? WqT : (z == 1) ? WkT : WvT; // [1024][128]
    const int w = threadIdx.x >> 6, lane = threadIdx.x & 63;
    const int g = lane >> 4, li = lane & 15;
    const int m0 = blockIdx.x * 64 + w * 16;
    const int n0 = blockIdx.y * 64;               // 0..960
    f32x4 acc[4] = {};
    #pragma unroll
    for (int ks = 0; ks < 4; ++ks) {
        const float* xr = xB + (size_t)(m0 + li) * 128 + ks * 32 + g * 8;
        float4 v0 = *(const float4*)xr, v1 = *(const float4*)(xr + 4);
        s16x8 a = { f2bf(v0.x), f2bf(v0.y), f2bf(v0.z), f2bf(v0.w),
                    f2bf(v1.x), f2bf(v1.y), f2bf(v1.z), f2bf(v1.w) };
        #pragma unroll
        for (int nt = 0; nt < 4; ++nt) {
            s16x8 bfr = *(const s16x8*)(WT + (size_t)(n0 + nt * 16 + li) * 128
                                           + ks * 32 + g * 8);
            mfma_bf16(&acc[nt], a, bfr);
        }
    }
    const float sc = (z == 0) ? 0.088388347648318447f : 1.0f; // 1/sqrt(128) into Q
    #pragma unroll
    for (int nt = 0; nt < 4; ++nt) {
        int col = n0 + nt * 16 + li;              // 0..1023
        int hh = col >> 7, dd = col & 127;        // head, dim
        if (z == 2) {
            int row0 = m0 + g * 4;                // s, multiple of 4
            int kt = row0 >> 6, so = row0 & 63;
            s16x4 o = { f2bf(acc[nt][0]), f2bf(acc[nt][1]),
                        f2bf(acc[nt][2]), f2bf(acc[nt][3]) };
            *(s16x4*)(Vt + (((size_t)hh * 32 + kt) * 128 + dd) * 64 + so) = o;
        } else {
            short* __restrict__ dst = (z == 0) ? Qh : Kh;
            #pragma unroll
            for (int r = 0; r < 4; ++r)
                dst[((size_t)hh * 2048 + m0 + g * 4 + r) * 128 + dd] =
                    f2bf(acc[nt][r] * sc);
        }
    }
}

// ---------------- flash attention, kv-split x2, async dbuf staging ---------
// grid (64 qblocks of 32 rows, 8 heads, 2 kv-halves) = 1024 blocks.
__global__ __launch_bounds__(128) void k_attn(
    const short* __restrict__ Qh, const short* __restrict__ Kh,
    const short* __restrict__ Vt, short* __restrict__ O0,
    short* __restrict__ O1, float2* __restrict__ ml0, float2* __restrict__ ml1)
{
    __shared__ __align__(16) short Kls[2][64 * 128];   // swizzled [k][d], dbuf
    __shared__ __align__(16) short Vls[2][128 * 64];   // swizzled [d][k], dbuf
    __shared__ __align__(16) short Pls[2][16 * 64];    // per-wave swizzled [q][k]
    const int hh = blockIdx.y;
    const int half = blockIdx.z;
    const size_t base  = (size_t)hh * 2048 * 128;
    const size_t vbase = (size_t)hh * 32 * 8192;       // tile-blocked V^T
    const int w = threadIdx.x >> 6, lane = threadIdx.x & 63;
    const int g = lane >> 4, li = lane & 15;
    const int q0 = blockIdx.x * 32;
    const int qw = q0 + w * 16;
    const int kt0 = half * 16;

    #define STAGE(BUF, KT)                                                      \
        { _Pragma("unroll")                                                     \
          for (int c2 = 0; c2 < 8; ++c2) {                                      \
              int ci = c2 * 128 + (int)threadIdx.x;                             \
              int row = ci >> 4, cc = ci & 15;                                  \
              gload16(Kh + base + (size_t)((KT) * 64 + row) * 128               \
                         + ((cc ^ (row & 7)) * 8),                              \
                      &Kls[BUF][(c2 * 128 + w * 64) * 8]);                      \
              int d = ci >> 3, jc = ci & 7;                                     \
              gload16(Vt + vbase + (size_t)(KT) * 8192 + d * 64                 \
                         + ((jc ^ (d & 7)) * 8),                                \
                      &Vls[BUF][(c2 * 128 + w * 64) * 8]);                      \
          } }

    s16x8 qf[4];
    #pragma unroll
    for (int ks = 0; ks < 4; ++ks)
        qf[ks] = *(const s16x8*)(Qh + base + (size_t)(qw + li) * 128 + ks * 32 + g * 8);

    f32x4 acc[8] = {};
    float mrow[4] = { -1e30f, -1e30f, -1e30f, -1e30f };
    float lrow[4] = { 0.f, 0.f, 0.f, 0.f };

    STAGE(0, kt0);
    for (int t = 0; t < 16; ++t) {
        const int cur = t & 1;
        __syncthreads();                  // drains vmcnt: buf[cur] ready
        if (t + 1 < 16) STAGE(cur ^ 1, kt0 + t + 1);   // in flight during compute

        f32x4 st[4];
        #pragma unroll
        for (int nt = 0; nt < 4; ++nt) {
            st[nt] = (f32x4){0.f, 0.f, 0.f, 0.f};
            #pragma unroll
            for (int ks = 0; ks < 4; ++ks) {
                s16x8 bfr = *(const s16x8*)&Kls[cur][(nt * 16 + li) * 128
                                                + (((ks * 4 + g) ^ (li & 7)) * 8)];
                mfma_bf16(&st[nt], qf[ks], bfr);
            }
        }

        #pragma unroll
        for (int r = 0; r < 4; ++r) {
            float mx = fmaxf(fmaxf(st[0][r], st[1][r]), fmaxf(st[2][r], st[3][r]));
            mx = fmaxf(mx, __shfl_xor(mx, 1));
            mx = fmaxf(mx, __shfl_xor(mx, 2));
            mx = fmaxf(mx, __shfl_xor(mx, 4));
            mx = fmaxf(mx, __shfl_xor(mx, 8));
            float mnew = fmaxf(mrow[r], mx);
            float alpha = __expf(mrow[r] - mnew);
            float rs = 0.f;
            #pragma unroll
            for (int nt = 0; nt < 4; ++nt) {
                float p = __expf(st[nt][r] - mnew);
                st[nt][r] = p;
                rs += p;
            }
            rs += __shfl_xor(rs, 1);
            rs += __shfl_xor(rs, 2);
            rs += __shfl_xor(rs, 4);
            rs += __shfl_xor(rs, 8);
            lrow[r] = lrow[r] * alpha + rs;
            mrow[r] = mnew;
            #pragma unroll
            for (int dt = 0; dt < 8; ++dt) acc[dt][r] *= alpha;
        }

        short* pw = Pls[w];
        #pragma unroll
        for (int nt = 0; nt < 4; ++nt)
            #pragma unroll
            for (int r = 0; r < 4; ++r) {
                int row = g * 4 + r;
                pw[row * 64 + (((nt * 2 + (li >> 3)) ^ (row & 7)) * 8) + (li & 7)]
                    = f2bf(st[nt][r]);
            }
        #pragma unroll
        for (int kk = 0; kk < 2; ++kk) {
            s16x8 af = *(const s16x8*)&pw[li * 64 + (((kk * 4 + g) ^ (li & 7)) * 8)];
            #pragma unroll
            for (int dt = 0; dt < 8; ++dt) {
                s16x8 bfr = *(const s16x8*)&Vls[cur][(dt * 16 + li) * 64
                                                + (((kk * 4 + g) ^ (li & 7)) * 8)];
                mfma_bf16(&acc[dt], af, bfr);
            }
        }
    }
    #undef STAGE

    short* __restrict__ Op = half ? O1 : O0;
    float2* __restrict__ mlp = half ? ml1 : ml0;
    #pragma unroll
    for (int r = 0; r < 4; ++r) {
        int row = q0 + w * 16 + g * 4 + r;
        if (li == 0) mlp[hh * 2048 + row] = make_float2(mrow[r], lrow[r]);
        #pragma unroll
        for (int dt = 0; dt < 8; ++dt)
            Op[(size_t)row * 1024 + hh * 128 + dt * 16 + li] = f2bf(acc[dt][r]);
    }
}

// ---------------- fused combine + out-proj + residual + LN1 ----------------
// per batch: grid 128 blocks x 64 thr; block owns 16 rows end-to-end.
// A-frag rows are lane-local -> kv-split combine happens inline in registers.
__global__ __launch_bounds__(64) void k_oproj(
    const short* __restrict__ O0, const short* __restrict__ O1,
    const float2* __restrict__ ml0, const float2* __restrict__ ml1,
    const short* __restrict__ WoT, const float* __restrict__ resid,
    const float* __restrict__ gain, float* __restrict__ outp)
{
    const int lane = threadIdx.x;
    const int g = lane >> 4, li = lane & 15;
    const int m0 = blockIdx.x * 16;
    const int row = m0 + li;                      // this lane's A-frag row
    float w0[8], w1[8], il[8];                    // per-head combine weights
    #pragma unroll
    for (int h = 0; h < 8; ++h) {
        float2 a = ml0[h * 2048 + row], bml = ml1[h * 2048 + row];
        float M = fmaxf(a.x, bml.x);
        float e0 = __expf(a.x - M), e1 = __expf(bml.x - M);
        w0[h] = e0; w1[h] = e1;
        il[h] = 1.f / (a.y * e0 + bml.y * e1);
    }
    f32x4 acc[8] = {};
    for (int ks = 0; ks < 32; ++ks) {             // K = 1024 = 8 heads x 128
        int h = ks >> 2;
        s16x8 a0 = *(const s16x8*)(O0 + (size_t)row * 1024 + ks * 32 + g * 8);
        s16x8 a1 = *(const s16x8*)(O1 + (size_t)row * 1024 + ks * 32 + g * 8);
        s16x8 a;
        #pragma unroll
        for (int e = 0; e < 8; ++e)
            a[e] = f2bf((bf2f(a0[e]) * w0[h] + bf2f(a1[e]) * w1[h]) * il[h]);
        #pragma unroll
        for (int nt = 0; nt < 8; ++nt) {
            s16x8 bfr = *(const s16x8*)(WoT + (size_t)(nt * 16 + li) * 1024
                                           + ks * 32 + g * 8);
            mfma_bf16(&acc[nt], a, bfr);
        }
    }
    float gv[8];
    #pragma unroll
    for (int nt = 0; nt < 8; ++nt) gv[nt] = gain[nt * 16 + li];
    #pragma unroll
    for (int r = 0; r < 4; ++r) {
        int orow = m0 + g * 4 + r;
        float s = 0.f, s2 = 0.f;
        #pragma unroll
        for (int nt = 0; nt < 8; ++nt) {
            float v = acc[nt][r] + resid[(size_t)orow * 128 + nt * 16 + li];
            acc[nt][r] = v;
            s += v; s2 += v * v;
        }
        s  += __shfl_xor(s, 1);  s  += __shfl_xor(s, 2);
        s  += __shfl_xor(s, 4);  s  += __shfl_xor(s, 8);
        s2 += __shfl_xor(s2, 1); s2 += __shfl_xor(s2, 2);
        s2 += __shfl_xor(s2, 4); s2 += __shfl_xor(s2, 8);
        float mean = s * (1.f / 128.f);
        float var  = s2 * (1.f / 128.f) - mean * mean;
        float rstd = rsqrtf(var + 1e-5f);
        #pragma unroll
        for (int nt = 0; nt < 8; ++nt)
            outp[(size_t)orow * 128 + nt * 16 + li] =
                (acc[nt][r] - mean) * rstd * gv[nt];
    }
}

// ---------------- fused FFN: LN2(x1 + relu(x1@W1)@W2) -----------------------
// ALL batches: grid (128, 4) x 64 thr; block owns 16 rows; H never stored.
__global__ __launch_bounds__(64) void k_ffn(
    const float* __restrict__ x1, const short* __restrict__ W1T,
    const short* __restrict__ W2T, const float* __restrict__ gain,
    float* __restrict__ outp)
{
    __shared__ __align__(16) short hls[16 * 64];  // per-block h chunk, swizzled
    const int lane = threadIdx.x;
    const int g = lane >> 4, li = lane & 15;
    const size_t m0 = (size_t)blockIdx.y * 2048 + blockIdx.x * 16;
    s16x8 xf[4];                                  // A-frags, loaded once
    #pragma unroll
    for (int ks = 0; ks < 4; ++ks) {
        const float* xr = x1 + (m0 + li) * 128 + ks * 32 + g * 8;
        float4 v0 = *(const float4*)xr, v1 = *(const float4*)(xr + 4);
        xf[ks] = (s16x8){ f2bf(v0.x), f2bf(v0.y), f2bf(v0.z), f2bf(v0.w),
                          f2bf(v1.x), f2bf(v1.y), f2bf(v1.z), f2bf(v1.w) };
    }
    f32x4 acc[8] = {};
    for (int ch = 0; ch < 32; ++ch) {             // dff in chunks of 64
        f32x4 st[4];                              // GEMM1: h = relu(x@W1 chunk)
        #pragma unroll
        for (int nt = 0; nt < 4; ++nt) {
            st[nt] = (f32x4){0.f, 0.f, 0.f, 0.f};
            #pragma unroll
            for (int ks = 0; ks < 4; ++ks) {
                s16x8 bfr = *(const s16x8*)(W1T + (size_t)(ch * 64 + nt * 16 + li) * 128
                                               + ks * 32 + g * 8);
                mfma_bf16(&st[nt], xf[ks], bfr);
            }
        }
        #pragma unroll
        for (int nt = 0; nt < 4; ++nt)            // stage h -> LDS (P pattern)
            #pragma unroll
            for (int r = 0; r < 4; ++r) {
                int rw = g * 4 + r;
                hls[rw * 64 + (((nt * 2 + (li >> 3)) ^ (rw & 7)) * 8) + (li & 7)]
                    = f2bf(fmaxf(st[nt][r], 0.f));
            }
        #pragma unroll
        for (int kk = 0; kk < 2; ++kk) {          // GEMM2: acc += h @ W2 chunk
            s16x8 af = *(const s16x8*)&hls[li * 64 + (((kk * 4 + g) ^ (li & 7)) * 8)];
            #pragma unroll
            for (int nt = 0; nt < 8; ++nt) {
                s16x8 bfr = *(const s16x8*)(W2T + (size_t)(nt * 16 + li) * 2048
                                               + ch * 64 + kk * 32 + g * 8);
                mfma_bf16(&acc[nt], af, bfr);
            }
        }
    }
    float gv[8];
    #pragma unroll
    for (int nt = 0; nt < 8; ++nt) gv[nt] = gain[nt * 16 + li];
    #pragma unroll
    for (int r = 0; r < 4; ++r) {
        size_t orow = m0 + g * 4 + r;
        float s = 0.f, s2 = 0.f;
        #pragma unroll
        for (int nt = 0; nt < 8; ++nt) {
            float v = acc[nt][r] + x1[orow * 128 + nt * 16 + li];
            acc[nt][r] = v;
            s += v; s2 += v * v;
        }
        s  += __shfl_xor(s, 1);  s  += __shfl_xor(s, 2);
        s  += __shfl_xor(s, 4);  s  += __shfl_xor(s, 8);
        s2 += __shfl_xor(s2, 1); s2 += __shfl_xor(s2, 2);
        s2 += __shfl_xor(s2, 4); s2 += __shfl_xor(s2, 8);
        float mean = s * (1.f / 128.f);
        float var  = s2 * (1.f / 128.f) - mean * mean;
        float rstd = rsqrtf(var + 1e-5f);
        #pragma unroll
        for (int nt = 0; nt < 8; ++nt)
            outp[orow * 128 + nt * 16 + li] = (acc[nt][r] - mean) * rstd * gv[nt];
    }
}

// ---------------------------------------------------------------------------
extern "C" void kernel_launch(void* const* d_in, const int* in_sizes, int n_in,
                              void* d_out, int out_size, void* d_ws, size_t ws_size,
                              hipStream_t stream)
{
    const float* x  = (const float*)d_in[0];
    const float* Wq = (const float*)d_in[1];
    const float* Wk = (const float*)d_in[2];
    const float* Wv = (const float*)d_in[3];
    const float* Wo = (const float*)d_in[4];
    const float* W1 = (const float*)d_in[5];
    const float* W2 = (const float*)d_in[6];
    const float* g1 = (const float*)d_in[7];
    const float* g2 = (const float*)d_in[8];
    float* out = (float*)d_out;
    (void)in_sizes; (void)n_in; (void)out_size; (void)ws_size;

    char* basep = (char*)d_ws;
    size_t off = 0;
    auto carve = [&](size_t bytes) {
        void* q = basep + off;
        off += (bytes + 255) & ~(size_t)255;
        return q;
    };
    // total ~22.3 MB (green proven to 23.3 in r12/r13)
    short*  WqT = (short*)carve(1024ull * 128 * 2);       // 256 KB
    short*  WkT = (short*)carve(1024ull * 128 * 2);
    short*  WvT = (short*)carve(1024ull * 128 * 2);
    short*  WoT = (short*)carve(128ull * 1024 * 2);       // 256 KB
    short*  W1T = (short*)carve(2048ull * 128 * 2);       // 512 KB
    short*  W2T = (short*)carve(128ull * 2048 * 2);       // 512 KB
    short*  Qh  = (short*)carve(8ull * 2048 * 128 * 2);   // 4 MB (8 heads)
    short*  Kh  = (short*)carve(8ull * 2048 * 128 * 2);   // 4 MB
    short*  Vt  = (short*)carve(8ull * 32 * 128 * 64 * 2);// 4 MB (tile-blocked)
    short*  O0  = (short*)carve(2048ull * 1024 * 2);      // 4 MB
    short*  O1  = (short*)carve(2048ull * 1024 * 2);      // 4 MB
    float2* ml0 = (float2*)carve(8ull * 2048 * 8);        // 128 KB
    float2* ml1 = (float2*)carve(8ull * 2048 * 8);        // 128 KB

    // weight prep
    k_transpose_w<<<512,  256, 0, stream>>>(Wq, WqT, 128, 10);
    k_transpose_w<<<512,  256, 0, stream>>>(Wk, WkT, 128, 10);
    k_transpose_w<<<512,  256, 0, stream>>>(Wv, WvT, 128, 10);
    k_transpose_w<<<512,  256, 0, stream>>>(Wo, WoT, 1024, 7);
    k_transpose_w<<<1024, 256, 0, stream>>>(W1, W1T, 128, 11);
    k_transpose_w<<<1024, 256, 0, stream>>>(W2, W2T, 2048, 7);

    // ---- stage A per batch: qkv -> attention -> fused oproj+LN1 ----
    for (int b = 0; b < 4; ++b) {
        const float* xb = x + (size_t)b * 2048 * 128;
        float* x1b = out + (size_t)b * 2048 * 128;   // x1 lives in d_out rows
        k_qkv<<<dim3(32, 16, 3), 256, 0, stream>>>(xb, WqT, WkT, WvT, Qh, Kh, Vt);
        k_attn<<<dim3(64, 8, 2), 128, 0, stream>>>(Qh, Kh, Vt, O0, O1, ml0, ml1);
        k_oproj<<<128, 64, 0, stream>>>(O0, O1, ml0, ml1, WoT, xb, g1, x1b);
    }

    // ---- stage B: fused FFN + LN2, ALL batches, one launch ----
    k_ffn<<<dim3(128, 4), 64, 0, stream>>>(out, W1T, W2T, g2, out);
}

// Round 15
// 445.536 us; speedup vs baseline: 5.0384x; 1.6173x over previous
//
#include <hip/hip_runtime.h>
#include <stdint.h>

// ---------------------------------------------------------------------------
// TransformerEncoderLayer: b=4 s=2048 d=128 h=8 (head_dim=128) dff=2048
// Round-15: occupancy attack on all three hot kernels (r14 post-mortem:
// 1-wave blocks / 4 waves-per-CU everywhere -> latency-bound).
//  - k_attn: 4 waves/block (QBLK=64), grid (32,8,2); tile staged once per
//    64 q-rows (halves staging traffic), 8 waves/CU.
//  - k_ffn: 4-wave K-split over dff chunks + LDS reduce; 8 waves/CU.
//  - k_oproj: 4-wave K-split over the 32 ks steps + LDS reduce.
// Math, layouts, swizzles byte-identical to r14 (green).
// ---------------------------------------------------------------------------

using f32x4 = __attribute__((ext_vector_type(4))) float;
using s16x8 = __attribute__((ext_vector_type(8))) short;
using s16x4 = __attribute__((ext_vector_type(4))) short;
typedef __bf16 bf16x8 __attribute__((ext_vector_type(8)));

__device__ inline void mfma_bf16(f32x4* acc, s16x8 a, s16x8 b) {
    *acc = __builtin_amdgcn_mfma_f32_16x16x32_bf16(
        __builtin_bit_cast(bf16x8, a), __builtin_bit_cast(bf16x8, b), *acc, 0, 0, 0);
}

__device__ inline short f2bf(float f) {   // RNE f32 -> bf16 bits
    uint32_t u = __builtin_bit_cast(uint32_t, f);
    u += 0x7fffu + ((u >> 16) & 1u);
    return (short)(u >> 16);
}

__device__ inline float bf2f(short s) {
    return __builtin_bit_cast(float, (uint32_t)((uint16_t)s) << 16);
}

// async global->LDS, 16B per lane; LDS dest = wave-uniform base + lane*16
__device__ inline void gload16(const short* g, short* l) {
    __builtin_amdgcn_global_load_lds(
        (const __attribute__((address_space(1))) void*)g,
        (__attribute__((address_space(3))) void*)l, 16, 0, 0);
}

// ---------------- weight transpose: w [R][C] f32 (C=1<<lc) -> wt [C][R] bf16
__global__ __launch_bounds__(256) void k_transpose_w(const float* __restrict__ w,
                                                     short* __restrict__ wt,
                                                     int R, int lc) {
    int i = blockIdx.x * 256 + threadIdx.x;
    int r = i >> lc, c = i & ((1 << lc) - 1);
    wt[c * R + r] = f2bf(w[i]);
}

// ---------------- QKV projection (one batch, ALL 8 heads) ------------------
// Q (pre-scaled 1/sqrt(d)), K row-major [h8][2048][128];
// V tile-blocked [h8][kt32][d128][s64].
__global__ __launch_bounds__(256) void k_qkv(
    const float* __restrict__ xB, const short* __restrict__ WqT,
    const short* __restrict__ WkT, const short* __restrict__ WvT,
    short* __restrict__ Qh, short* __restrict__ Kh, short* __restrict__ Vt)
{
    const int z = blockIdx.z;
    const short* __restrict__ WT = (z == 0) ? WqT : (z == 1) ? WkT : WvT; // [1024][128]
    const int w = threadIdx.x >> 6, lane = threadIdx.x & 63;
    const int g = lane >> 4, li = lane & 15;
    const int m0 = blockIdx.x * 64 + w * 16;
    const int n0 = blockIdx.y * 64;               // 0..960
    f32x4 acc[4] = {};
    #pragma unroll
    for (int ks = 0; ks < 4; ++ks) {
        const float* xr = xB + (size_t)(m0 + li) * 128 + ks * 32 + g * 8;
        float4 v0 = *(const float4*)xr, v1 = *(const float4*)(xr + 4);
        s16x8 a = { f2bf(v0.x), f2bf(v0.y), f2bf(v0.z), f2bf(v0.w),
                    f2bf(v1.x), f2bf(v1.y), f2bf(v1.z), f2bf(v1.w) };
        #pragma unroll
        for (int nt = 0; nt < 4; ++nt) {
            s16x8 bfr = *(const s16x8*)(WT + (size_t)(n0 + nt * 16 + li) * 128
                                           + ks * 32 + g * 8);
            mfma_bf16(&acc[nt], a, bfr);
        }
    }
    const float sc = (z == 0) ? 0.088388347648318447f : 1.0f; // 1/sqrt(128) into Q
    #pragma unroll
    for (int nt = 0; nt < 4; ++nt) {
        int col = n0 + nt * 16 + li;              // 0..1023
        int hh = col >> 7, dd = col & 127;        // head, dim
        if (z == 2) {
            int row0 = m0 + g * 4;                // s, multiple of 4
            int kt = row0 >> 6, so = row0 & 63;
            s16x4 o = { f2bf(acc[nt][0]), f2bf(acc[nt][1]),
                        f2bf(acc[nt][2]), f2bf(acc[nt][3]) };
            *(s16x4*)(Vt + (((size_t)hh * 32 + kt) * 128 + dd) * 64 + so) = o;
        } else {
            short* __restrict__ dst = (z == 0) ? Qh : Kh;
            #pragma unroll
            for (int r = 0; r < 4; ++r)
                dst[((size_t)hh * 2048 + m0 + g * 4 + r) * 128 + dd] =
                    f2bf(acc[nt][r] * sc);
        }
    }
}

// ---------------- flash attention, 4 waves/block, kv-split x2 --------------
// grid (32 qblocks of 64 rows, 8 heads, 2 kv-halves) = 512 blocks x 256 thr.
// Each staged K/V tile is consumed by 64 q rows (4 waves).
__global__ __launch_bounds__(256) void k_attn(
    const short* __restrict__ Qh, const short* __restrict__ Kh,
    const short* __restrict__ Vt, short* __restrict__ O0,
    short* __restrict__ O1, float2* __restrict__ ml0, float2* __restrict__ ml1)
{
    __shared__ __align__(16) short Kls[2][64 * 128];   // swizzled [k][d], dbuf
    __shared__ __align__(16) short Vls[2][128 * 64];   // swizzled [d][k], dbuf
    __shared__ __align__(16) short Pls[4][16 * 64];    // per-wave swizzled [q][k]
    const int hh = blockIdx.y;
    const int half = blockIdx.z;
    const size_t base  = (size_t)hh * 2048 * 128;
    const size_t vbase = (size_t)hh * 32 * 8192;       // tile-blocked V^T
    const int w = threadIdx.x >> 6, lane = threadIdx.x & 63;
    const int g = lane >> 4, li = lane & 15;
    const int q0 = blockIdx.x * 64;
    const int qw = q0 + w * 16;
    const int kt0 = half * 16;

    // 256 threads stage 1024 K-chunks + 1024 V-chunks (16B each).
    // LDS dest = wave-uniform base + lane*16; swizzle folded into global src.
    #define STAGE(BUF, KT)                                                      \
        { _Pragma("unroll")                                                     \
          for (int c2 = 0; c2 < 4; ++c2) {                                      \
              int ci = c2 * 256 + (int)threadIdx.x;                             \
              int row = ci >> 4, cc = ci & 15;                                  \
              gload16(Kh + base + (size_t)((KT) * 64 + row) * 128               \
                         + ((cc ^ (row & 7)) * 8),                              \
                      &Kls[BUF][(c2 * 256 + w * 64) * 8]);                      \
              int d = ci >> 3, jc = ci & 7;                                     \
              gload16(Vt + vbase + (size_t)(KT) * 8192 + d * 64                 \
                         + ((jc ^ (d & 7)) * 8),                                \
                      &Vls[BUF][(c2 * 256 + w * 64) * 8]);                      \
          } }

    s16x8 qf[4];
    #pragma unroll
    for (int ks = 0; ks < 4; ++ks)
        qf[ks] = *(const s16x8*)(Qh + base + (size_t)(qw + li) * 128 + ks * 32 + g * 8);

    f32x4 acc[8] = {};
    float mrow[4] = { -1e30f, -1e30f, -1e30f, -1e30f };
    float lrow[4] = { 0.f, 0.f, 0.f, 0.f };

    STAGE(0, kt0);
    for (int t = 0; t < 16; ++t) {
        const int cur = t & 1;
        __syncthreads();                  // drains vmcnt: buf[cur] ready
        if (t + 1 < 16) STAGE(cur ^ 1, kt0 + t + 1);   // in flight during compute

        f32x4 st[4];
        #pragma unroll
        for (int nt = 0; nt < 4; ++nt) {
            st[nt] = (f32x4){0.f, 0.f, 0.f, 0.f};
            #pragma unroll
            for (int ks = 0; ks < 4; ++ks) {
                s16x8 bfr = *(const s16x8*)&Kls[cur][(nt * 16 + li) * 128
                                                + (((ks * 4 + g) ^ (li & 7)) * 8)];
                mfma_bf16(&st[nt], qf[ks], bfr);
            }
        }

        #pragma unroll
        for (int r = 0; r < 4; ++r) {
            float mx = fmaxf(fmaxf(st[0][r], st[1][r]), fmaxf(st[2][r], st[3][r]));
            mx = fmaxf(mx, __shfl_xor(mx, 1));
            mx = fmaxf(mx, __shfl_xor(mx, 2));
            mx = fmaxf(mx, __shfl_xor(mx, 4));
            mx = fmaxf(mx, __shfl_xor(mx, 8));
            float mnew = fmaxf(mrow[r], mx);
            float alpha = __expf(mrow[r] - mnew);
            float rs = 0.f;
            #pragma unroll
            for (int nt = 0; nt < 4; ++nt) {
                float p = __expf(st[nt][r] - mnew);
                st[nt][r] = p;
                rs += p;
            }
            rs += __shfl_xor(rs, 1);
            rs += __shfl_xor(rs, 2);
            rs += __shfl_xor(rs, 4);
            rs += __shfl_xor(rs, 8);
            lrow[r] = lrow[r] * alpha + rs;
            mrow[r] = mnew;
            #pragma unroll
            for (int dt = 0; dt < 8; ++dt) acc[dt][r] *= alpha;
        }

        short* pw = Pls[w];
        #pragma unroll
        for (int nt = 0; nt < 4; ++nt)
            #pragma unroll
            for (int r = 0; r < 4; ++r) {
                int row = g * 4 + r;
                pw[row * 64 + (((nt * 2 + (li >> 3)) ^ (row & 7)) * 8) + (li & 7)]
                    = f2bf(st[nt][r]);
            }
        #pragma unroll
        for (int kk = 0; kk < 2; ++kk) {
            s16x8 af = *(const s16x8*)&pw[li * 64 + (((kk * 4 + g) ^ (li & 7)) * 8)];
            #pragma unroll
            for (int dt = 0; dt < 8; ++dt) {
                s16x8 bfr = *(const s16x8*)&Vls[cur][(dt * 16 + li) * 64
                                                + (((kk * 4 + g) ^ (li & 7)) * 8)];
                mfma_bf16(&acc[dt], af, bfr);
            }
        }
    }
    #undef STAGE

    short* __restrict__ Op = half ? O1 : O0;
    float2* __restrict__ mlp = half ? ml1 : ml0;
    #pragma unroll
    for (int r = 0; r < 4; ++r) {
        int row = q0 + w * 16 + g * 4 + r;
        if (li == 0) mlp[hh * 2048 + row] = make_float2(mrow[r], lrow[r]);
        #pragma unroll
        for (int dt = 0; dt < 8; ++dt)
            Op[(size_t)row * 1024 + hh * 128 + dt * 16 + li] = f2bf(acc[dt][r]);
    }
}

// ---------------- fused combine + out-proj + residual + LN1 ----------------
// per batch: grid 128 blocks x 256 thr; block owns 16 rows; 4-wave K-split
// (wave w handles ks = w*8 .. w*8+7, i.e. heads 2w, 2w+1); LDS reduce.
__global__ __launch_bounds__(256) void k_oproj(
    const short* __restrict__ O0, const short* __restrict__ O1,
    const float2* __restrict__ ml0, const float2* __restrict__ ml1,
    const short* __restrict__ WoT, const float* __restrict__ resid,
    const float* __restrict__ gain, float* __restrict__ outp)
{
    __shared__ float red[3][16 * 128];            // 24 KB partial-acc dump
    const int w = threadIdx.x >> 6, lane = threadIdx.x & 63;
    const int g = lane >> 4, li = lane & 15;
    const int m0 = blockIdx.x * 16;
    const int row = m0 + li;                      // this lane's A-frag row
    float w0[2], w1[2], il[2];                    // this wave's 2 heads
    #pragma unroll
    for (int hi = 0; hi < 2; ++hi) {
        int h = w * 2 + hi;
        float2 a = ml0[h * 2048 + row], bml = ml1[h * 2048 + row];
        float M = fmaxf(a.x, bml.x);
        float e0 = __expf(a.x - M), e1 = __expf(bml.x - M);
        w0[hi] = e0; w1[hi] = e1;
        il[hi] = 1.f / (a.y * e0 + bml.y * e1);
    }
    f32x4 acc[8] = {};
    #pragma unroll
    for (int kq = 0; kq < 8; ++kq) {              // ks = w*8 + kq
        int ks = w * 8 + kq;
        int hi = kq >> 2;
        s16x8 a0 = *(const s16x8*)(O0 + (size_t)row * 1024 + ks * 32 + g * 8);
        s16x8 a1 = *(const s16x8*)(O1 + (size_t)row * 1024 + ks * 32 + g * 8);
        s16x8 a;
        #pragma unroll
        for (int e = 0; e < 8; ++e)
            a[e] = f2bf((bf2f(a0[e]) * w0[hi] + bf2f(a1[e]) * w1[hi]) * il[hi]);
        #pragma unroll
        for (int nt = 0; nt < 8; ++nt) {
            s16x8 bfr = *(const s16x8*)(WoT + (size_t)(nt * 16 + li) * 1024
                                           + ks * 32 + g * 8);
            mfma_bf16(&acc[nt], a, bfr);
        }
    }
    if (w > 0) {
        #pragma unroll
        for (int nt = 0; nt < 8; ++nt)
            #pragma unroll
            for (int r = 0; r < 4; ++r)
                red[w - 1][(g * 4 + r) * 128 + nt * 16 + li] = acc[nt][r];
    }
    __syncthreads();
    if (w == 0) {
        float gv[8];
        #pragma unroll
        for (int nt = 0; nt < 8; ++nt) gv[nt] = gain[nt * 16 + li];
        #pragma unroll
        for (int r = 0; r < 4; ++r) {
            int orow = m0 + g * 4 + r;
            float s = 0.f, s2 = 0.f;
            #pragma unroll
            for (int nt = 0; nt < 8; ++nt) {
                float v = acc[nt][r]
                        + red[0][(g * 4 + r) * 128 + nt * 16 + li]
                        + red[1][(g * 4 + r) * 128 + nt * 16 + li]
                        + red[2][(g * 4 + r) * 128 + nt * 16 + li]
                        + resid[(size_t)orow * 128 + nt * 16 + li];
                acc[nt][r] = v;
                s += v; s2 += v * v;
            }
            s  += __shfl_xor(s, 1);  s  += __shfl_xor(s, 2);
            s  += __shfl_xor(s, 4);  s  += __shfl_xor(s, 8);
            s2 += __shfl_xor(s2, 1); s2 += __shfl_xor(s2, 2);
            s2 += __shfl_xor(s2, 4); s2 += __shfl_xor(s2, 8);
            float mean = s * (1.f / 128.f);
            float var  = s2 * (1.f / 128.f) - mean * mean;
            float rstd = rsqrtf(var + 1e-5f);
            #pragma unroll
            for (int nt = 0; nt < 8; ++nt)
                outp[(size_t)orow * 128 + nt * 16 + li] =
                    (acc[nt][r] - mean) * rstd * gv[nt];
        }
    }
}

// ---------------- fused FFN: LN2(x1 + relu(x1@W1)@W2) -----------------------
// ALL batches: grid (128, 4) x 256 thr; block owns 16 rows; 4-wave split over
// dff chunks (wave w: ch = w*8 .. w*8+7) + LDS reduce; H never stored.
__global__ __launch_bounds__(256) void k_ffn(
    const float* __restrict__ x1, const short* __restrict__ W1T,
    const short* __restrict__ W2T, const float* __restrict__ gain,
    float* __restrict__ outp)
{
    __shared__ __align__(16) short hls[4][16 * 64]; // per-wave h chunk, swizzled
    __shared__ float red[3][16 * 128];              // 24 KB partial-acc dump
    const int w = threadIdx.x >> 6, lane = threadIdx.x & 63;
    const int g = lane >> 4, li = lane & 15;
    const size_t m0 = (size_t)blockIdx.y * 2048 + blockIdx.x * 16;
    s16x8 xf[4];                                  // A-frags, loaded once
    #pragma unroll
    for (int ks = 0; ks < 4; ++ks) {
        const float* xr = x1 + (m0 + li) * 128 + ks * 32 + g * 8;
        float4 v0 = *(const float4*)xr, v1 = *(const float4*)(xr + 4);
        xf[ks] = (s16x8){ f2bf(v0.x), f2bf(v0.y), f2bf(v0.z), f2bf(v0.w),
                          f2bf(v1.x), f2bf(v1.y), f2bf(v1.z), f2bf(v1.w) };
    }
    f32x4 acc[8] = {};
    #pragma unroll 1
    for (int cq = 0; cq < 8; ++cq) {              // ch = w*8 + cq
        int ch = w * 8 + cq;
        f32x4 st[4];                              // GEMM1: h = relu(x@W1 chunk)
        #pragma unroll
        for (int nt = 0; nt < 4; ++nt) {
            st[nt] = (f32x4){0.f, 0.f, 0.f, 0.f};
            #pragma unroll
            for (int ks = 0; ks < 4; ++ks) {
                s16x8 bfr = *(const s16x8*)(W1T + (size_t)(ch * 64 + nt * 16 + li) * 128
                                               + ks * 32 + g * 8);
                mfma_bf16(&st[nt], xf[ks], bfr);
            }
        }
        short* hw = hls[w];
        #pragma unroll
        for (int nt = 0; nt < 4; ++nt)            // stage h -> LDS (P pattern)
            #pragma unroll
            for (int r = 0; r < 4; ++r) {
                int rw = g * 4 + r;
                hw[rw * 64 + (((nt * 2 + (li >> 3)) ^ (rw & 7)) * 8) + (li & 7)]
                    = f2bf(fmaxf(st[nt][r], 0.f));
            }
        #pragma unroll
        for (int kk = 0; kk < 2; ++kk) {          // GEMM2: acc += h @ W2 chunk
            s16x8 af = *(const s16x8*)&hw[li * 64 + (((kk * 4 + g) ^ (li & 7)) * 8)];
            #pragma unroll
            for (int nt = 0; nt < 8; ++nt) {
                s16x8 bfr = *(const s16x8*)(W2T + (size_t)(nt * 16 + li) * 2048
                                               + ch * 64 + kk * 32 + g * 8);
                mfma_bf16(&acc[nt], af, bfr);
            }
        }
    }
    if (w > 0) {
        #pragma unroll
        for (int nt = 0; nt < 8; ++nt)
            #pragma unroll
            for (int r = 0; r < 4; ++r)
                red[w - 1][(g * 4 + r) * 128 + nt * 16 + li] = acc[nt][r];
    }
    __syncthreads();
    if (w == 0) {
        float gv[8];
        #pragma unroll
        for (int nt = 0; nt < 8; ++nt) gv[nt] = gain[nt * 16 + li];
        #pragma unroll
        for (int r = 0; r < 4; ++r) {
            size_t orow = m0 + g * 4 + r;
            float s = 0.f, s2 = 0.f;
            #pragma unroll
            for (int nt = 0; nt < 8; ++nt) {
                float v = acc[nt][r]
                        + red[0][(g * 4 + r) * 128 + nt * 16 + li]
                        + red[1][(g * 4 + r) * 128 + nt * 16 + li]
                        + red[2][(g * 4 + r) * 128 + nt * 16 + li]
                        + x1[orow * 128 + nt * 16 + li];
                acc[nt][r] = v;
                s += v; s2 += v * v;
            }
            s  += __shfl_xor(s, 1);  s  += __shfl_xor(s, 2);
            s  += __shfl_xor(s, 4);  s  += __shfl_xor(s, 8);
            s2 += __shfl_xor(s2, 1); s2 += __shfl_xor(s2, 2);
            s2 += __shfl_xor(s2, 4); s2 += __shfl_xor(s2, 8);
            float mean = s * (1.f / 128.f);
            float var  = s2 * (1.f / 128.f) - mean * mean;
            float rstd = rsqrtf(var + 1e-5f);
            #pragma unroll
            for (int nt = 0; nt < 8; ++nt)
                outp[orow * 128 + nt * 16 + li] = (acc[nt][r] - mean) * rstd * gv[nt];
        }
    }
}

// ---------------------------------------------------------------------------
extern "C" void kernel_launch(void* const* d_in, const int* in_sizes, int n_in,
                              void* d_out, int out_size, void* d_ws, size_t ws_size,
                              hipStream_t stream)
{
    const float* x  = (const float*)d_in[0];
    const float* Wq = (const float*)d_in[1];
    const float* Wk = (const float*)d_in[2];
    const float* Wv = (const float*)d_in[3];
    const float* Wo = (const float*)d_in[4];
    const float* W1 = (const float*)d_in[5];
    const float* W2 = (const float*)d_in[6];
    const float* g1 = (const float*)d_in[7];
    const float* g2 = (const float*)d_in[8];
    float* out = (float*)d_out;
    (void)in_sizes; (void)n_in; (void)out_size; (void)ws_size;

    char* basep = (char*)d_ws;
    size_t off = 0;
    auto carve = [&](size_t bytes) {
        void* q = basep + off;
        off += (bytes + 255) & ~(size_t)255;
        return q;
    };
    // total ~22.3 MB (green proven to 23.3 in r12/r13)
    short*  WqT = (short*)carve(1024ull * 128 * 2);       // 256 KB
    short*  WkT = (short*)carve(1024ull * 128 * 2);
    short*  WvT = (short*)carve(1024ull * 128 * 2);
    short*  WoT = (short*)carve(128ull * 1024 * 2);       // 256 KB
    short*  W1T = (short*)carve(2048ull * 128 * 2);       // 512 KB
    short*  W2T = (short*)carve(128ull * 2048 * 2);       // 512 KB
    short*  Qh  = (short*)carve(8ull * 2048 * 128 * 2);   // 4 MB (8 heads)
    short*  Kh  = (short*)carve(8ull * 2048 * 128 * 2);   // 4 MB
    short*  Vt  = (short*)carve(8ull * 32 * 128 * 64 * 2);// 4 MB (tile-blocked)
    short*  O0  = (short*)carve(2048ull * 1024 * 2);      // 4 MB
    short*  O1  = (short*)carve(2048ull * 1024 * 2);      // 4 MB
    float2* ml0 = (float2*)carve(8ull * 2048 * 8);        // 128 KB
    float2* ml1 = (float2*)carve(8ull * 2048 * 8);        // 128 KB

    // weight prep
    k_transpose_w<<<512,  256, 0, stream>>>(Wq, WqT, 128, 10);
    k_transpose_w<<<512,  256, 0, stream>>>(Wk, WkT, 128, 10);
    k_transpose_w<<<512,  256, 0, stream>>>(Wv, WvT, 128, 10);
    k_transpose_w<<<512,  256, 0, stream>>>(Wo, WoT, 1024, 7);
    k_transpose_w<<<1024, 256, 0, stream>>>(W1, W1T, 128, 11);
    k_transpose_w<<<1024, 256, 0, stream>>>(W2, W2T, 2048, 7);

    // ---- stage A per batch: qkv -> attention -> fused oproj+LN1 ----
    for (int b = 0; b < 4; ++b) {
        const float* xb = x + (size_t)b * 2048 * 128;
        float* x1b = out + (size_t)b * 2048 * 128;   // x1 lives in d_out rows
        k_qkv<<<dim3(32, 16, 3), 256, 0, stream>>>(xb, WqT, WkT, WvT, Qh, Kh, Vt);
        k_attn<<<dim3(32, 8, 2), 256, 0, stream>>>(Qh, Kh, Vt, O0, O1, ml0, ml1);
        k_oproj<<<128, 256, 0, stream>>>(O0, O1, ml0, ml1, WoT, xb, g1, x1b);
    }

    // ---- stage B: fused FFN + LN2, ALL batches, one launch ----
    k_ffn<<<dim3(128, 4), 256, 0, stream>>>(out, W1T, W2T, g2, out);
}

// Round 16
// 431.839 us; speedup vs baseline: 5.1982x; 1.0317x over previous
//
#include <hip/hip_runtime.h>
#include <stdint.h>

// ---------------------------------------------------------------------------
// TransformerEncoderLayer: b=4 s=2048 d=128 h=8 (head_dim=128) dff=2048
// Round-16:
//  - k_ffn: 32 rows/block (weight frags reused across 2 M-tiles), unroll-2
//    chunk loop (cross-chunk pipelining); halves L2 weight traffic.
//  - k_attn: defer-max (T13): wave-uniform skip of rescale when max growth <=8.
//  - all 6 weight transposes in ONE launch.
// Everything else byte-identical to r15 (green).
// ---------------------------------------------------------------------------

using f32x4 = __attribute__((ext_vector_type(4))) float;
using s16x8 = __attribute__((ext_vector_type(8))) short;
using s16x4 = __attribute__((ext_vector_type(4))) short;
typedef __bf16 bf16x8 __attribute__((ext_vector_type(8)));

__device__ inline void mfma_bf16(f32x4* acc, s16x8 a, s16x8 b) {
    *acc = __builtin_amdgcn_mfma_f32_16x16x32_bf16(
        __builtin_bit_cast(bf16x8, a), __builtin_bit_cast(bf16x8, b), *acc, 0, 0, 0);
}

__device__ inline short f2bf(float f) {   // RNE f32 -> bf16 bits
    uint32_t u = __builtin_bit_cast(uint32_t, f);
    u += 0x7fffu + ((u >> 16) & 1u);
    return (short)(u >> 16);
}

__device__ inline float bf2f(short s) {
    return __builtin_bit_cast(float, (uint32_t)((uint16_t)s) << 16);
}

// async global->LDS, 16B per lane; LDS dest = wave-uniform base + lane*16
__device__ inline void gload16(const short* g, short* l) {
    __builtin_amdgcn_global_load_lds(
        (const __attribute__((address_space(1))) void*)g,
        (__attribute__((address_space(3))) void*)l, 16, 0, 0);
}

// ---------------- ALL weight transposes, one launch ------------------------
// w [R][C] f32 (C=1<<lc) -> wt [C][R] bf16; ranges switched on blockIdx.x.
__global__ __launch_bounds__(256) void k_transpose_all(
    const float* __restrict__ Wq, const float* __restrict__ Wk,
    const float* __restrict__ Wv, const float* __restrict__ Wo,
    const float* __restrict__ W1, const float* __restrict__ W2,
    short* __restrict__ WqT, short* __restrict__ WkT, short* __restrict__ WvT,
    short* __restrict__ WoT, short* __restrict__ W1T, short* __restrict__ W2T)
{
    int b = blockIdx.x;
    const float* w; short* wt; int R, lc, lb;
    if (b < 512)       { w = Wq; wt = WqT; R = 128;  lc = 10; lb = 0;    }
    else if (b < 1024) { w = Wk; wt = WkT; R = 128;  lc = 10; lb = 512;  }
    else if (b < 1536) { w = Wv; wt = WvT; R = 128;  lc = 10; lb = 1024; }
    else if (b < 2048) { w = Wo; wt = WoT; R = 1024; lc = 7;  lb = 1536; }
    else if (b < 3072) { w = W1; wt = W1T; R = 128;  lc = 11; lb = 2048; }
    else               { w = W2; wt = W2T; R = 2048; lc = 7;  lb = 3072; }
    int i = (b - lb) * 256 + threadIdx.x;
    int r = i >> lc, c = i & ((1 << lc) - 1);
    wt[c * R + r] = f2bf(w[i]);
}

// ---------------- QKV projection (one batch, ALL 8 heads) ------------------
// Q (pre-scaled 1/sqrt(d)), K row-major [h8][2048][128];
// V tile-blocked [h8][kt32][d128][s64].
__global__ __launch_bounds__(256) void k_qkv(
    const float* __restrict__ xB, const short* __restrict__ WqT,
    const short* __restrict__ WkT, const short* __restrict__ WvT,
    short* __restrict__ Qh, short* __restrict__ Kh, short* __restrict__ Vt)
{
    const int z = blockIdx.z;
    const short* __restrict__ WT = (z == 0) ? WqT : (z == 1) ? WkT : WvT; // [1024][128]
    const int w = threadIdx.x >> 6, lane = threadIdx.x & 63;
    const int g = lane >> 4, li = lane & 15;
    const int m0 = blockIdx.x * 64 + w * 16;
    const int n0 = blockIdx.y * 64;               // 0..960
    f32x4 acc[4] = {};
    #pragma unroll
    for (int ks = 0; ks < 4; ++ks) {
        const float* xr = xB + (size_t)(m0 + li) * 128 + ks * 32 + g * 8;
        float4 v0 = *(const float4*)xr, v1 = *(const float4*)(xr + 4);
        s16x8 a = { f2bf(v0.x), f2bf(v0.y), f2bf(v0.z), f2bf(v0.w),
                    f2bf(v1.x), f2bf(v1.y), f2bf(v1.z), f2bf(v1.w) };
        #pragma unroll
        for (int nt = 0; nt < 4; ++nt) {
            s16x8 bfr = *(const s16x8*)(WT + (size_t)(n0 + nt * 16 + li) * 128
                                           + ks * 32 + g * 8);
            mfma_bf16(&acc[nt], a, bfr);
        }
    }
    const float sc = (z == 0) ? 0.088388347648318447f : 1.0f; // 1/sqrt(128) into Q
    #pragma unroll
    for (int nt = 0; nt < 4; ++nt) {
        int col = n0 + nt * 16 + li;              // 0..1023
        int hh = col >> 7, dd = col & 127;        // head, dim
        if (z == 2) {
            int row0 = m0 + g * 4;                // s, multiple of 4
            int kt = row0 >> 6, so = row0 & 63;
            s16x4 o = { f2bf(acc[nt][0]), f2bf(acc[nt][1]),
                        f2bf(acc[nt][2]), f2bf(acc[nt][3]) };
            *(s16x4*)(Vt + (((size_t)hh * 32 + kt) * 128 + dd) * 64 + so) = o;
        } else {
            short* __restrict__ dst = (z == 0) ? Qh : Kh;
            #pragma unroll
            for (int r = 0; r < 4; ++r)
                dst[((size_t)hh * 2048 + m0 + g * 4 + r) * 128 + dd] =
                    f2bf(acc[nt][r] * sc);
        }
    }
}

// ---------------- flash attention, 4 waves/block, kv-split x2, defer-max ---
// grid (32 qblocks of 64 rows, 8 heads, 2 kv-halves) = 512 blocks x 256 thr.
__global__ __launch_bounds__(256) void k_attn(
    const short* __restrict__ Qh, const short* __restrict__ Kh,
    const short* __restrict__ Vt, short* __restrict__ O0,
    short* __restrict__ O1, float2* __restrict__ ml0, float2* __restrict__ ml1)
{
    __shared__ __align__(16) short Kls[2][64 * 128];   // swizzled [k][d], dbuf
    __shared__ __align__(16) short Vls[2][128 * 64];   // swizzled [d][k], dbuf
    __shared__ __align__(16) short Pls[4][16 * 64];    // per-wave swizzled [q][k]
    const int hh = blockIdx.y;
    const int half = blockIdx.z;
    const size_t base  = (size_t)hh * 2048 * 128;
    const size_t vbase = (size_t)hh * 32 * 8192;       // tile-blocked V^T
    const int w = threadIdx.x >> 6, lane = threadIdx.x & 63;
    const int g = lane >> 4, li = lane & 15;
    const int q0 = blockIdx.x * 64;
    const int qw = q0 + w * 16;
    const int kt0 = half * 16;

    #define STAGE(BUF, KT)                                                      \
        { _Pragma("unroll")                                                     \
          for (int c2 = 0; c2 < 4; ++c2) {                                      \
              int ci = c2 * 256 + (int)threadIdx.x;                             \
              int row = ci >> 4, cc = ci & 15;                                  \
              gload16(Kh + base + (size_t)((KT) * 64 + row) * 128               \
                         + ((cc ^ (row & 7)) * 8),                              \
                      &Kls[BUF][(c2 * 256 + w * 64) * 8]);                      \
              int d = ci >> 3, jc = ci & 7;                                     \
              gload16(Vt + vbase + (size_t)(KT) * 8192 + d * 64                 \
                         + ((jc ^ (d & 7)) * 8),                                \
                      &Vls[BUF][(c2 * 256 + w * 64) * 8]);                      \
          } }

    s16x8 qf[4];
    #pragma unroll
    for (int ks = 0; ks < 4; ++ks)
        qf[ks] = *(const s16x8*)(Qh + base + (size_t)(qw + li) * 128 + ks * 32 + g * 8);

    f32x4 acc[8] = {};
    float mrow[4] = { -1e30f, -1e30f, -1e30f, -1e30f };
    float lrow[4] = { 0.f, 0.f, 0.f, 0.f };

    STAGE(0, kt0);
    for (int t = 0; t < 16; ++t) {
        const int cur = t & 1;
        __syncthreads();                  // drains vmcnt: buf[cur] ready
        if (t + 1 < 16) STAGE(cur ^ 1, kt0 + t + 1);   // in flight during compute

        f32x4 st[4];
        #pragma unroll
        for (int nt = 0; nt < 4; ++nt) {
            st[nt] = (f32x4){0.f, 0.f, 0.f, 0.f};
            #pragma unroll
            for (int ks = 0; ks < 4; ++ks) {
                s16x8 bfr = *(const s16x8*)&Kls[cur][(nt * 16 + li) * 128
                                                + (((ks * 4 + g) ^ (li & 7)) * 8)];
                mfma_bf16(&st[nt], qf[ks], bfr);
            }
        }

        // tile max per row + defer-max condition (T13, THR=8)
        float mxv[4];
        bool cond = true;
        #pragma unroll
        for (int r = 0; r < 4; ++r) {
            float mx = fmaxf(fmaxf(st[0][r], st[1][r]), fmaxf(st[2][r], st[3][r]));
            mx = fmaxf(mx, __shfl_xor(mx, 1));
            mx = fmaxf(mx, __shfl_xor(mx, 2));
            mx = fmaxf(mx, __shfl_xor(mx, 4));
            mx = fmaxf(mx, __shfl_xor(mx, 8));
            mxv[r] = mx;
            cond = cond && (mx <= mrow[r] + 8.f);
        }
        if (__all(cond)) {
            // no rescale: P = exp(s - m_old) bounded by e^8; acc/m unchanged
            #pragma unroll
            for (int r = 0; r < 4; ++r) {
                float rs = 0.f;
                #pragma unroll
                for (int nt = 0; nt < 4; ++nt) {
                    float p = __expf(st[nt][r] - mrow[r]);
                    st[nt][r] = p;
                    rs += p;
                }
                rs += __shfl_xor(rs, 1);
                rs += __shfl_xor(rs, 2);
                rs += __shfl_xor(rs, 4);
                rs += __shfl_xor(rs, 8);
                lrow[r] += rs;
            }
        } else {
            #pragma unroll
            for (int r = 0; r < 4; ++r) {
                float mnew = fmaxf(mrow[r], mxv[r]);
                float alpha = __expf(mrow[r] - mnew);
                float rs = 0.f;
                #pragma unroll
                for (int nt = 0; nt < 4; ++nt) {
                    float p = __expf(st[nt][r] - mnew);
                    st[nt][r] = p;
                    rs += p;
                }
                rs += __shfl_xor(rs, 1);
                rs += __shfl_xor(rs, 2);
                rs += __shfl_xor(rs, 4);
                rs += __shfl_xor(rs, 8);
                lrow[r] = lrow[r] * alpha + rs;
                mrow[r] = mnew;
                #pragma unroll
                for (int dt = 0; dt < 8; ++dt) acc[dt][r] *= alpha;
            }
        }

        short* pw = Pls[w];
        #pragma unroll
        for (int nt = 0; nt < 4; ++nt)
            #pragma unroll
            for (int r = 0; r < 4; ++r) {
                int row = g * 4 + r;
                pw[row * 64 + (((nt * 2 + (li >> 3)) ^ (row & 7)) * 8) + (li & 7)]
                    = f2bf(st[nt][r]);
            }
        #pragma unroll
        for (int kk = 0; kk < 2; ++kk) {
            s16x8 af = *(const s16x8*)&pw[li * 64 + (((kk * 4 + g) ^ (li & 7)) * 8)];
            #pragma unroll
            for (int dt = 0; dt < 8; ++dt) {
                s16x8 bfr = *(const s16x8*)&Vls[cur][(dt * 16 + li) * 64
                                                + (((kk * 4 + g) ^ (li & 7)) * 8)];
                mfma_bf16(&acc[dt], af, bfr);
            }
        }
    }
    #undef STAGE

    short* __restrict__ Op = half ? O1 : O0;
    float2* __restrict__ mlp = half ? ml1 : ml0;
    #pragma unroll
    for (int r = 0; r < 4; ++r) {
        int row = q0 + w * 16 + g * 4 + r;
        if (li == 0) mlp[hh * 2048 + row] = make_float2(mrow[r], lrow[r]);
        #pragma unroll
        for (int dt = 0; dt < 8; ++dt)
            Op[(size_t)row * 1024 + hh * 128 + dt * 16 + li] = f2bf(acc[dt][r]);
    }
}

// ---------------- fused combine + out-proj + residual + LN1 ----------------
// per batch: grid 128 blocks x 256 thr; block owns 16 rows; 4-wave K-split.
__global__ __launch_bounds__(256) void k_oproj(
    const short* __restrict__ O0, const short* __restrict__ O1,
    const float2* __restrict__ ml0, const float2* __restrict__ ml1,
    const short* __restrict__ WoT, const float* __restrict__ resid,
    const float* __restrict__ gain, float* __restrict__ outp)
{
    __shared__ float red[3][16 * 128];            // 24 KB partial-acc dump
    const int w = threadIdx.x >> 6, lane = threadIdx.x & 63;
    const int g = lane >> 4, li = lane & 15;
    const int m0 = blockIdx.x * 16;
    const int row = m0 + li;                      // this lane's A-frag row
    float w0[2], w1[2], il[2];                    // this wave's 2 heads
    #pragma unroll
    for (int hi = 0; hi < 2; ++hi) {
        int h = w * 2 + hi;
        float2 a = ml0[h * 2048 + row], bml = ml1[h * 2048 + row];
        float M = fmaxf(a.x, bml.x);
        float e0 = __expf(a.x - M), e1 = __expf(bml.x - M);
        w0[hi] = e0; w1[hi] = e1;
        il[hi] = 1.f / (a.y * e0 + bml.y * e1);
    }
    f32x4 acc[8] = {};
    #pragma unroll
    for (int kq = 0; kq < 8; ++kq) {              // ks = w*8 + kq
        int ks = w * 8 + kq;
        int hi = kq >> 2;
        s16x8 a0 = *(const s16x8*)(O0 + (size_t)row * 1024 + ks * 32 + g * 8);
        s16x8 a1 = *(const s16x8*)(O1 + (size_t)row * 1024 + ks * 32 + g * 8);
        s16x8 a;
        #pragma unroll
        for (int e = 0; e < 8; ++e)
            a[e] = f2bf((bf2f(a0[e]) * w0[hi] + bf2f(a1[e]) * w1[hi]) * il[hi]);
        #pragma unroll
        for (int nt = 0; nt < 8; ++nt) {
            s16x8 bfr = *(const s16x8*)(WoT + (size_t)(nt * 16 + li) * 1024
                                           + ks * 32 + g * 8);
            mfma_bf16(&acc[nt], a, bfr);
        }
    }
    if (w > 0) {
        #pragma unroll
        for (int nt = 0; nt < 8; ++nt)
            #pragma unroll
            for (int r = 0; r < 4; ++r)
                red[w - 1][(g * 4 + r) * 128 + nt * 16 + li] = acc[nt][r];
    }
    __syncthreads();
    if (w == 0) {
        float gv[8];
        #pragma unroll
        for (int nt = 0; nt < 8; ++nt) gv[nt] = gain[nt * 16 + li];
        #pragma unroll
        for (int r = 0; r < 4; ++r) {
            int orow = m0 + g * 4 + r;
            float s = 0.f, s2 = 0.f;
            #pragma unroll
            for (int nt = 0; nt < 8; ++nt) {
                float v = acc[nt][r]
                        + red[0][(g * 4 + r) * 128 + nt * 16 + li]
                        + red[1][(g * 4 + r) * 128 + nt * 16 + li]
                        + red[2][(g * 4 + r) * 128 + nt * 16 + li]
                        + resid[(size_t)orow * 128 + nt * 16 + li];
                acc[nt][r] = v;
                s += v; s2 += v * v;
            }
            s  += __shfl_xor(s, 1);  s  += __shfl_xor(s, 2);
            s  += __shfl_xor(s, 4);  s  += __shfl_xor(s, 8);
            s2 += __shfl_xor(s2, 1); s2 += __shfl_xor(s2, 2);
            s2 += __shfl_xor(s2, 4); s2 += __shfl_xor(s2, 8);
            float mean = s * (1.f / 128.f);
            float var  = s2 * (1.f / 128.f) - mean * mean;
            float rstd = rsqrtf(var + 1e-5f);
            #pragma unroll
            for (int nt = 0; nt < 8; ++nt)
                outp[(size_t)orow * 128 + nt * 16 + li] =
                    (acc[nt][r] - mean) * rstd * gv[nt];
        }
    }
}

// ---------------- fused FFN: LN2(x1 + relu(x1@W1)@W2) -----------------------
// ALL batches: grid (64, 4) x 256 thr; block owns 32 rows (2 M-tiles share
// every weight fragment); 4-wave split over dff chunks + LDS reduce.
__global__ __launch_bounds__(256) void k_ffn(
    const float* __restrict__ x1, const short* __restrict__ W1T,
    const short* __restrict__ W2T, const float* __restrict__ gain,
    float* __restrict__ outp)
{
    __shared__ __align__(16) short hls[4][2][16 * 64]; // [wave][mt], swizzled
    __shared__ float red[3][2][16 * 128];              // 48 KB partial-acc dump
    const int w = threadIdx.x >> 6, lane = threadIdx.x & 63;
    const int g = lane >> 4, li = lane & 15;
    const size_t m0 = (size_t)blockIdx.y * 2048 + blockIdx.x * 32;
    s16x8 xf[2][4];                               // A-frags, loaded once
    #pragma unroll
    for (int mt = 0; mt < 2; ++mt)
        #pragma unroll
        for (int ks = 0; ks < 4; ++ks) {
            const float* xr = x1 + (m0 + mt * 16 + li) * 128 + ks * 32 + g * 8;
            float4 v0 = *(const float4*)xr, v1 = *(const float4*)(xr + 4);
            xf[mt][ks] = (s16x8){ f2bf(v0.x), f2bf(v0.y), f2bf(v0.z), f2bf(v0.w),
                                  f2bf(v1.x), f2bf(v1.y), f2bf(v1.z), f2bf(v1.w) };
        }
    f32x4 acc[2][8] = {};
    #pragma unroll 2
    for (int cq = 0; cq < 8; ++cq) {              // ch = w*8 + cq
        int ch = w * 8 + cq;
        f32x4 st[2][4] = {};                      // GEMM1: h = relu(x@W1 chunk)
        #pragma unroll
        for (int nt = 0; nt < 4; ++nt)
            #pragma unroll
            for (int ks = 0; ks < 4; ++ks) {
                s16x8 bfr = *(const s16x8*)(W1T + (size_t)(ch * 64 + nt * 16 + li) * 128
                                               + ks * 32 + g * 8);
                mfma_bf16(&st[0][nt], xf[0][ks], bfr);
                mfma_bf16(&st[1][nt], xf[1][ks], bfr);
            }
        #pragma unroll
        for (int mt = 0; mt < 2; ++mt) {          // stage h -> LDS (P pattern)
            short* hw = hls[w][mt];
            #pragma unroll
            for (int nt = 0; nt < 4; ++nt)
                #pragma unroll
                for (int r = 0; r < 4; ++r) {
                    int rw = g * 4 + r;
                    hw[rw * 64 + (((nt * 2 + (li >> 3)) ^ (rw & 7)) * 8) + (li & 7)]
                        = f2bf(fmaxf(st[mt][nt][r], 0.f));
                }
        }
        #pragma unroll
        for (int kk = 0; kk < 2; ++kk) {          // GEMM2: acc += h @ W2 chunk
            s16x8 af0 = *(const s16x8*)&hls[w][0][li * 64
                                                  + (((kk * 4 + g) ^ (li & 7)) * 8)];
            s16x8 af1 = *(const s16x8*)&hls[w][1][li * 64
                                                  + (((kk * 4 + g) ^ (li & 7)) * 8)];
            #pragma unroll
            for (int nt = 0; nt < 8; ++nt) {
                s16x8 bfr = *(const s16x8*)(W2T + (size_t)(nt * 16 + li) * 2048
                                               + ch * 64 + kk * 32 + g * 8);
                mfma_bf16(&acc[0][nt], af0, bfr);
                mfma_bf16(&acc[1][nt], af1, bfr);
            }
        }
    }
    if (w > 0) {
        #pragma unroll
        for (int mt = 0; mt < 2; ++mt)
            #pragma unroll
            for (int nt = 0; nt < 8; ++nt)
                #pragma unroll
                for (int r = 0; r < 4; ++r)
                    red[w - 1][mt][(g * 4 + r) * 128 + nt * 16 + li] = acc[mt][nt][r];
    }
    __syncthreads();
    if (w == 0) {
        float gv[8];
        #pragma unroll
        for (int nt = 0; nt < 8; ++nt) gv[nt] = gain[nt * 16 + li];
        #pragma unroll
        for (int mt = 0; mt < 2; ++mt)
            #pragma unroll
            for (int r = 0; r < 4; ++r) {
                size_t orow = m0 + mt * 16 + g * 4 + r;
                float s = 0.f, s2 = 0.f;
                #pragma unroll
                for (int nt = 0; nt < 8; ++nt) {
                    float v = acc[mt][nt][r]
                            + red[0][mt][(g * 4 + r) * 128 + nt * 16 + li]
                            + red[1][mt][(g * 4 + r) * 128 + nt * 16 + li]
                            + red[2][mt][(g * 4 + r) * 128 + nt * 16 + li]
                            + x1[orow * 128 + nt * 16 + li];
                    acc[mt][nt][r] = v;
                    s += v; s2 += v * v;
                }
                s  += __shfl_xor(s, 1);  s  += __shfl_xor(s, 2);
                s  += __shfl_xor(s, 4);  s  += __shfl_xor(s, 8);
                s2 += __shfl_xor(s2, 1); s2 += __shfl_xor(s2, 2);
                s2 += __shfl_xor(s2, 4); s2 += __shfl_xor(s2, 8);
                float mean = s * (1.f / 128.f);
                float var  = s2 * (1.f / 128.f) - mean * mean;
                float rstd = rsqrtf(var + 1e-5f);
                #pragma unroll
                for (int nt = 0; nt < 8; ++nt)
                    outp[orow * 128 + nt * 16 + li] =
                        (acc[mt][nt][r] - mean) * rstd * gv[nt];
            }
    }
}

// ---------------------------------------------------------------------------
extern "C" void kernel_launch(void* const* d_in, const int* in_sizes, int n_in,
                              void* d_out, int out_size, void* d_ws, size_t ws_size,
                              hipStream_t stream)
{
    const float* x  = (const float*)d_in[0];
    const float* Wq = (const float*)d_in[1];
    const float* Wk = (const float*)d_in[2];
    const float* Wv = (const float*)d_in[3];
    const float* Wo = (const float*)d_in[4];
    const float* W1 = (const float*)d_in[5];
    const float* W2 = (const float*)d_in[6];
    const float* g1 = (const float*)d_in[7];
    const float* g2 = (const float*)d_in[8];
    float* out = (float*)d_out;
    (void)in_sizes; (void)n_in; (void)out_size; (void)ws_size;

    char* basep = (char*)d_ws;
    size_t off = 0;
    auto carve = [&](size_t bytes) {
        void* q = basep + off;
        off += (bytes + 255) & ~(size_t)255;
        return q;
    };
    // total ~22.3 MB (green proven to 23.3 in r12/r13)
    short*  WqT = (short*)carve(1024ull * 128 * 2);       // 256 KB
    short*  WkT = (short*)carve(1024ull * 128 * 2);
    short*  WvT = (short*)carve(1024ull * 128 * 2);
    short*  WoT = (short*)carve(128ull * 1024 * 2);       // 256 KB
    short*  W1T = (short*)carve(2048ull * 128 * 2);       // 512 KB
    short*  W2T = (short*)carve(128ull * 2048 * 2);       // 512 KB
    short*  Qh  = (short*)carve(8ull * 2048 * 128 * 2);   // 4 MB (8 heads)
    short*  Kh  = (short*)carve(8ull * 2048 * 128 * 2);   // 4 MB
    short*  Vt  = (short*)carve(8ull * 32 * 128 * 64 * 2);// 4 MB (tile-blocked)
    short*  O0  = (short*)carve(2048ull * 1024 * 2);      // 4 MB
    short*  O1  = (short*)carve(2048ull * 1024 * 2);      // 4 MB
    float2* ml0 = (float2*)carve(8ull * 2048 * 8);        // 128 KB
    float2* ml1 = (float2*)carve(8ull * 2048 * 8);        // 128 KB

    // weight prep: ONE launch
    k_transpose_all<<<4096, 256, 0, stream>>>(Wq, Wk, Wv, Wo, W1, W2,
                                              WqT, WkT, WvT, WoT, W1T, W2T);

    // ---- stage A per batch: qkv -> attention -> fused oproj+LN1 ----
    for (int b = 0; b < 4; ++b) {
        const float* xb = x + (size_t)b * 2048 * 128;
        float* x1b = out + (size_t)b * 2048 * 128;   // x1 lives in d_out rows
        k_qkv<<<dim3(32, 16, 3), 256, 0, stream>>>(xb, WqT, WkT, WvT, Qh, Kh, Vt);
        k_attn<<<dim3(32, 8, 2), 256, 0, stream>>>(Qh, Kh, Vt, O0, O1, ml0, ml1);
        k_oproj<<<128, 256, 0, stream>>>(O0, O1, ml0, ml1, WoT, xb, g1, x1b);
    }

    // ---- stage B: fused FFN + LN2, ALL batches, one launch ----
    k_ffn<<<dim3(64, 4), 256, 0, stream>>>(out, W1T, W2T, g2, out);
}

// Round 17
// 386.064 us; speedup vs baseline: 5.8146x; 1.1186x over previous
//
#include <hip/hip_runtime.h>
#include <stdint.h>

// ---------------------------------------------------------------------------
// TransformerEncoderLayer: b=4 s=2048 d=128 h=8 (head_dim=128) dff=2048
// Round-17:
//  - k_attn: shuffle-free softmax common path (defer-max check via per-lane
//    __all; lrow kept as per-lane partial, reduced once in epilogue).
//  - k_ffn: unroll-4 chunk loop (1 wave/SIMD -> ILP is the only latency hiding).
// Everything else byte-identical to r16 (green).
// ---------------------------------------------------------------------------

using f32x4 = __attribute__((ext_vector_type(4))) float;
using s16x8 = __attribute__((ext_vector_type(8))) short;
using s16x4 = __attribute__((ext_vector_type(4))) short;
typedef __bf16 bf16x8 __attribute__((ext_vector_type(8)));

__device__ inline void mfma_bf16(f32x4* acc, s16x8 a, s16x8 b) {
    *acc = __builtin_amdgcn_mfma_f32_16x16x32_bf16(
        __builtin_bit_cast(bf16x8, a), __builtin_bit_cast(bf16x8, b), *acc, 0, 0, 0);
}

__device__ inline short f2bf(float f) {   // RNE f32 -> bf16 bits
    uint32_t u = __builtin_bit_cast(uint32_t, f);
    u += 0x7fffu + ((u >> 16) & 1u);
    return (short)(u >> 16);
}

__device__ inline float bf2f(short s) {
    return __builtin_bit_cast(float, (uint32_t)((uint16_t)s) << 16);
}

// async global->LDS, 16B per lane; LDS dest = wave-uniform base + lane*16
__device__ inline void gload16(const short* g, short* l) {
    __builtin_amdgcn_global_load_lds(
        (const __attribute__((address_space(1))) void*)g,
        (__attribute__((address_space(3))) void*)l, 16, 0, 0);
}

// ---------------- ALL weight transposes, one launch ------------------------
__global__ __launch_bounds__(256) void k_transpose_all(
    const float* __restrict__ Wq, const float* __restrict__ Wk,
    const float* __restrict__ Wv, const float* __restrict__ Wo,
    const float* __restrict__ W1, const float* __restrict__ W2,
    short* __restrict__ WqT, short* __restrict__ WkT, short* __restrict__ WvT,
    short* __restrict__ WoT, short* __restrict__ W1T, short* __restrict__ W2T)
{
    int b = blockIdx.x;
    const float* w; short* wt; int R, lc, lb;
    if (b < 512)       { w = Wq; wt = WqT; R = 128;  lc = 10; lb = 0;    }
    else if (b < 1024) { w = Wk; wt = WkT; R = 128;  lc = 10; lb = 512;  }
    else if (b < 1536) { w = Wv; wt = WvT; R = 128;  lc = 10; lb = 1024; }
    else if (b < 2048) { w = Wo; wt = WoT; R = 1024; lc = 7;  lb = 1536; }
    else if (b < 3072) { w = W1; wt = W1T; R = 128;  lc = 11; lb = 2048; }
    else               { w = W2; wt = W2T; R = 2048; lc = 7;  lb = 3072; }
    int i = (b - lb) * 256 + threadIdx.x;
    int r = i >> lc, c = i & ((1 << lc) - 1);
    wt[c * R + r] = f2bf(w[i]);
}

// ---------------- QKV projection (one batch, ALL 8 heads) ------------------
// Q (pre-scaled 1/sqrt(d)), K row-major [h8][2048][128];
// V tile-blocked [h8][kt32][d128][s64].
__global__ __launch_bounds__(256) void k_qkv(
    const float* __restrict__ xB, const short* __restrict__ WqT,
    const short* __restrict__ WkT, const short* __restrict__ WvT,
    short* __restrict__ Qh, short* __restrict__ Kh, short* __restrict__ Vt)
{
    const int z = blockIdx.z;
    const short* __restrict__ WT = (z == 0) ? WqT : (z == 1) ? WkT : WvT; // [1024][128]
    const int w = threadIdx.x >> 6, lane = threadIdx.x & 63;
    const int g = lane >> 4, li = lane & 15;
    const int m0 = blockIdx.x * 64 + w * 16;
    const int n0 = blockIdx.y * 64;               // 0..960
    f32x4 acc[4] = {};
    #pragma unroll
    for (int ks = 0; ks < 4; ++ks) {
        const float* xr = xB + (size_t)(m0 + li) * 128 + ks * 32 + g * 8;
        float4 v0 = *(const float4*)xr, v1 = *(const float4*)(xr + 4);
        s16x8 a = { f2bf(v0.x), f2bf(v0.y), f2bf(v0.z), f2bf(v0.w),
                    f2bf(v1.x), f2bf(v1.y), f2bf(v1.z), f2bf(v1.w) };
        #pragma unroll
        for (int nt = 0; nt < 4; ++nt) {
            s16x8 bfr = *(const s16x8*)(WT + (size_t)(n0 + nt * 16 + li) * 128
                                           + ks * 32 + g * 8);
            mfma_bf16(&acc[nt], a, bfr);
        }
    }
    const float sc = (z == 0) ? 0.088388347648318447f : 1.0f; // 1/sqrt(128) into Q
    #pragma unroll
    for (int nt = 0; nt < 4; ++nt) {
        int col = n0 + nt * 16 + li;              // 0..1023
        int hh = col >> 7, dd = col & 127;        // head, dim
        if (z == 2) {
            int row0 = m0 + g * 4;                // s, multiple of 4
            int kt = row0 >> 6, so = row0 & 63;
            s16x4 o = { f2bf(acc[nt][0]), f2bf(acc[nt][1]),
                        f2bf(acc[nt][2]), f2bf(acc[nt][3]) };
            *(s16x4*)(Vt + (((size_t)hh * 32 + kt) * 128 + dd) * 64 + so) = o;
        } else {
            short* __restrict__ dst = (z == 0) ? Qh : Kh;
            #pragma unroll
            for (int r = 0; r < 4; ++r)
                dst[((size_t)hh * 2048 + m0 + g * 4 + r) * 128 + dd] =
                    f2bf(acc[nt][r] * sc);
        }
    }
}

// ---------------- flash attention, 4 waves/block, kv-split x2 --------------
// grid (32 qblocks of 64 rows, 8 heads, 2 kv-halves) = 512 blocks x 256 thr.
// Softmax: shuffle-free common path (per-lane defer check, per-lane l partial).
__global__ __launch_bounds__(256) void k_attn(
    const short* __restrict__ Qh, const short* __restrict__ Kh,
    const short* __restrict__ Vt, short* __restrict__ O0,
    short* __restrict__ O1, float2* __restrict__ ml0, float2* __restrict__ ml1)
{
    __shared__ __align__(16) short Kls[2][64 * 128];   // swizzled [k][d], dbuf
    __shared__ __align__(16) short Vls[2][128 * 64];   // swizzled [d][k], dbuf
    __shared__ __align__(16) short Pls[4][16 * 64];    // per-wave swizzled [q][k]
    const int hh = blockIdx.y;
    const int half = blockIdx.z;
    const size_t base  = (size_t)hh * 2048 * 128;
    const size_t vbase = (size_t)hh * 32 * 8192;       // tile-blocked V^T
    const int w = threadIdx.x >> 6, lane = threadIdx.x & 63;
    const int g = lane >> 4, li = lane & 15;
    const int q0 = blockIdx.x * 64;
    const int qw = q0 + w * 16;
    const int kt0 = half * 16;

    #define STAGE(BUF, KT)                                                      \
        { _Pragma("unroll")                                                     \
          for (int c2 = 0; c2 < 4; ++c2) {                                      \
              int ci = c2 * 256 + (int)threadIdx.x;                             \
              int row = ci >> 4, cc = ci & 15;                                  \
              gload16(Kh + base + (size_t)((KT) * 64 + row) * 128               \
                         + ((cc ^ (row & 7)) * 8),                              \
                      &Kls[BUF][(c2 * 256 + w * 64) * 8]);                      \
              int d = ci >> 3, jc = ci & 7;                                     \
              gload16(Vt + vbase + (size_t)(KT) * 8192 + d * 64                 \
                         + ((jc ^ (d & 7)) * 8),                                \
                      &Vls[BUF][(c2 * 256 + w * 64) * 8]);                      \
          } }

    s16x8 qf[4];
    #pragma unroll
    for (int ks = 0; ks < 4; ++ks)
        qf[ks] = *(const s16x8*)(Qh + base + (size_t)(qw + li) * 128 + ks * 32 + g * 8);

    f32x4 acc[8] = {};
    float mrow[4] = { -1e30f, -1e30f, -1e30f, -1e30f };
    float lpart[4] = { 0.f, 0.f, 0.f, 0.f };    // PER-LANE partial of l

    STAGE(0, kt0);
    for (int t = 0; t < 16; ++t) {
        const int cur = t & 1;
        __syncthreads();                  // drains vmcnt: buf[cur] ready
        if (t + 1 < 16) STAGE(cur ^ 1, kt0 + t + 1);   // in flight during compute

        f32x4 st[4];
        #pragma unroll
        for (int nt = 0; nt < 4; ++nt) {
            st[nt] = (f32x4){0.f, 0.f, 0.f, 0.f};
            #pragma unroll
            for (int ks = 0; ks < 4; ++ks) {
                s16x8 bfr = *(const s16x8*)&Kls[cur][(nt * 16 + li) * 128
                                                + (((ks * 4 + g) ^ (li & 7)) * 8)];
                mfma_bf16(&st[nt], qf[ks], bfr);
            }
        }

        // per-LANE max; defer-max check needs NO shuffles:
        // all lanes' local maxes <= thr  <=>  all row maxes <= thr.
        float mxl[4];
        bool cond = true;
        #pragma unroll
        for (int r = 0; r < 4; ++r) {
            mxl[r] = fmaxf(fmaxf(st[0][r], st[1][r]), fmaxf(st[2][r], st[3][r]));
            cond = cond && (mxl[r] <= mrow[r] + 8.f);
        }
        if (__all(cond)) {
            // common path: no rescale, no shuffles; P bounded by e^8
            #pragma unroll
            for (int r = 0; r < 4; ++r) {
                float rs = 0.f;
                #pragma unroll
                for (int nt = 0; nt < 4; ++nt) {
                    float p = __expf(st[nt][r] - mrow[r]);
                    st[nt][r] = p;
                    rs += p;
                }
                lpart[r] += rs;
            }
        } else {
            #pragma unroll
            for (int r = 0; r < 4; ++r) {
                float mx = mxl[r];
                mx = fmaxf(mx, __shfl_xor(mx, 1));
                mx = fmaxf(mx, __shfl_xor(mx, 2));
                mx = fmaxf(mx, __shfl_xor(mx, 4));
                mx = fmaxf(mx, __shfl_xor(mx, 8));
                float mnew = fmaxf(mrow[r], mx);
                float alpha = __expf(mrow[r] - mnew);
                float rs = 0.f;
                #pragma unroll
                for (int nt = 0; nt < 4; ++nt) {
                    float p = __expf(st[nt][r] - mnew);
                    st[nt][r] = p;
                    rs += p;
                }
                lpart[r] = lpart[r] * alpha + rs;   // alpha row-uniform
                mrow[r] = mnew;
                #pragma unroll
                for (int dt = 0; dt < 8; ++dt) acc[dt][r] *= alpha;
            }
        }

        short* pw = Pls[w];
        #pragma unroll
        for (int nt = 0; nt < 4; ++nt)
            #pragma unroll
            for (int r = 0; r < 4; ++r) {
                int row = g * 4 + r;
                pw[row * 64 + (((nt * 2 + (li >> 3)) ^ (row & 7)) * 8) + (li & 7)]
                    = f2bf(st[nt][r]);
            }
        #pragma unroll
        for (int kk = 0; kk < 2; ++kk) {
            s16x8 af = *(const s16x8*)&pw[li * 64 + (((kk * 4 + g) ^ (li & 7)) * 8)];
            #pragma unroll
            for (int dt = 0; dt < 8; ++dt) {
                s16x8 bfr = *(const s16x8*)&Vls[cur][(dt * 16 + li) * 64
                                                + (((kk * 4 + g) ^ (li & 7)) * 8)];
                mfma_bf16(&acc[dt], af, bfr);
            }
        }
    }
    #undef STAGE

    // epilogue: reduce per-lane l partials once
    float lrow[4];
    #pragma unroll
    for (int r = 0; r < 4; ++r) {
        float rs = lpart[r];
        rs += __shfl_xor(rs, 1);
        rs += __shfl_xor(rs, 2);
        rs += __shfl_xor(rs, 4);
        rs += __shfl_xor(rs, 8);
        lrow[r] = rs;
    }
    short* __restrict__ Op = half ? O1 : O0;
    float2* __restrict__ mlp = half ? ml1 : ml0;
    #pragma unroll
    for (int r = 0; r < 4; ++r) {
        int row = q0 + w * 16 + g * 4 + r;
        if (li == 0) mlp[hh * 2048 + row] = make_float2(mrow[r], lrow[r]);
        #pragma unroll
        for (int dt = 0; dt < 8; ++dt)
            Op[(size_t)row * 1024 + hh * 128 + dt * 16 + li] = f2bf(acc[dt][r]);
    }
}

// ---------------- fused combine + out-proj + residual + LN1 ----------------
// per batch: grid 128 blocks x 256 thr; block owns 16 rows; 4-wave K-split.
__global__ __launch_bounds__(256) void k_oproj(
    const short* __restrict__ O0, const short* __restrict__ O1,
    const float2* __restrict__ ml0, const float2* __restrict__ ml1,
    const short* __restrict__ WoT, const float* __restrict__ resid,
    const float* __restrict__ gain, float* __restrict__ outp)
{
    __shared__ float red[3][16 * 128];            // 24 KB partial-acc dump
    const int w = threadIdx.x >> 6, lane = threadIdx.x & 63;
    const int g = lane >> 4, li = lane & 15;
    const int m0 = blockIdx.x * 16;
    const int row = m0 + li;                      // this lane's A-frag row
    float w0[2], w1[2], il[2];                    // this wave's 2 heads
    #pragma unroll
    for (int hi = 0; hi < 2; ++hi) {
        int h = w * 2 + hi;
        float2 a = ml0[h * 2048 + row], bml = ml1[h * 2048 + row];
        float M = fmaxf(a.x, bml.x);
        float e0 = __expf(a.x - M), e1 = __expf(bml.x - M);
        w0[hi] = e0; w1[hi] = e1;
        il[hi] = 1.f / (a.y * e0 + bml.y * e1);
    }
    f32x4 acc[8] = {};
    #pragma unroll
    for (int kq = 0; kq < 8; ++kq) {              // ks = w*8 + kq
        int ks = w * 8 + kq;
        int hi = kq >> 2;
        s16x8 a0 = *(const s16x8*)(O0 + (size_t)row * 1024 + ks * 32 + g * 8);
        s16x8 a1 = *(const s16x8*)(O1 + (size_t)row * 1024 + ks * 32 + g * 8);
        s16x8 a;
        #pragma unroll
        for (int e = 0; e < 8; ++e)
            a[e] = f2bf((bf2f(a0[e]) * w0[hi] + bf2f(a1[e]) * w1[hi]) * il[hi]);
        #pragma unroll
        for (int nt = 0; nt < 8; ++nt) {
            s16x8 bfr = *(const s16x8*)(WoT + (size_t)(nt * 16 + li) * 1024
                                           + ks * 32 + g * 8);
            mfma_bf16(&acc[nt], a, bfr);
        }
    }
    if (w > 0) {
        #pragma unroll
        for (int nt = 0; nt < 8; ++nt)
            #pragma unroll
            for (int r = 0; r < 4; ++r)
                red[w - 1][(g * 4 + r) * 128 + nt * 16 + li] = acc[nt][r];
    }
    __syncthreads();
    if (w == 0) {
        float gv[8];
        #pragma unroll
        for (int nt = 0; nt < 8; ++nt) gv[nt] = gain[nt * 16 + li];
        #pragma unroll
        for (int r = 0; r < 4; ++r) {
            int orow = m0 + g * 4 + r;
            float s = 0.f, s2 = 0.f;
            #pragma unroll
            for (int nt = 0; nt < 8; ++nt) {
                float v = acc[nt][r]
                        + red[0][(g * 4 + r) * 128 + nt * 16 + li]
                        + red[1][(g * 4 + r) * 128 + nt * 16 + li]
                        + red[2][(g * 4 + r) * 128 + nt * 16 + li]
                        + resid[(size_t)orow * 128 + nt * 16 + li];
                acc[nt][r] = v;
                s += v; s2 += v * v;
            }
            s  += __shfl_xor(s, 1);  s  += __shfl_xor(s, 2);
            s  += __shfl_xor(s, 4);  s  += __shfl_xor(s, 8);
            s2 += __shfl_xor(s2, 1); s2 += __shfl_xor(s2, 2);
            s2 += __shfl_xor(s2, 4); s2 += __shfl_xor(s2, 8);
            float mean = s * (1.f / 128.f);
            float var  = s2 * (1.f / 128.f) - mean * mean;
            float rstd = rsqrtf(var + 1e-5f);
            #pragma unroll
            for (int nt = 0; nt < 8; ++nt)
                outp[(size_t)orow * 128 + nt * 16 + li] =
                    (acc[nt][r] - mean) * rstd * gv[nt];
        }
    }
}

// ---------------- fused FFN: LN2(x1 + relu(x1@W1)@W2) -----------------------
// ALL batches: grid (64, 4) x 256 thr; block owns 32 rows (2 M-tiles share
// every weight fragment); 4-wave split over dff chunks + LDS reduce.
__global__ __launch_bounds__(256) void k_ffn(
    const float* __restrict__ x1, const short* __restrict__ W1T,
    const short* __restrict__ W2T, const float* __restrict__ gain,
    float* __restrict__ outp)
{
    __shared__ __align__(16) short hls[4][2][16 * 64]; // [wave][mt], swizzled
    __shared__ float red[3][2][16 * 128];              // 48 KB partial-acc dump
    const int w = threadIdx.x >> 6, lane = threadIdx.x & 63;
    const int g = lane >> 4, li = lane & 15;
    const size_t m0 = (size_t)blockIdx.y * 2048 + blockIdx.x * 32;
    s16x8 xf[2][4];                               // A-frags, loaded once
    #pragma unroll
    for (int mt = 0; mt < 2; ++mt)
        #pragma unroll
        for (int ks = 0; ks < 4; ++ks) {
            const float* xr = x1 + (m0 + mt * 16 + li) * 128 + ks * 32 + g * 8;
            float4 v0 = *(const float4*)xr, v1 = *(const float4*)(xr + 4);
            xf[mt][ks] = (s16x8){ f2bf(v0.x), f2bf(v0.y), f2bf(v0.z), f2bf(v0.w),
                                  f2bf(v1.x), f2bf(v1.y), f2bf(v1.z), f2bf(v1.w) };
        }
    f32x4 acc[2][8] = {};
    #pragma unroll 4
    for (int cq = 0; cq < 8; ++cq) {              // ch = w*8 + cq
        int ch = w * 8 + cq;
        f32x4 st[2][4] = {};                      // GEMM1: h = relu(x@W1 chunk)
        #pragma unroll
        for (int nt = 0; nt < 4; ++nt)
            #pragma unroll
            for (int ks = 0; ks < 4; ++ks) {
                s16x8 bfr = *(const s16x8*)(W1T + (size_t)(ch * 64 + nt * 16 + li) * 128
                                               + ks * 32 + g * 8);
                mfma_bf16(&st[0][nt], xf[0][ks], bfr);
                mfma_bf16(&st[1][nt], xf[1][ks], bfr);
            }
        #pragma unroll
        for (int mt = 0; mt < 2; ++mt) {          // stage h -> LDS (P pattern)
            short* hw = hls[w][mt];
            #pragma unroll
            for (int nt = 0; nt < 4; ++nt)
                #pragma unroll
                for (int r = 0; r < 4; ++r) {
                    int rw = g * 4 + r;
                    hw[rw * 64 + (((nt * 2 + (li >> 3)) ^ (rw & 7)) * 8) + (li & 7)]
                        = f2bf(fmaxf(st[mt][nt][r], 0.f));
                }
        }
        #pragma unroll
        for (int kk = 0; kk < 2; ++kk) {          // GEMM2: acc += h @ W2 chunk
            s16x8 af0 = *(const s16x8*)&hls[w][0][li * 64
                                                  + (((kk * 4 + g) ^ (li & 7)) * 8)];
            s16x8 af1 = *(const s16x8*)&hls[w][1][li * 64
                                                  + (((kk * 4 + g) ^ (li & 7)) * 8)];
            #pragma unroll
            for (int nt = 0; nt < 8; ++nt) {
                s16x8 bfr = *(const s16x8*)(W2T + (size_t)(nt * 16 + li) * 2048
                                               + ch * 64 + kk * 32 + g * 8);
                mfma_bf16(&acc[0][nt], af0, bfr);
                mfma_bf16(&acc[1][nt], af1, bfr);
            }
        }
    }
    if (w > 0) {
        #pragma unroll
        for (int mt = 0; mt < 2; ++mt)
            #pragma unroll
            for (int nt = 0; nt < 8; ++nt)
                #pragma unroll
                for (int r = 0; r < 4; ++r)
                    red[w - 1][mt][(g * 4 + r) * 128 + nt * 16 + li] = acc[mt][nt][r];
    }
    __syncthreads();
    if (w == 0) {
        float gv[8];
        #pragma unroll
        for (int nt = 0; nt < 8; ++nt) gv[nt] = gain[nt * 16 + li];
        #pragma unroll
        for (int mt = 0; mt < 2; ++mt)
            #pragma unroll
            for (int r = 0; r < 4; ++r) {
                size_t orow = m0 + mt * 16 + g * 4 + r;
                float s = 0.f, s2 = 0.f;
                #pragma unroll
                for (int nt = 0; nt < 8; ++nt) {
                    float v = acc[mt][nt][r]
                            + red[0][mt][(g * 4 + r) * 128 + nt * 16 + li]
                            + red[1][mt][(g * 4 + r) * 128 + nt * 16 + li]
                            + red[2][mt][(g * 4 + r) * 128 + nt * 16 + li]
                            + x1[orow * 128 + nt * 16 + li];
                    acc[mt][nt][r] = v;
                    s += v; s2 += v * v;
                }
                s  += __shfl_xor(s, 1);  s  += __shfl_xor(s, 2);
                s  += __shfl_xor(s, 4);  s  += __shfl_xor(s, 8);
                s2 += __shfl_xor(s2, 1); s2 += __shfl_xor(s2, 2);
                s2 += __shfl_xor(s2, 4); s2 += __shfl_xor(s2, 8);
                float mean = s * (1.f / 128.f);
                float var  = s2 * (1.f / 128.f) - mean * mean;
                float rstd = rsqrtf(var + 1e-5f);
                #pragma unroll
                for (int nt = 0; nt < 8; ++nt)
                    outp[orow * 128 + nt * 16 + li] =
                        (acc[mt][nt][r] - mean) * rstd * gv[nt];
            }
    }
}

// ---------------------------------------------------------------------------
extern "C" void kernel_launch(void* const* d_in, const int* in_sizes, int n_in,
                              void* d_out, int out_size, void* d_ws, size_t ws_size,
                              hipStream_t stream)
{
    const float* x  = (const float*)d_in[0];
    const float* Wq = (const float*)d_in[1];
    const float* Wk = (const float*)d_in[2];
    const float* Wv = (const float*)d_in[3];
    const float* Wo = (const float*)d_in[4];
    const float* W1 = (const float*)d_in[5];
    const float* W2 = (const float*)d_in[6];
    const float* g1 = (const float*)d_in[7];
    const float* g2 = (const float*)d_in[8];
    float* out = (float*)d_out;
    (void)in_sizes; (void)n_in; (void)out_size; (void)ws_size;

    char* basep = (char*)d_ws;
    size_t off = 0;
    auto carve = [&](size_t bytes) {
        void* q = basep + off;
        off += (bytes + 255) & ~(size_t)255;
        return q;
    };
    // total ~22.3 MB (green proven to 23.3 in r12/r13)
    short*  WqT = (short*)carve(1024ull * 128 * 2);       // 256 KB
    short*  WkT = (short*)carve(1024ull * 128 * 2);
    short*  WvT = (short*)carve(1024ull * 128 * 2);
    short*  WoT = (short*)carve(128ull * 1024 * 2);       // 256 KB
    short*  W1T = (short*)carve(2048ull * 128 * 2);       // 512 KB
    short*  W2T = (short*)carve(128ull * 2048 * 2);       // 512 KB
    short*  Qh  = (short*)carve(8ull * 2048 * 128 * 2);   // 4 MB (8 heads)
    short*  Kh  = (short*)carve(8ull * 2048 * 128 * 2);   // 4 MB
    short*  Vt  = (short*)carve(8ull * 32 * 128 * 64 * 2);// 4 MB (tile-blocked)
    short*  O0  = (short*)carve(2048ull * 1024 * 2);      // 4 MB
    short*  O1  = (short*)carve(2048ull * 1024 * 2);      // 4 MB
    float2* ml0 = (float2*)carve(8ull * 2048 * 8);        // 128 KB
    float2* ml1 = (float2*)carve(8ull * 2048 * 8);        // 128 KB

    // weight prep: ONE launch
    k_transpose_all<<<4096, 256, 0, stream>>>(Wq, Wk, Wv, Wo, W1, W2,
                                              WqT, WkT, WvT, WoT, W1T, W2T);

    // ---- stage A per batch: qkv -> attention -> fused oproj+LN1 ----
    for (int b = 0; b < 4; ++b) {
        const float* xb = x + (size_t)b * 2048 * 128;
        float* x1b = out + (size_t)b * 2048 * 128;   // x1 lives in d_out rows
        k_qkv<<<dim3(32, 16, 3), 256, 0, stream>>>(xb, WqT, WkT, WvT, Qh, Kh, Vt);
        k_attn<<<dim3(32, 8, 2), 256, 0, stream>>>(Qh, Kh, Vt, O0, O1, ml0, ml1);
        k_oproj<<<128, 256, 0, stream>>>(O0, O1, ml0, ml1, WoT, xb, g1, x1b);
    }

    // ---- stage B: fused FFN + LN2, ALL batches, one launch ----
    k_ffn<<<dim3(64, 4), 256, 0, stream>>>(out, W1T, W2T, g2, out);
}

// Round 18
// 384.769 us; speedup vs baseline: 5.8341x; 1.0034x over previous
//
#include <hip/hip_runtime.h>
#include <stdint.h>

// ---------------------------------------------------------------------------
// TransformerEncoderLayer: b=4 s=2048 d=128 h=8 (head_dim=128) dff=2048
// Round-18:
//  - k_attn: QBLK=128 (8 waves/block) -> staged K/V tile feeds 2x q rows,
//    halves L2 staging traffic; s_setprio(1) around MFMA clusters (T5).
//  - k_ffn: hls double-buffered (cq&1) -> breaks loop-carried LDS hazard that
//    blocked cross-chunk pipelining (r17 post-mortem).
//  - k_qkv: reads pre-converted bf16 x (k_cvt once for all batches).
// Everything else byte-identical to r17 (green).
// ---------------------------------------------------------------------------

using f32x4 = __attribute__((ext_vector_type(4))) float;
using s16x8 = __attribute__((ext_vector_type(8))) short;
using s16x4 = __attribute__((ext_vector_type(4))) short;
typedef __bf16 bf16x8 __attribute__((ext_vector_type(8)));

__device__ inline void mfma_bf16(f32x4* acc, s16x8 a, s16x8 b) {
    *acc = __builtin_amdgcn_mfma_f32_16x16x32_bf16(
        __builtin_bit_cast(bf16x8, a), __builtin_bit_cast(bf16x8, b), *acc, 0, 0, 0);
}

__device__ inline short f2bf(float f) {   // RNE f32 -> bf16 bits
    uint32_t u = __builtin_bit_cast(uint32_t, f);
    u += 0x7fffu + ((u >> 16) & 1u);
    return (short)(u >> 16);
}

__device__ inline float bf2f(short s) {
    return __builtin_bit_cast(float, (uint32_t)((uint16_t)s) << 16);
}

// async global->LDS, 16B per lane; LDS dest = wave-uniform base + lane*16
__device__ inline void gload16(const short* g, short* l) {
    __builtin_amdgcn_global_load_lds(
        (const __attribute__((address_space(1))) void*)g,
        (__attribute__((address_space(3))) void*)l, 16, 0, 0);
}

// ---------------- x f32 -> bf16 (all batches, one launch) ------------------
__global__ __launch_bounds__(256) void k_cvt(const float* __restrict__ x,
                                             short* __restrict__ xb) {
    int i = (blockIdx.x * 256 + threadIdx.x) * 4;
    float4 v = *(const float4*)(x + i);
    s16x4 o = { f2bf(v.x), f2bf(v.y), f2bf(v.z), f2bf(v.w) };
    *(s16x4*)(xb + i) = o;
}

// ---------------- ALL weight transposes, one launch ------------------------
__global__ __launch_bounds__(256) void k_transpose_all(
    const float* __restrict__ Wq, const float* __restrict__ Wk,
    const float* __restrict__ Wv, const float* __restrict__ Wo,
    const float* __restrict__ W1, const float* __restrict__ W2,
    short* __restrict__ WqT, short* __restrict__ WkT, short* __restrict__ WvT,
    short* __restrict__ WoT, short* __restrict__ W1T, short* __restrict__ W2T)
{
    int b = blockIdx.x;
    const float* w; short* wt; int R, lc, lb;
    if (b < 512)       { w = Wq; wt = WqT; R = 128;  lc = 10; lb = 0;    }
    else if (b < 1024) { w = Wk; wt = WkT; R = 128;  lc = 10; lb = 512;  }
    else if (b < 1536) { w = Wv; wt = WvT; R = 128;  lc = 10; lb = 1024; }
    else if (b < 2048) { w = Wo; wt = WoT; R = 1024; lc = 7;  lb = 1536; }
    else if (b < 3072) { w = W1; wt = W1T; R = 128;  lc = 11; lb = 2048; }
    else               { w = W2; wt = W2T; R = 2048; lc = 7;  lb = 3072; }
    int i = (b - lb) * 256 + threadIdx.x;
    int r = i >> lc, c = i & ((1 << lc) - 1);
    wt[c * R + r] = f2bf(w[i]);
}

// ---------------- QKV projection (one batch, ALL 8 heads) ------------------
// A read from pre-converted bf16 xb. Q (pre-scaled 1/sqrt(d)), K row-major
// [h8][2048][128]; V tile-blocked [h8][kt32][d128][s64].
__global__ __launch_bounds__(256) void k_qkv(
    const short* __restrict__ xbB, const short* __restrict__ WqT,
    const short* __restrict__ WkT, const short* __restrict__ WvT,
    short* __restrict__ Qh, short* __restrict__ Kh, short* __restrict__ Vt)
{
    const int z = blockIdx.z;
    const short* __restrict__ WT = (z == 0) ? WqT : (z == 1) ? WkT : WvT; // [1024][128]
    const int w = threadIdx.x >> 6, lane = threadIdx.x & 63;
    const int g = lane >> 4, li = lane & 15;
    const int m0 = blockIdx.x * 64 + w * 16;
    const int n0 = blockIdx.y * 64;               // 0..960
    f32x4 acc[4] = {};
    #pragma unroll
    for (int ks = 0; ks < 4; ++ks) {
        s16x8 a = *(const s16x8*)(xbB + (size_t)(m0 + li) * 128 + ks * 32 + g * 8);
        #pragma unroll
        for (int nt = 0; nt < 4; ++nt) {
            s16x8 bfr = *(const s16x8*)(WT + (size_t)(n0 + nt * 16 + li) * 128
                                           + ks * 32 + g * 8);
            mfma_bf16(&acc[nt], a, bfr);
        }
    }
    const float sc = (z == 0) ? 0.088388347648318447f : 1.0f; // 1/sqrt(128) into Q
    #pragma unroll
    for (int nt = 0; nt < 4; ++nt) {
        int col = n0 + nt * 16 + li;              // 0..1023
        int hh = col >> 7, dd = col & 127;        // head, dim
        if (z == 2) {
            int row0 = m0 + g * 4;                // s, multiple of 4
            int kt = row0 >> 6, so = row0 & 63;
            s16x4 o = { f2bf(acc[nt][0]), f2bf(acc[nt][1]),
                        f2bf(acc[nt][2]), f2bf(acc[nt][3]) };
            *(s16x4*)(Vt + (((size_t)hh * 32 + kt) * 128 + dd) * 64 + so) = o;
        } else {
            short* __restrict__ dst = (z == 0) ? Qh : Kh;
            #pragma unroll
            for (int r = 0; r < 4; ++r)
                dst[((size_t)hh * 2048 + m0 + g * 4 + r) * 128 + dd] =
                    f2bf(acc[nt][r] * sc);
        }
    }
}

// ---------------- flash attention, 8 waves/block (QBLK=128), kv-split x2 ---
// grid (16 qblocks of 128 rows, 8 heads, 2 kv-halves) = 256 blocks x 512 thr.
// Each staged K/V tile feeds 128 q rows. Shuffle-free softmax common path.
__global__ __launch_bounds__(512) void k_attn(
    const short* __restrict__ Qh, const short* __restrict__ Kh,
    const short* __restrict__ Vt, short* __restrict__ O0,
    short* __restrict__ O1, float2* __restrict__ ml0, float2* __restrict__ ml1)
{
    __shared__ __align__(16) short Kls[2][64 * 128];   // swizzled [k][d], dbuf
    __shared__ __align__(16) short Vls[2][128 * 64];   // swizzled [d][k], dbuf
    __shared__ __align__(16) short Pls[8][16 * 64];    // per-wave swizzled [q][k]
    const int hh = blockIdx.y;
    const int half = blockIdx.z;
    const size_t base  = (size_t)hh * 2048 * 128;
    const size_t vbase = (size_t)hh * 32 * 8192;       // tile-blocked V^T
    const int w = threadIdx.x >> 6, lane = threadIdx.x & 63;
    const int g = lane >> 4, li = lane & 15;
    const int q0 = blockIdx.x * 128;
    const int qw = q0 + w * 16;
    const int kt0 = half * 16;

    // 512 threads stage 1024 K-chunks + 1024 V-chunks (16B each).
    #define STAGE(BUF, KT)                                                      \
        { _Pragma("unroll")                                                     \
          for (int c2 = 0; c2 < 2; ++c2) {                                      \
              int ci = c2 * 512 + (int)threadIdx.x;                             \
              int row = ci >> 4, cc = ci & 15;                                  \
              gload16(Kh + base + (size_t)((KT) * 64 + row) * 128               \
                         + ((cc ^ (row & 7)) * 8),                              \
                      &Kls[BUF][(c2 * 512 + w * 64) * 8]);                      \
              int d = ci >> 3, jc = ci & 7;                                     \
              gload16(Vt + vbase + (size_t)(KT) * 8192 + d * 64                 \
                         + ((jc ^ (d & 7)) * 8),                                \
                      &Vls[BUF][(c2 * 512 + w * 64) * 8]);                      \
          } }

    s16x8 qf[4];
    #pragma unroll
    for (int ks = 0; ks < 4; ++ks)
        qf[ks] = *(const s16x8*)(Qh + base + (size_t)(qw + li) * 128 + ks * 32 + g * 8);

    f32x4 acc[8] = {};
    float mrow[4] = { -1e30f, -1e30f, -1e30f, -1e30f };
    float lpart[4] = { 0.f, 0.f, 0.f, 0.f };    // PER-LANE partial of l

    STAGE(0, kt0);
    for (int t = 0; t < 16; ++t) {
        const int cur = t & 1;
        __syncthreads();                  // drains vmcnt: buf[cur] ready
        if (t + 1 < 16) STAGE(cur ^ 1, kt0 + t + 1);   // in flight during compute

        f32x4 st[4];
        __builtin_amdgcn_s_setprio(1);
        #pragma unroll
        for (int nt = 0; nt < 4; ++nt) {
            st[nt] = (f32x4){0.f, 0.f, 0.f, 0.f};
            #pragma unroll
            for (int ks = 0; ks < 4; ++ks) {
                s16x8 bfr = *(const s16x8*)&Kls[cur][(nt * 16 + li) * 128
                                                + (((ks * 4 + g) ^ (li & 7)) * 8)];
                mfma_bf16(&st[nt], qf[ks], bfr);
            }
        }
        __builtin_amdgcn_s_setprio(0);

        // per-LANE max; defer-max check needs NO shuffles.
        float mxl[4];
        bool cond = true;
        #pragma unroll
        for (int r = 0; r < 4; ++r) {
            mxl[r] = fmaxf(fmaxf(st[0][r], st[1][r]), fmaxf(st[2][r], st[3][r]));
            cond = cond && (mxl[r] <= mrow[r] + 8.f);
        }
        if (__all(cond)) {
            #pragma unroll
            for (int r = 0; r < 4; ++r) {
                float rs = 0.f;
                #pragma unroll
                for (int nt = 0; nt < 4; ++nt) {
                    float p = __expf(st[nt][r] - mrow[r]);
                    st[nt][r] = p;
                    rs += p;
                }
                lpart[r] += rs;
            }
        } else {
            #pragma unroll
            for (int r = 0; r < 4; ++r) {
                float mx = mxl[r];
                mx = fmaxf(mx, __shfl_xor(mx, 1));
                mx = fmaxf(mx, __shfl_xor(mx, 2));
                mx = fmaxf(mx, __shfl_xor(mx, 4));
                mx = fmaxf(mx, __shfl_xor(mx, 8));
                float mnew = fmaxf(mrow[r], mx);
                float alpha = __expf(mrow[r] - mnew);
                float rs = 0.f;
                #pragma unroll
                for (int nt = 0; nt < 4; ++nt) {
                    float p = __expf(st[nt][r] - mnew);
                    st[nt][r] = p;
                    rs += p;
                }
                lpart[r] = lpart[r] * alpha + rs;   // alpha row-uniform
                mrow[r] = mnew;
                #pragma unroll
                for (int dt = 0; dt < 8; ++dt) acc[dt][r] *= alpha;
            }
        }

        short* pw = Pls[w];
        #pragma unroll
        for (int nt = 0; nt < 4; ++nt)
            #pragma unroll
            for (int r = 0; r < 4; ++r) {
                int row = g * 4 + r;
                pw[row * 64 + (((nt * 2 + (li >> 3)) ^ (row & 7)) * 8) + (li & 7)]
                    = f2bf(st[nt][r]);
            }
        __builtin_amdgcn_s_setprio(1);
        #pragma unroll
        for (int kk = 0; kk < 2; ++kk) {
            s16x8 af = *(const s16x8*)&pw[li * 64 + (((kk * 4 + g) ^ (li & 7)) * 8)];
            #pragma unroll
            for (int dt = 0; dt < 8; ++dt) {
                s16x8 bfr = *(const s16x8*)&Vls[cur][(dt * 16 + li) * 64
                                                + (((kk * 4 + g) ^ (li & 7)) * 8)];
                mfma_bf16(&acc[dt], af, bfr);
            }
        }
        __builtin_amdgcn_s_setprio(0);
    }
    #undef STAGE

    // epilogue: reduce per-lane l partials once
    float lrow[4];
    #pragma unroll
    for (int r = 0; r < 4; ++r) {
        float rs = lpart[r];
        rs += __shfl_xor(rs, 1);
        rs += __shfl_xor(rs, 2);
        rs += __shfl_xor(rs, 4);
        rs += __shfl_xor(rs, 8);
        lrow[r] = rs;
    }
    short* __restrict__ Op = half ? O1 : O0;
    float2* __restrict__ mlp = half ? ml1 : ml0;
    #pragma unroll
    for (int r = 0; r < 4; ++r) {
        int row = q0 + w * 16 + g * 4 + r;
        if (li == 0) mlp[hh * 2048 + row] = make_float2(mrow[r], lrow[r]);
        #pragma unroll
        for (int dt = 0; dt < 8; ++dt)
            Op[(size_t)row * 1024 + hh * 128 + dt * 16 + li] = f2bf(acc[dt][r]);
    }
}

// ---------------- fused combine + out-proj + residual + LN1 ----------------
// per batch: grid 128 blocks x 256 thr; block owns 16 rows; 4-wave K-split.
__global__ __launch_bounds__(256) void k_oproj(
    const short* __restrict__ O0, const short* __restrict__ O1,
    const float2* __restrict__ ml0, const float2* __restrict__ ml1,
    const short* __restrict__ WoT, const float* __restrict__ resid,
    const float* __restrict__ gain, float* __restrict__ outp)
{
    __shared__ float red[3][16 * 128];            // 24 KB partial-acc dump
    const int w = threadIdx.x >> 6, lane = threadIdx.x & 63;
    const int g = lane >> 4, li = lane & 15;
    const int m0 = blockIdx.x * 16;
    const int row = m0 + li;                      // this lane's A-frag row
    float w0[2], w1[2], il[2];                    // this wave's 2 heads
    #pragma unroll
    for (int hi = 0; hi < 2; ++hi) {
        int h = w * 2 + hi;
        float2 a = ml0[h * 2048 + row], bml = ml1[h * 2048 + row];
        float M = fmaxf(a.x, bml.x);
        float e0 = __expf(a.x - M), e1 = __expf(bml.x - M);
        w0[hi] = e0; w1[hi] = e1;
        il[hi] = 1.f / (a.y * e0 + bml.y * e1);
    }
    f32x4 acc[8] = {};
    #pragma unroll
    for (int kq = 0; kq < 8; ++kq) {              // ks = w*8 + kq
        int ks = w * 8 + kq;
        int hi = kq >> 2;
        s16x8 a0 = *(const s16x8*)(O0 + (size_t)row * 1024 + ks * 32 + g * 8);
        s16x8 a1 = *(const s16x8*)(O1 + (size_t)row * 1024 + ks * 32 + g * 8);
        s16x8 a;
        #pragma unroll
        for (int e = 0; e < 8; ++e)
            a[e] = f2bf((bf2f(a0[e]) * w0[hi] + bf2f(a1[e]) * w1[hi]) * il[hi]);
        #pragma unroll
        for (int nt = 0; nt < 8; ++nt) {
            s16x8 bfr = *(const s16x8*)(WoT + (size_t)(nt * 16 + li) * 1024
                                           + ks * 32 + g * 8);
            mfma_bf16(&acc[nt], a, bfr);
        }
    }
    if (w > 0) {
        #pragma unroll
        for (int nt = 0; nt < 8; ++nt)
            #pragma unroll
            for (int r = 0; r < 4; ++r)
                red[w - 1][(g * 4 + r) * 128 + nt * 16 + li] = acc[nt][r];
    }
    __syncthreads();
    if (w == 0) {
        float gv[8];
        #pragma unroll
        for (int nt = 0; nt < 8; ++nt) gv[nt] = gain[nt * 16 + li];
        #pragma unroll
        for (int r = 0; r < 4; ++r) {
            int orow = m0 + g * 4 + r;
            float s = 0.f, s2 = 0.f;
            #pragma unroll
            for (int nt = 0; nt < 8; ++nt) {
                float v = acc[nt][r]
                        + red[0][(g * 4 + r) * 128 + nt * 16 + li]
                        + red[1][(g * 4 + r) * 128 + nt * 16 + li]
                        + red[2][(g * 4 + r) * 128 + nt * 16 + li]
                        + resid[(size_t)orow * 128 + nt * 16 + li];
                acc[nt][r] = v;
                s += v; s2 += v * v;
            }
            s  += __shfl_xor(s, 1);  s  += __shfl_xor(s, 2);
            s  += __shfl_xor(s, 4);  s  += __shfl_xor(s, 8);
            s2 += __shfl_xor(s2, 1); s2 += __shfl_xor(s2, 2);
            s2 += __shfl_xor(s2, 4); s2 += __shfl_xor(s2, 8);
            float mean = s * (1.f / 128.f);
            float var  = s2 * (1.f / 128.f) - mean * mean;
            float rstd = rsqrtf(var + 1e-5f);
            #pragma unroll
            for (int nt = 0; nt < 8; ++nt)
                outp[(size_t)orow * 128 + nt * 16 + li] =
                    (acc[nt][r] - mean) * rstd * gv[nt];
        }
    }
}

// ---------------- fused FFN: LN2(x1 + relu(x1@W1)@W2) -----------------------
// ALL batches: grid (64, 4) x 256 thr; block owns 32 rows; 4-wave dff-split;
// hls DOUBLE-BUFFERED so chunk i+1 GEMM1 overlaps chunk i GEMM2.
__global__ __launch_bounds__(256) void k_ffn(
    const float* __restrict__ x1, const short* __restrict__ W1T,
    const short* __restrict__ W2T, const float* __restrict__ gain,
    float* __restrict__ outp)
{
    __shared__ __align__(16) short hls[4][2][2][16 * 64]; // [wave][dbuf][mt]
    __shared__ float red[3][2][16 * 128];                 // 48 KB partial dump
    const int w = threadIdx.x >> 6, lane = threadIdx.x & 63;
    const int g = lane >> 4, li = lane & 15;
    const size_t m0 = (size_t)blockIdx.y * 2048 + blockIdx.x * 32;
    s16x8 xf[2][4];                               // A-frags, loaded once
    #pragma unroll
    for (int mt = 0; mt < 2; ++mt)
        #pragma unroll
        for (int ks = 0; ks < 4; ++ks) {
            const float* xr = x1 + (m0 + mt * 16 + li) * 128 + ks * 32 + g * 8;
            float4 v0 = *(const float4*)xr, v1 = *(const float4*)(xr + 4);
            xf[mt][ks] = (s16x8){ f2bf(v0.x), f2bf(v0.y), f2bf(v0.z), f2bf(v0.w),
                                  f2bf(v1.x), f2bf(v1.y), f2bf(v1.z), f2bf(v1.w) };
        }
    f32x4 acc[2][8] = {};
    #pragma unroll 2
    for (int cq = 0; cq < 8; ++cq) {              // ch = w*8 + cq
        int ch = w * 8 + cq;
        int cur = cq & 1;
        f32x4 st[2][4] = {};                      // GEMM1: h = relu(x@W1 chunk)
        #pragma unroll
        for (int nt = 0; nt < 4; ++nt)
            #pragma unroll
            for (int ks = 0; ks < 4; ++ks) {
                s16x8 bfr = *(const s16x8*)(W1T + (size_t)(ch * 64 + nt * 16 + li) * 128
                                               + ks * 32 + g * 8);
                mfma_bf16(&st[0][nt], xf[0][ks], bfr);
                mfma_bf16(&st[1][nt], xf[1][ks], bfr);
            }
        #pragma unroll
        for (int mt = 0; mt < 2; ++mt) {          // stage h -> LDS (dbuf)
            short* hw = hls[w][cur][mt];
            #pragma unroll
            for (int nt = 0; nt < 4; ++nt)
                #pragma unroll
                for (int r = 0; r < 4; ++r) {
                    int rw = g * 4 + r;
                    hw[rw * 64 + (((nt * 2 + (li >> 3)) ^ (rw & 7)) * 8) + (li & 7)]
                        = f2bf(fmaxf(st[mt][nt][r], 0.f));
                }
        }
        #pragma unroll
        for (int kk = 0; kk < 2; ++kk) {          // GEMM2: acc += h @ W2 chunk
            s16x8 af0 = *(const s16x8*)&hls[w][cur][0][li * 64
                                                  + (((kk * 4 + g) ^ (li & 7)) * 8)];
            s16x8 af1 = *(const s16x8*)&hls[w][cur][1][li * 64
                                                  + (((kk * 4 + g) ^ (li & 7)) * 8)];
            #pragma unroll
            for (int nt = 0; nt < 8; ++nt) {
                s16x8 bfr = *(const s16x8*)(W2T + (size_t)(nt * 16 + li) * 2048
                                               + ch * 64 + kk * 32 + g * 8);
                mfma_bf16(&acc[0][nt], af0, bfr);
                mfma_bf16(&acc[1][nt], af1, bfr);
            }
        }
    }
    if (w > 0) {
        #pragma unroll
        for (int mt = 0; mt < 2; ++mt)
            #pragma unroll
            for (int nt = 0; nt < 8; ++nt)
                #pragma unroll
                for (int r = 0; r < 4; ++r)
                    red[w - 1][mt][(g * 4 + r) * 128 + nt * 16 + li] = acc[mt][nt][r];
    }
    __syncthreads();
    if (w == 0) {
        float gv[8];
        #pragma unroll
        for (int nt = 0; nt < 8; ++nt) gv[nt] = gain[nt * 16 + li];
        #pragma unroll
        for (int mt = 0; mt < 2; ++mt)
            #pragma unroll
            for (int r = 0; r < 4; ++r) {
                size_t orow = m0 + mt * 16 + g * 4 + r;
                float s = 0.f, s2 = 0.f;
                #pragma unroll
                for (int nt = 0; nt < 8; ++nt) {
                    float v = acc[mt][nt][r]
                            + red[0][mt][(g * 4 + r) * 128 + nt * 16 + li]
                            + red[1][mt][(g * 4 + r) * 128 + nt * 16 + li]
                            + red[2][mt][(g * 4 + r) * 128 + nt * 16 + li]
                            + x1[orow * 128 + nt * 16 + li];
                    acc[mt][nt][r] = v;
                    s += v; s2 += v * v;
                }
                s  += __shfl_xor(s, 1);  s  += __shfl_xor(s, 2);
                s  += __shfl_xor(s, 4);  s  += __shfl_xor(s, 8);
                s2 += __shfl_xor(s2, 1); s2 += __shfl_xor(s2, 2);
                s2 += __shfl_xor(s2, 4); s2 += __shfl_xor(s2, 8);
                float mean = s * (1.f / 128.f);
                float var  = s2 * (1.f / 128.f) - mean * mean;
                float rstd = rsqrtf(var + 1e-5f);
                #pragma unroll
                for (int nt = 0; nt < 8; ++nt)
                    outp[orow * 128 + nt * 16 + li] =
                        (acc[mt][nt][r] - mean) * rstd * gv[nt];
            }
    }
}

// ---------------------------------------------------------------------------
extern "C" void kernel_launch(void* const* d_in, const int* in_sizes, int n_in,
                              void* d_out, int out_size, void* d_ws, size_t ws_size,
                              hipStream_t stream)
{
    const float* x  = (const float*)d_in[0];
    const float* Wq = (const float*)d_in[1];
    const float* Wk = (const float*)d_in[2];
    const float* Wv = (const float*)d_in[3];
    const float* Wo = (const float*)d_in[4];
    const float* W1 = (const float*)d_in[5];
    const float* W2 = (const float*)d_in[6];
    const float* g1 = (const float*)d_in[7];
    const float* g2 = (const float*)d_in[8];
    float* out = (float*)d_out;
    (void)in_sizes; (void)n_in; (void)out_size; (void)ws_size;

    char* basep = (char*)d_ws;
    size_t off = 0;
    auto carve = [&](size_t bytes) {
        void* q = basep + off;
        off += (bytes + 255) & ~(size_t)255;
        return q;
    };
    // total ~26.3 MB (green proven to 23.3; cliff located ~45)
    short*  WqT = (short*)carve(1024ull * 128 * 2);       // 256 KB
    short*  WkT = (short*)carve(1024ull * 128 * 2);
    short*  WvT = (short*)carve(1024ull * 128 * 2);
    short*  WoT = (short*)carve(128ull * 1024 * 2);       // 256 KB
    short*  W1T = (short*)carve(2048ull * 128 * 2);       // 512 KB
    short*  W2T = (short*)carve(128ull * 2048 * 2);       // 512 KB
    short*  xb  = (short*)carve(8192ull * 128 * 2);       // 2 MB (bf16 x, all b)
    short*  Qh  = (short*)carve(8ull * 2048 * 128 * 2);   // 4 MB (8 heads)
    short*  Kh  = (short*)carve(8ull * 2048 * 128 * 2);   // 4 MB
    short*  Vt  = (short*)carve(8ull * 32 * 128 * 64 * 2);// 4 MB (tile-blocked)
    short*  O0  = (short*)carve(2048ull * 1024 * 2);      // 4 MB
    short*  O1  = (short*)carve(2048ull * 1024 * 2);      // 4 MB
    float2* ml0 = (float2*)carve(8ull * 2048 * 8);        // 128 KB
    float2* ml1 = (float2*)carve(8ull * 2048 * 8);        // 128 KB

    // prep: x -> bf16, weights -> transposed bf16
    k_cvt<<<1024, 256, 0, stream>>>(x, xb);
    k_transpose_all<<<4096, 256, 0, stream>>>(Wq, Wk, Wv, Wo, W1, W2,
                                              WqT, WkT, WvT, WoT, W1T, W2T);

    // ---- stage A per batch: qkv -> attention -> fused oproj+LN1 ----
    for (int b = 0; b < 4; ++b) {
        const float* xf32 = x + (size_t)b * 2048 * 128;
        float* x1b = out + (size_t)b * 2048 * 128;   // x1 lives in d_out rows
        k_qkv<<<dim3(32, 16, 3), 256, 0, stream>>>(xb + (size_t)b * 2048 * 128,
                                                   WqT, WkT, WvT, Qh, Kh, Vt);
        k_attn<<<dim3(16, 8, 2), 512, 0, stream>>>(Qh, Kh, Vt, O0, O1, ml0, ml1);
        k_oproj<<<128, 256, 0, stream>>>(O0, O1, ml0, ml1, WoT, xf32, g1, x1b);
    }

    // ---- stage B: fused FFN + LN2, ALL batches, one launch ----
    k_ffn<<<dim3(64, 4), 256, 0, stream>>>(out, W1T, W2T, g2, out);
}

// Round 19
// 360.191 us; speedup vs baseline: 6.2322x; 1.0682x over previous
//
#include <hip/hip_runtime.h>
#include <stdint.h>

// ---------------------------------------------------------------------------
// TransformerEncoderLayer: b=4 s=2048 d=128 h=8 (head_dim=128) dff=2048
// Round-19 (r18 post-mortem: both nulls -> revised to latency/TLP fixes):
//  - k_ffn: 8-wave K-split (2 waves/SIMD), LDS f32-atomic reduce (16KB red),
//    hls single-buffered. Attacks 1-wave/SIMD L2-latency exposure.
//  - k_qkv: B-tile (16KB) staged via global_load_lds w/ source-folded swizzle
//    (attention's proven pattern) -> L2 latency off the MFMA chain.
// k_attn / k_oproj byte-identical to r18 (green).
// ---------------------------------------------------------------------------

using f32x4 = __attribute__((ext_vector_type(4))) float;
using s16x8 = __attribute__((ext_vector_type(8))) short;
using s16x4 = __attribute__((ext_vector_type(4))) short;
typedef __bf16 bf16x8 __attribute__((ext_vector_type(8)));

__device__ inline void mfma_bf16(f32x4* acc, s16x8 a, s16x8 b) {
    *acc = __builtin_amdgcn_mfma_f32_16x16x32_bf16(
        __builtin_bit_cast(bf16x8, a), __builtin_bit_cast(bf16x8, b), *acc, 0, 0, 0);
}

__device__ inline short f2bf(float f) {   // RNE f32 -> bf16 bits
    uint32_t u = __builtin_bit_cast(uint32_t, f);
    u += 0x7fffu + ((u >> 16) & 1u);
    return (short)(u >> 16);
}

__device__ inline float bf2f(short s) {
    return __builtin_bit_cast(float, (uint32_t)((uint16_t)s) << 16);
}

// async global->LDS, 16B per lane; LDS dest = wave-uniform base + lane*16
__device__ inline void gload16(const short* g, short* l) {
    __builtin_amdgcn_global_load_lds(
        (const __attribute__((address_space(1))) void*)g,
        (__attribute__((address_space(3))) void*)l, 16, 0, 0);
}

// ---------------- x f32 -> bf16 (all batches, one launch) ------------------
__global__ __launch_bounds__(256) void k_cvt(const float* __restrict__ x,
                                             short* __restrict__ xb) {
    int i = (blockIdx.x * 256 + threadIdx.x) * 4;
    float4 v = *(const float4*)(x + i);
    s16x4 o = { f2bf(v.x), f2bf(v.y), f2bf(v.z), f2bf(v.w) };
    *(s16x4*)(xb + i) = o;
}

// ---------------- ALL weight transposes, one launch ------------------------
__global__ __launch_bounds__(256) void k_transpose_all(
    const float* __restrict__ Wq, const float* __restrict__ Wk,
    const float* __restrict__ Wv, const float* __restrict__ Wo,
    const float* __restrict__ W1, const float* __restrict__ W2,
    short* __restrict__ WqT, short* __restrict__ WkT, short* __restrict__ WvT,
    short* __restrict__ WoT, short* __restrict__ W1T, short* __restrict__ W2T)
{
    int b = blockIdx.x;
    const float* w; short* wt; int R, lc, lb;
    if (b < 512)       { w = Wq; wt = WqT; R = 128;  lc = 10; lb = 0;    }
    else if (b < 1024) { w = Wk; wt = WkT; R = 128;  lc = 10; lb = 512;  }
    else if (b < 1536) { w = Wv; wt = WvT; R = 128;  lc = 10; lb = 1024; }
    else if (b < 2048) { w = Wo; wt = WoT; R = 1024; lc = 7;  lb = 1536; }
    else if (b < 3072) { w = W1; wt = W1T; R = 128;  lc = 11; lb = 2048; }
    else               { w = W2; wt = W2T; R = 2048; lc = 7;  lb = 3072; }
    int i = (b - lb) * 256 + threadIdx.x;
    int r = i >> lc, c = i & ((1 << lc) - 1);
    wt[c * R + r] = f2bf(w[i]);
}

// ---------------- QKV projection (one batch, ALL 8 heads) ------------------
// B-tile (64 cols x K=128, 16KB) staged in LDS via global_load_lds with the
// swizzle folded into the global source (attention's proven pattern).
__global__ __launch_bounds__(256) void k_qkv(
    const short* __restrict__ xbB, const short* __restrict__ WqT,
    const short* __restrict__ WkT, const short* __restrict__ WvT,
    short* __restrict__ Qh, short* __restrict__ Kh, short* __restrict__ Vt)
{
    __shared__ __align__(16) short Bls[64 * 128];   // swizzled [col][k]
    const int z = blockIdx.z;
    const short* __restrict__ WT = (z == 0) ? WqT : (z == 1) ? WkT : WvT; // [1024][128]
    const int w = threadIdx.x >> 6, lane = threadIdx.x & 63;
    const int g = lane >> 4, li = lane & 15;
    const int m0 = blockIdx.x * 64 + w * 16;
    const int n0 = blockIdx.y * 64;               // 0..960

    // stage B tile: 1024 chunks of 16B, 256 thr x 4
    #pragma unroll
    for (int c2 = 0; c2 < 4; ++c2) {
        int ci = c2 * 256 + (int)threadIdx.x;
        int row = ci >> 4, cc = ci & 15;
        gload16(WT + (size_t)(n0 + row) * 128 + ((cc ^ (row & 7)) * 8),
                &Bls[(c2 * 256 + w * 64) * 8]);
    }
    __syncthreads();

    f32x4 acc[4] = {};
    #pragma unroll
    for (int ks = 0; ks < 4; ++ks) {
        s16x8 a = *(const s16x8*)(xbB + (size_t)(m0 + li) * 128 + ks * 32 + g * 8);
        #pragma unroll
        for (int nt = 0; nt < 4; ++nt) {
            s16x8 bfr = *(const s16x8*)&Bls[(nt * 16 + li) * 128
                                            + (((ks * 4 + g) ^ (li & 7)) * 8)];
            mfma_bf16(&acc[nt], a, bfr);
        }
    }
    const float sc = (z == 0) ? 0.088388347648318447f : 1.0f; // 1/sqrt(128) into Q
    #pragma unroll
    for (int nt = 0; nt < 4; ++nt) {
        int col = n0 + nt * 16 + li;              // 0..1023
        int hh = col >> 7, dd = col & 127;        // head, dim
        if (z == 2) {
            int row0 = m0 + g * 4;                // s, multiple of 4
            int kt = row0 >> 6, so = row0 & 63;
            s16x4 o = { f2bf(acc[nt][0]), f2bf(acc[nt][1]),
                        f2bf(acc[nt][2]), f2bf(acc[nt][3]) };
            *(s16x4*)(Vt + (((size_t)hh * 32 + kt) * 128 + dd) * 64 + so) = o;
        } else {
            short* __restrict__ dst = (z == 0) ? Qh : Kh;
            #pragma unroll
            for (int r = 0; r < 4; ++r)
                dst[((size_t)hh * 2048 + m0 + g * 4 + r) * 128 + dd] =
                    f2bf(acc[nt][r] * sc);
        }
    }
}

// ---------------- flash attention, 8 waves/block (QBLK=128), kv-split x2 ---
// grid (16 qblocks of 128 rows, 8 heads, 2 kv-halves) = 256 blocks x 512 thr.
__global__ __launch_bounds__(512) void k_attn(
    const short* __restrict__ Qh, const short* __restrict__ Kh,
    const short* __restrict__ Vt, short* __restrict__ O0,
    short* __restrict__ O1, float2* __restrict__ ml0, float2* __restrict__ ml1)
{
    __shared__ __align__(16) short Kls[2][64 * 128];   // swizzled [k][d], dbuf
    __shared__ __align__(16) short Vls[2][128 * 64];   // swizzled [d][k], dbuf
    __shared__ __align__(16) short Pls[8][16 * 64];    // per-wave swizzled [q][k]
    const int hh = blockIdx.y;
    const int half = blockIdx.z;
    const size_t base  = (size_t)hh * 2048 * 128;
    const size_t vbase = (size_t)hh * 32 * 8192;       // tile-blocked V^T
    const int w = threadIdx.x >> 6, lane = threadIdx.x & 63;
    const int g = lane >> 4, li = lane & 15;
    const int q0 = blockIdx.x * 128;
    const int qw = q0 + w * 16;
    const int kt0 = half * 16;

    #define STAGE(BUF, KT)                                                      \
        { _Pragma("unroll")                                                     \
          for (int c2 = 0; c2 < 2; ++c2) {                                      \
              int ci = c2 * 512 + (int)threadIdx.x;                             \
              int row = ci >> 4, cc = ci & 15;                                  \
              gload16(Kh + base + (size_t)((KT) * 64 + row) * 128               \
                         + ((cc ^ (row & 7)) * 8),                              \
                      &Kls[BUF][(c2 * 512 + w * 64) * 8]);                      \
              int d = ci >> 3, jc = ci & 7;                                     \
              gload16(Vt + vbase + (size_t)(KT) * 8192 + d * 64                 \
                         + ((jc ^ (d & 7)) * 8),                                \
                      &Vls[BUF][(c2 * 512 + w * 64) * 8]);                      \
          } }

    s16x8 qf[4];
    #pragma unroll
    for (int ks = 0; ks < 4; ++ks)
        qf[ks] = *(const s16x8*)(Qh + base + (size_t)(qw + li) * 128 + ks * 32 + g * 8);

    f32x4 acc[8] = {};
    float mrow[4] = { -1e30f, -1e30f, -1e30f, -1e30f };
    float lpart[4] = { 0.f, 0.f, 0.f, 0.f };    // PER-LANE partial of l

    STAGE(0, kt0);
    for (int t = 0; t < 16; ++t) {
        const int cur = t & 1;
        __syncthreads();                  // drains vmcnt: buf[cur] ready
        if (t + 1 < 16) STAGE(cur ^ 1, kt0 + t + 1);   // in flight during compute

        f32x4 st[4];
        __builtin_amdgcn_s_setprio(1);
        #pragma unroll
        for (int nt = 0; nt < 4; ++nt) {
            st[nt] = (f32x4){0.f, 0.f, 0.f, 0.f};
            #pragma unroll
            for (int ks = 0; ks < 4; ++ks) {
                s16x8 bfr = *(const s16x8*)&Kls[cur][(nt * 16 + li) * 128
                                                + (((ks * 4 + g) ^ (li & 7)) * 8)];
                mfma_bf16(&st[nt], qf[ks], bfr);
            }
        }
        __builtin_amdgcn_s_setprio(0);

        float mxl[4];
        bool cond = true;
        #pragma unroll
        for (int r = 0; r < 4; ++r) {
            mxl[r] = fmaxf(fmaxf(st[0][r], st[1][r]), fmaxf(st[2][r], st[3][r]));
            cond = cond && (mxl[r] <= mrow[r] + 8.f);
        }
        if (__all(cond)) {
            #pragma unroll
            for (int r = 0; r < 4; ++r) {
                float rs = 0.f;
                #pragma unroll
                for (int nt = 0; nt < 4; ++nt) {
                    float p = __expf(st[nt][r] - mrow[r]);
                    st[nt][r] = p;
                    rs += p;
                }
                lpart[r] += rs;
            }
        } else {
            #pragma unroll
            for (int r = 0; r < 4; ++r) {
                float mx = mxl[r];
                mx = fmaxf(mx, __shfl_xor(mx, 1));
                mx = fmaxf(mx, __shfl_xor(mx, 2));
                mx = fmaxf(mx, __shfl_xor(mx, 4));
                mx = fmaxf(mx, __shfl_xor(mx, 8));
                float mnew = fmaxf(mrow[r], mx);
                float alpha = __expf(mrow[r] - mnew);
                float rs = 0.f;
                #pragma unroll
                for (int nt = 0; nt < 4; ++nt) {
                    float p = __expf(st[nt][r] - mnew);
                    st[nt][r] = p;
                    rs += p;
                }
                lpart[r] = lpart[r] * alpha + rs;   // alpha row-uniform
                mrow[r] = mnew;
                #pragma unroll
                for (int dt = 0; dt < 8; ++dt) acc[dt][r] *= alpha;
            }
        }

        short* pw = Pls[w];
        #pragma unroll
        for (int nt = 0; nt < 4; ++nt)
            #pragma unroll
            for (int r = 0; r < 4; ++r) {
                int row = g * 4 + r;
                pw[row * 64 + (((nt * 2 + (li >> 3)) ^ (row & 7)) * 8) + (li & 7)]
                    = f2bf(st[nt][r]);
            }
        __builtin_amdgcn_s_setprio(1);
        #pragma unroll
        for (int kk = 0; kk < 2; ++kk) {
            s16x8 af = *(const s16x8*)&pw[li * 64 + (((kk * 4 + g) ^ (li & 7)) * 8)];
            #pragma unroll
            for (int dt = 0; dt < 8; ++dt) {
                s16x8 bfr = *(const s16x8*)&Vls[cur][(dt * 16 + li) * 64
                                                + (((kk * 4 + g) ^ (li & 7)) * 8)];
                mfma_bf16(&acc[dt], af, bfr);
            }
        }
        __builtin_amdgcn_s_setprio(0);
    }
    #undef STAGE

    float lrow[4];
    #pragma unroll
    for (int r = 0; r < 4; ++r) {
        float rs = lpart[r];
        rs += __shfl_xor(rs, 1);
        rs += __shfl_xor(rs, 2);
        rs += __shfl_xor(rs, 4);
        rs += __shfl_xor(rs, 8);
        lrow[r] = rs;
    }
    short* __restrict__ Op = half ? O1 : O0;
    float2* __restrict__ mlp = half ? ml1 : ml0;
    #pragma unroll
    for (int r = 0; r < 4; ++r) {
        int row = q0 + w * 16 + g * 4 + r;
        if (li == 0) mlp[hh * 2048 + row] = make_float2(mrow[r], lrow[r]);
        #pragma unroll
        for (int dt = 0; dt < 8; ++dt)
            Op[(size_t)row * 1024 + hh * 128 + dt * 16 + li] = f2bf(acc[dt][r]);
    }
}

// ---------------- fused combine + out-proj + residual + LN1 ----------------
__global__ __launch_bounds__(256) void k_oproj(
    const short* __restrict__ O0, const short* __restrict__ O1,
    const float2* __restrict__ ml0, const float2* __restrict__ ml1,
    const short* __restrict__ WoT, const float* __restrict__ resid,
    const float* __restrict__ gain, float* __restrict__ outp)
{
    __shared__ float red[3][16 * 128];            // 24 KB partial-acc dump
    const int w = threadIdx.x >> 6, lane = threadIdx.x & 63;
    const int g = lane >> 4, li = lane & 15;
    const int m0 = blockIdx.x * 16;
    const int row = m0 + li;
    float w0[2], w1[2], il[2];
    #pragma unroll
    for (int hi = 0; hi < 2; ++hi) {
        int h = w * 2 + hi;
        float2 a = ml0[h * 2048 + row], bml = ml1[h * 2048 + row];
        float M = fmaxf(a.x, bml.x);
        float e0 = __expf(a.x - M), e1 = __expf(bml.x - M);
        w0[hi] = e0; w1[hi] = e1;
        il[hi] = 1.f / (a.y * e0 + bml.y * e1);
    }
    f32x4 acc[8] = {};
    #pragma unroll
    for (int kq = 0; kq < 8; ++kq) {
        int ks = w * 8 + kq;
        int hi = kq >> 2;
        s16x8 a0 = *(const s16x8*)(O0 + (size_t)row * 1024 + ks * 32 + g * 8);
        s16x8 a1 = *(const s16x8*)(O1 + (size_t)row * 1024 + ks * 32 + g * 8);
        s16x8 a;
        #pragma unroll
        for (int e = 0; e < 8; ++e)
            a[e] = f2bf((bf2f(a0[e]) * w0[hi] + bf2f(a1[e]) * w1[hi]) * il[hi]);
        #pragma unroll
        for (int nt = 0; nt < 8; ++nt) {
            s16x8 bfr = *(const s16x8*)(WoT + (size_t)(nt * 16 + li) * 1024
                                           + ks * 32 + g * 8);
            mfma_bf16(&acc[nt], a, bfr);
        }
    }
    if (w > 0) {
        #pragma unroll
        for (int nt = 0; nt < 8; ++nt)
            #pragma unroll
            for (int r = 0; r < 4; ++r)
                red[w - 1][(g * 4 + r) * 128 + nt * 16 + li] = acc[nt][r];
    }
    __syncthreads();
    if (w == 0) {
        float gv[8];
        #pragma unroll
        for (int nt = 0; nt < 8; ++nt) gv[nt] = gain[nt * 16 + li];
        #pragma unroll
        for (int r = 0; r < 4; ++r) {
            int orow = m0 + g * 4 + r;
            float s = 0.f, s2 = 0.f;
            #pragma unroll
            for (int nt = 0; nt < 8; ++nt) {
                float v = acc[nt][r]
                        + red[0][(g * 4 + r) * 128 + nt * 16 + li]
                        + red[1][(g * 4 + r) * 128 + nt * 16 + li]
                        + red[2][(g * 4 + r) * 128 + nt * 16 + li]
                        + resid[(size_t)orow * 128 + nt * 16 + li];
                acc[nt][r] = v;
                s += v; s2 += v * v;
            }
            s  += __shfl_xor(s, 1);  s  += __shfl_xor(s, 2);
            s  += __shfl_xor(s, 4);  s  += __shfl_xor(s, 8);
            s2 += __shfl_xor(s2, 1); s2 += __shfl_xor(s2, 2);
            s2 += __shfl_xor(s2, 4); s2 += __shfl_xor(s2, 8);
            float mean = s * (1.f / 128.f);
            float var  = s2 * (1.f / 128.f) - mean * mean;
            float rstd = rsqrtf(var + 1e-5f);
            #pragma unroll
            for (int nt = 0; nt < 8; ++nt)
                outp[(size_t)orow * 128 + nt * 16 + li] =
                    (acc[nt][r] - mean) * rstd * gv[nt];
        }
    }
}

// ---------------- fused FFN: LN2(x1 + relu(x1@W1)@W2) -----------------------
// ALL batches: grid (64, 4) x 512 thr (8 waves); block owns 32 rows; 8-wave
// split over dff chunks (4 each); cross-wave reduce via LDS f32 atomicAdd.
__global__ __launch_bounds__(512) void k_ffn(
    const float* __restrict__ x1, const short* __restrict__ W1T,
    const short* __restrict__ W2T, const float* __restrict__ gain,
    float* __restrict__ outp)
{
    __shared__ __align__(16) short hls[8][2][16 * 64]; // [wave][mt], swizzled
    __shared__ float red[2][16 * 128];                 // 16 KB atomic reduce
    const int w = threadIdx.x >> 6, lane = threadIdx.x & 63;
    const int g = lane >> 4, li = lane & 15;
    const size_t m0 = (size_t)blockIdx.y * 2048 + blockIdx.x * 32;
    // zero the reduce buffer (512 thr x 8 floats)
    #pragma unroll
    for (int i = 0; i < 8; ++i)
        ((float*)red)[i * 512 + threadIdx.x] = 0.f;
    s16x8 xf[2][4];
    #pragma unroll
    for (int mt = 0; mt < 2; ++mt)
        #pragma unroll
        for (int ks = 0; ks < 4; ++ks) {
            const float* xr = x1 + (m0 + mt * 16 + li) * 128 + ks * 32 + g * 8;
            float4 v0 = *(const float4*)xr, v1 = *(const float4*)(xr + 4);
            xf[mt][ks] = (s16x8){ f2bf(v0.x), f2bf(v0.y), f2bf(v0.z), f2bf(v0.w),
                                  f2bf(v1.x), f2bf(v1.y), f2bf(v1.z), f2bf(v1.w) };
        }
    __syncthreads();                               // red zeroed
    f32x4 acc[2][8] = {};
    #pragma unroll
    for (int cq = 0; cq < 4; ++cq) {               // ch = w*4 + cq
        int ch = w * 4 + cq;
        f32x4 st[2][4] = {};
        #pragma unroll
        for (int nt = 0; nt < 4; ++nt)
            #pragma unroll
            for (int ks = 0; ks < 4; ++ks) {
                s16x8 bfr = *(const s16x8*)(W1T + (size_t)(ch * 64 + nt * 16 + li) * 128
                                               + ks * 32 + g * 8);
                mfma_bf16(&st[0][nt], xf[0][ks], bfr);
                mfma_bf16(&st[1][nt], xf[1][ks], bfr);
            }
        #pragma unroll
        for (int mt = 0; mt < 2; ++mt) {
            short* hw = hls[w][mt];
            #pragma unroll
            for (int nt = 0; nt < 4; ++nt)
                #pragma unroll
                for (int r = 0; r < 4; ++r) {
                    int rw = g * 4 + r;
                    hw[rw * 64 + (((nt * 2 + (li >> 3)) ^ (rw & 7)) * 8) + (li & 7)]
                        = f2bf(fmaxf(st[mt][nt][r], 0.f));
                }
        }
        #pragma unroll
        for (int kk = 0; kk < 2; ++kk) {
            s16x8 af0 = *(const s16x8*)&hls[w][0][li * 64
                                                  + (((kk * 4 + g) ^ (li & 7)) * 8)];
            s16x8 af1 = *(const s16x8*)&hls[w][1][li * 64
                                                  + (((kk * 4 + g) ^ (li & 7)) * 8)];
            #pragma unroll
            for (int nt = 0; nt < 8; ++nt) {
                s16x8 bfr = *(const s16x8*)(W2T + (size_t)(nt * 16 + li) * 2048
                                               + ch * 64 + kk * 32 + g * 8);
                mfma_bf16(&acc[0][nt], af0, bfr);
                mfma_bf16(&acc[1][nt], af1, bfr);
            }
        }
    }
    // cross-wave reduce: every wave atomically adds its partials
    #pragma unroll
    for (int mt = 0; mt < 2; ++mt)
        #pragma unroll
        for (int nt = 0; nt < 8; ++nt)
            #pragma unroll
            for (int r = 0; r < 4; ++r)
                atomicAdd(&red[mt][(g * 4 + r) * 128 + nt * 16 + li], acc[mt][nt][r]);
    __syncthreads();
    if (w == 0) {
        float gv[8];
        #pragma unroll
        for (int nt = 0; nt < 8; ++nt) gv[nt] = gain[nt * 16 + li];
        #pragma unroll
        for (int mt = 0; mt < 2; ++mt)
            #pragma unroll
            for (int r = 0; r < 4; ++r) {
                size_t orow = m0 + mt * 16 + g * 4 + r;
                float s = 0.f, s2 = 0.f;
                float vv[8];
                #pragma unroll
                for (int nt = 0; nt < 8; ++nt) {
                    float v = red[mt][(g * 4 + r) * 128 + nt * 16 + li]
                            + x1[orow * 128 + nt * 16 + li];
                    vv[nt] = v;
                    s += v; s2 += v * v;
                }
                s  += __shfl_xor(s, 1);  s  += __shfl_xor(s, 2);
                s  += __shfl_xor(s, 4);  s  += __shfl_xor(s, 8);
                s2 += __shfl_xor(s2, 1); s2 += __shfl_xor(s2, 2);
                s2 += __shfl_xor(s2, 4); s2 += __shfl_xor(s2, 8);
                float mean = s * (1.f / 128.f);
                float var  = s2 * (1.f / 128.f) - mean * mean;
                float rstd = rsqrtf(var + 1e-5f);
                #pragma unroll
                for (int nt = 0; nt < 8; ++nt)
                    outp[orow * 128 + nt * 16 + li] = (vv[nt] - mean) * rstd * gv[nt];
            }
    }
}

// ---------------------------------------------------------------------------
extern "C" void kernel_launch(void* const* d_in, const int* in_sizes, int n_in,
                              void* d_out, int out_size, void* d_ws, size_t ws_size,
                              hipStream_t stream)
{
    const float* x  = (const float*)d_in[0];
    const float* Wq = (const float*)d_in[1];
    const float* Wk = (const float*)d_in[2];
    const float* Wv = (const float*)d_in[3];
    const float* Wo = (const float*)d_in[4];
    const float* W1 = (const float*)d_in[5];
    const float* W2 = (const float*)d_in[6];
    const float* g1 = (const float*)d_in[7];
    const float* g2 = (const float*)d_in[8];
    float* out = (float*)d_out;
    (void)in_sizes; (void)n_in; (void)out_size; (void)ws_size;

    char* basep = (char*)d_ws;
    size_t off = 0;
    auto carve = [&](size_t bytes) {
        void* q = basep + off;
        off += (bytes + 255) & ~(size_t)255;
        return q;
    };
    // total ~26.3 MB (green proven at 26.3 in r18; cliff located ~45)
    short*  WqT = (short*)carve(1024ull * 128 * 2);
    short*  WkT = (short*)carve(1024ull * 128 * 2);
    short*  WvT = (short*)carve(1024ull * 128 * 2);
    short*  WoT = (short*)carve(128ull * 1024 * 2);
    short*  W1T = (short*)carve(2048ull * 128 * 2);
    short*  W2T = (short*)carve(128ull * 2048 * 2);
    short*  xb  = (short*)carve(8192ull * 128 * 2);
    short*  Qh  = (short*)carve(8ull * 2048 * 128 * 2);
    short*  Kh  = (short*)carve(8ull * 2048 * 128 * 2);
    short*  Vt  = (short*)carve(8ull * 32 * 128 * 64 * 2);
    short*  O0  = (short*)carve(2048ull * 1024 * 2);
    short*  O1  = (short*)carve(2048ull * 1024 * 2);
    float2* ml0 = (float2*)carve(8ull * 2048 * 8);
    float2* ml1 = (float2*)carve(8ull * 2048 * 8);

    k_cvt<<<1024, 256, 0, stream>>>(x, xb);
    k_transpose_all<<<4096, 256, 0, stream>>>(Wq, Wk, Wv, Wo, W1, W2,
                                              WqT, WkT, WvT, WoT, W1T, W2T);

    for (int b = 0; b < 4; ++b) {
        const float* xf32 = x + (size_t)b * 2048 * 128;
        float* x1b = out + (size_t)b * 2048 * 128;
        k_qkv<<<dim3(32, 16, 3), 256, 0, stream>>>(xb + (size_t)b * 2048 * 128,
                                                   WqT, WkT, WvT, Qh, Kh, Vt);
        k_attn<<<dim3(16, 8, 2), 512, 0, stream>>>(Qh, Kh, Vt, O0, O1, ml0, ml1);
        k_oproj<<<128, 256, 0, stream>>>(O0, O1, ml0, ml1, WoT, xf32, g1, x1b);
    }

    k_ffn<<<dim3(64, 4), 512, 0, stream>>>(out, W1T, W2T, g2, out);
}